// Round 6
// baseline (6555.733 us; speedup 1.0000x reference)
//
#include <hip/hip_runtime.h>

#define NEG_SLOPE 0.2f

constexpr int F = 512;    // heads * channels
constexpr int F_IN = 30;

// ---------------- CSR build ----------------

__global__ void hist_kernel(const int* __restrict__ ei, int* __restrict__ counts,
                            int N, int E) {
  int e = blockIdx.x * blockDim.x + threadIdx.x;
  int Et = E + N;
  if (e >= Et) return;
  int d = (e < E) ? ei[E + e] : (e - E);
  atomicAdd(&counts[d], 1);
}

__global__ void scan_kernel(const int* __restrict__ counts, int* __restrict__ offsets,
                            int* __restrict__ cursor, int n) {
  __shared__ int lds[1024];
  __shared__ int carry_s;
  if (threadIdx.x == 0) carry_s = 0;
  __syncthreads();
  for (int base = 0; base < n; base += 1024) {
    int i = base + threadIdx.x;
    int v = (i < n) ? counts[i] : 0;
    lds[threadIdx.x] = v;
    __syncthreads();
    for (int off = 1; off < 1024; off <<= 1) {
      int t = (threadIdx.x >= off) ? lds[threadIdx.x - off] : 0;
      __syncthreads();
      lds[threadIdx.x] += t;
      __syncthreads();
    }
    int excl = lds[threadIdx.x] - v;
    if (i < n) { int o = carry_s + excl; offsets[i] = o; cursor[i] = o; }
    __syncthreads();
    if (threadIdx.x == 1023) carry_s += lds[1023];
    __syncthreads();
  }
  if (threadIdx.x == 0) offsets[n] = carry_s;
}

__global__ void scatter_kernel(const int* __restrict__ ei, int* __restrict__ cursor,
                               int* __restrict__ src_s, int* __restrict__ dst_s,
                               int N, int E) {
  int e = blockIdx.x * blockDim.x + threadIdx.x;
  int Et = E + N;
  if (e >= Et) return;
  int s, d;
  if (e < E) { s = ei[e]; d = ei[E + e]; } else { s = e - E; d = e - E; }
  int p = atomicAdd(&cursor[d], 1);
  src_s[p] = s;
  dst_s[p] = d;
}

// Canonicalize within-segment order (atomic scatter order varies across
// replays -> FP sums drift). Sort each node's src list ascending.
__global__ void segsort_kernel(int* __restrict__ src_s, const int* __restrict__ off, int N) {
  int n = blockIdx.x * blockDim.x + threadIdx.x;
  if (n >= N) return;
  int p0 = off[n], p1 = off[n + 1];
  for (int i = p0 + 1; i < p1; ++i) {
    int key = src_s[i];
    int j = i - 1;
    while (j >= p0 && src_s[j] > key) { src_s[j + 1] = src_s[j]; --j; }
    src_s[j + 1] = key;
  }
}

// ---------------- GEMM (layer1, K=30):  out[N,512] = X[N,30] @ W[30,512] ----

__global__ void gemm30_kernel(const float* __restrict__ X, const float* __restrict__ W,
                              float* __restrict__ out, int N) {
  __shared__ float xs[16][F_IN];
  int row0 = blockIdx.x * 16;
  int tid = threadIdx.x;
  for (int i = tid; i < 16 * F_IN; i += 256) {
    int r = i / F_IN, k = i - r * F_IN;
    int row = row0 + r;
    xs[r][k] = (row < N) ? X[(size_t)row * F_IN + k] : 0.f;
  }
  __syncthreads();
  int cg = tid & 127;     // 128 col groups of 4
  int rg = tid >> 7;      // 0..1 -> rows rg*8 .. rg*8+7
  int c0 = cg * 4;
  float4 acc[8];
#pragma unroll
  for (int r = 0; r < 8; ++r) acc[r] = make_float4(0.f, 0.f, 0.f, 0.f);
#pragma unroll 2
  for (int k = 0; k < F_IN; ++k) {
    float4 w = *(const float4*)(W + (size_t)k * F + c0);
#pragma unroll
    for (int r = 0; r < 8; ++r) {
      float xv = xs[rg * 8 + r][k];
      acc[r].x += xv * w.x; acc[r].y += xv * w.y;
      acc[r].z += xv * w.z; acc[r].w += xv * w.w;
    }
  }
#pragma unroll
  for (int r = 0; r < 8; ++r) {
    int row = row0 + rg * 8 + r;
    if (row < N) *(float4*)(out + (size_t)row * F + c0) = acc[r];
  }
}

// ---------------- GEMM (layer2, K=512): out[N,512] = X[N,512] @ W[512,512] --
// block = 256 threads; tile = 32 rows x 512 cols; K in LDS chunks of 128;
// thread -> 16 rows x 4 cols; inner loop 4 k's at a time (ds_read_b128).

__global__ __launch_bounds__(256, 4)
void gemm512_kernel(const float* __restrict__ X, const float* __restrict__ W,
                    float* __restrict__ out, int N) {
  __shared__ float xs[32][128];
  int row0 = blockIdx.x * 32;
  int tid = threadIdx.x;
  int cg = tid & 127;     // col group of 4
  int rg = tid >> 7;      // 0..1 -> rows rg*16 .. +15
  int c0 = cg * 4;
  float4 acc[16];
#pragma unroll
  for (int r = 0; r < 16; ++r) acc[r] = make_float4(0.f, 0.f, 0.f, 0.f);

  for (int kc = 0; kc < 4; ++kc) {
    // stage 32x128 chunk: 1024 float4s over 256 threads
#pragma unroll
    for (int i = 0; i < 4; ++i) {
      int idx = tid + i * 256;
      int r = idx >> 5;       // 0..31
      int kq = idx & 31;      // float4 index within row chunk
      int row = row0 + r;
      float4 v = make_float4(0.f, 0.f, 0.f, 0.f);
      if (row < N) v = *(const float4*)(X + (size_t)row * F + kc * 128 + kq * 4);
      *(float4*)(&xs[r][kq * 4]) = v;
    }
    __syncthreads();
#pragma unroll 2
    for (int k4 = 0; k4 < 128; k4 += 4) {
      float4 w0 = *(const float4*)(W + (size_t)(kc * 128 + k4 + 0) * F + c0);
      float4 w1 = *(const float4*)(W + (size_t)(kc * 128 + k4 + 1) * F + c0);
      float4 w2 = *(const float4*)(W + (size_t)(kc * 128 + k4 + 2) * F + c0);
      float4 w3 = *(const float4*)(W + (size_t)(kc * 128 + k4 + 3) * F + c0);
#pragma unroll
      for (int r = 0; r < 16; ++r) {
        float4 xv = *(const float4*)(&xs[rg * 16 + r][k4]);
        acc[r].x += xv.x * w0.x + xv.y * w1.x + xv.z * w2.x + xv.w * w3.x;
        acc[r].y += xv.x * w0.y + xv.y * w1.y + xv.z * w2.y + xv.w * w3.y;
        acc[r].z += xv.x * w0.z + xv.y * w1.z + xv.z * w2.z + xv.w * w3.z;
        acc[r].w += xv.x * w0.w + xv.y * w1.w + xv.z * w2.w + xv.w * w3.w;
      }
    }
    __syncthreads();
  }
#pragma unroll
  for (int r = 0; r < 16; ++r) {
    int row = row0 + rg * 16 + r;
    if (row < N) *(float4*)(out + (size_t)row * F + c0) = acc[r];
  }
}

// GEMM for layer3: out[N,4] = X[N,512] @ W3[512,4]; one wave per node
__global__ void gemm3_kernel(const float* __restrict__ X, const float* __restrict__ W3,
                             float* __restrict__ h3, int N) {
  int n = blockIdx.x * 4 + (threadIdx.x >> 6);
  int lane = threadIdx.x & 63;
  if (n >= N) return;
  float acc[4] = {0.f, 0.f, 0.f, 0.f};
  for (int k = lane; k < F; k += 64) {
    float xv = X[(size_t)n * F + k];
#pragma unroll
    for (int j = 0; j < 4; ++j) acc[j] += xv * W3[k * 4 + j];
  }
#pragma unroll
  for (int j = 0; j < 4; ++j)
    for (int off = 32; off > 0; off >>= 1) acc[j] += __shfl_down(acc[j], off);
  if (lane == 0) {
    float4 o; o.x = acc[0]; o.y = acc[1]; o.z = acc[2]; o.w = acc[3];
    *(float4*)(h3 + (size_t)n * 4) = o;
  }
}

// ---------------- alpha dots ----------------
// block = 128 threads = 1 node; thread tid -> channels 4*tid.., head = tid>>5

__global__ void alpha_kernel(const float* __restrict__ h, const float* __restrict__ asrc,
                             const float* __restrict__ adst, float* __restrict__ as,
                             float* __restrict__ ad) {
  int n = blockIdx.x;
  int tid = threadIdx.x;
  int c0 = tid * 4;
  float4 hv = *(const float4*)(h + (size_t)n * F + c0);
  float4 sa = *(const float4*)(asrc + c0);
  float4 da = *(const float4*)(adst + c0);
  float ps = hv.x * sa.x + hv.y * sa.y + hv.z * sa.z + hv.w * sa.w;
  float pd = hv.x * da.x + hv.y * da.y + hv.z * da.z + hv.w * da.w;
#pragma unroll
  for (int off = 16; off > 0; off >>= 1) {
    ps += __shfl_down(ps, off);
    pd += __shfl_down(pd, off);
  }
  if ((tid & 31) == 0) {
    int head = tid >> 5;
    as[n * 4 + head] = ps;
    ad[n * 4 + head] = pd;
  }
}

// layer3: C=1 -> as[n,h] = h3[n,h]*a3s[h]
__global__ void alpha3_kernel(const float* __restrict__ h3, const float* __restrict__ a3s,
                              const float* __restrict__ a3d, float* __restrict__ as,
                              float* __restrict__ ad, int N) {
  int t = blockIdx.x * blockDim.x + threadIdx.x;
  if (t >= N * 4) return;
  int hh = t & 3;
  float v = h3[t];
  as[t] = v * a3s[hh];
  ad[t] = v * a3d[hh];
}

// ---------------- edge scores (sorted order) ----------------

__device__ __forceinline__ float leaky(float v) { return v > 0.f ? v : NEG_SLOPE * v; }

__global__ void edge_score_kernel(const float* __restrict__ as, const float* __restrict__ ad,
                                  const int* __restrict__ src_s, const int* __restrict__ dst_s,
                                  float* __restrict__ escore, int Et) {
  int p = blockIdx.x * blockDim.x + threadIdx.x;
  if (p >= Et) return;
  int s = src_s[p], d = dst_s[p];
  float4 a = *(const float4*)(as + (size_t)s * 4);
  float4 b = *(const float4*)(ad + (size_t)d * 4);
  float4 e;
  e.x = leaky(a.x + b.x);
  e.y = leaky(a.y + b.y);
  e.z = leaky(a.z + b.z);
  e.w = leaky(a.w + b.w);
  *(float4*)(escore + (size_t)p * 4) = e;
}

// ---------------- segment softmax stats ----------------
// one thread per (node, head); online max+sum in a single pass

__global__ void softmax_stats_kernel(const float* __restrict__ escore, const int* __restrict__ off,
                                     float* __restrict__ m_out, float* __restrict__ d_out_, int N) {
  int t = blockIdx.x * blockDim.x + threadIdx.x;
  if (t >= N * 4) return;
  int n = t >> 2, h = t & 3;
  int p0 = off[n], p1 = off[n + 1];
  float m = -1e30f, s = 0.f;
  for (int p = p0; p < p1; ++p) {
    float e = escore[(size_t)p * 4 + h];
    if (e > m) { s *= __expf(m - e); m = e; }
    s += __expf(e - m);
  }
  m_out[t] = m;
  d_out_[t] = s + 1e-16f;
}

// ---------------- aggregate: single pass, alpha computed inline ----------------
// block = 128 threads, one node per block; thread tid -> channels 4*tid..

template <bool RELU>
__global__ void aggregate_kernel(const float* __restrict__ hsrc, const float* __restrict__ escore,
                                 const int* __restrict__ src_s, const int* __restrict__ off,
                                 const float* __restrict__ m_buf, const float* __restrict__ d_buf,
                                 const float* __restrict__ bias, float* __restrict__ out) {
  int n = blockIdx.x;
  int tid = threadIdx.x;
  int c0 = tid * 4;
  int head = tid >> 5;
  int p0 = off[n], p1 = off[n + 1];
  float mh = m_buf[n * 4 + head];
  float inv = 1.f / d_buf[n * 4 + head];
  float4 acc = make_float4(0.f, 0.f, 0.f, 0.f);
  for (int p = p0; p < p1; ++p) {
    float a = __expf(escore[(size_t)p * 4 + head] - mh) * inv;
    int s = src_s[p];
    float4 hv = *(const float4*)(hsrc + (size_t)s * F + c0);
    acc.x += a * hv.x; acc.y += a * hv.y;
    acc.z += a * hv.z; acc.w += a * hv.w;
  }
  float4 bv = *(const float4*)(bias + c0);
  acc.x += bv.x; acc.y += bv.y; acc.z += bv.z; acc.w += bv.w;
  if (RELU) {
    acc.x = fmaxf(acc.x, 0.f); acc.y = fmaxf(acc.y, 0.f);
    acc.z = fmaxf(acc.z, 0.f); acc.w = fmaxf(acc.w, 0.f);
  }
  *(float4*)(out + (size_t)n * F + c0) = acc;
}

// layer3: one thread per (node, head); single pass; reduce 4 heads via shfl
__global__ void aggregate3_kernel(const float* __restrict__ h3, const float* __restrict__ escore,
                                  const int* __restrict__ src_s, const int* __restrict__ off,
                                  const float* __restrict__ m_buf, const float* __restrict__ d_buf,
                                  const float* __restrict__ b3, float* __restrict__ out, int N) {
  int t = blockIdx.x * blockDim.x + threadIdx.x;
  if (t >= N * 4) return;
  int n = t >> 2, head = t & 3;
  int p0 = off[n], p1 = off[n + 1];
  float mh = m_buf[t];
  float inv = 1.f / d_buf[t];
  float acc = 0.f;
  for (int p = p0; p < p1; ++p) {
    float a = __expf(escore[(size_t)p * 4 + head] - mh) * inv;
    acc += a * h3[(size_t)src_s[p] * 4 + head];
  }
  acc += __shfl_down(acc, 1);
  acc += __shfl_down(acc, 2);
  if (head == 0) out[n] = acc * 0.25f + b3[0];
}

// ---------------- host orchestration ----------------

extern "C" void kernel_launch(void* const* d_in, const int* in_sizes, int n_in,
                              void* d_out, int out_size, void* d_ws, size_t ws_size,
                              hipStream_t stream) {
  const float* x   = (const float*)d_in[0];
  const int*   ei  = (const int*)d_in[1];
  const float* W1  = (const float*)d_in[2];
  const float* a1s = (const float*)d_in[3];
  const float* a1d = (const float*)d_in[4];
  const float* b1  = (const float*)d_in[5];
  const float* W2  = (const float*)d_in[6];
  const float* a2s = (const float*)d_in[7];
  const float* a2d = (const float*)d_in[8];
  const float* b2  = (const float*)d_in[9];
  const float* W3  = (const float*)d_in[10];
  const float* a3s = (const float*)d_in[11];
  const float* a3d = (const float*)d_in[12];
  const float* b3  = (const float*)d_in[13];

  const int N = in_sizes[0] / F_IN;
  const int E = in_sizes[1] / 2;
  const int Et = E + N;

  char* base = (char*)d_ws;
  size_t off = 0;
  auto alloc = [&](size_t bytes) {
    void* p = base + off;
    off = (off + bytes + 255) & ~(size_t)255;
    return p;
  };
  float* A      = (float*)alloc((size_t)N * F * sizeof(float));
  float* Bbuf   = (float*)alloc((size_t)N * F * sizeof(float));
  float* escore = (float*)alloc((size_t)Et * 4 * sizeof(float));
  int*   src_s  = (int*)alloc((size_t)Et * sizeof(int));
  int*   dst_s  = (int*)alloc((size_t)Et * sizeof(int));
  int*   counts = (int*)alloc((size_t)N * sizeof(int));
  int*   offs   = (int*)alloc((size_t)(N + 1) * sizeof(int));
  int*   cursor = (int*)alloc((size_t)N * sizeof(int));
  float* as     = (float*)alloc((size_t)N * 4 * sizeof(float));
  float* ad     = (float*)alloc((size_t)N * 4 * sizeof(float));
  float* m_buf  = (float*)alloc((size_t)N * 4 * sizeof(float));
  float* d_buf  = (float*)alloc((size_t)N * 4 * sizeof(float));
  float* h3     = (float*)alloc((size_t)N * 4 * sizeof(float));

  // ---- CSR build (graph fixed across layers) ----
  hipMemsetAsync(counts, 0, (size_t)N * sizeof(int), stream);
  {
    int g = (Et + 255) / 256;
    hipLaunchKernelGGL(hist_kernel, dim3(g), dim3(256), 0, stream, ei, counts, N, E);
    hipLaunchKernelGGL(scan_kernel, dim3(1), dim3(1024), 0, stream, counts, offs, cursor, N);
    hipLaunchKernelGGL(scatter_kernel, dim3(g), dim3(256), 0, stream, ei, cursor, src_s, dst_s, N, E);
    hipLaunchKernelGGL(segsort_kernel, dim3((N + 255) / 256), dim3(256), 0, stream, src_s, offs, N);
  }

  int edgeGrid = (Et + 255) / 256;
  int nhGrid   = (N * 4 + 255) / 256;

  // ---- layer 1 ----
  hipLaunchKernelGGL(gemm30_kernel, dim3((N + 15) / 16), dim3(256), 0, stream, x, W1, A, N);
  hipLaunchKernelGGL(alpha_kernel, dim3(N), dim3(128), 0, stream, A, a1s, a1d, as, ad);
  hipLaunchKernelGGL(edge_score_kernel, dim3(edgeGrid), dim3(256), 0, stream, as, ad, src_s, dst_s, escore, Et);
  hipLaunchKernelGGL(softmax_stats_kernel, dim3(nhGrid), dim3(256), 0, stream, escore, offs, m_buf, d_buf, N);
  hipLaunchKernelGGL((aggregate_kernel<true>), dim3(N), dim3(128), 0, stream, A, escore, src_s, offs, m_buf, d_buf, b1, Bbuf);

  // ---- layer 2 ----
  hipLaunchKernelGGL(gemm512_kernel, dim3((N + 31) / 32), dim3(256), 0, stream, Bbuf, W2, A, N);
  hipLaunchKernelGGL(alpha_kernel, dim3(N), dim3(128), 0, stream, A, a2s, a2d, as, ad);
  hipLaunchKernelGGL(edge_score_kernel, dim3(edgeGrid), dim3(256), 0, stream, as, ad, src_s, dst_s, escore, Et);
  hipLaunchKernelGGL(softmax_stats_kernel, dim3(nhGrid), dim3(256), 0, stream, escore, offs, m_buf, d_buf, N);
  hipLaunchKernelGGL((aggregate_kernel<true>), dim3(N), dim3(128), 0, stream, A, escore, src_s, offs, m_buf, d_buf, b2, Bbuf);

  // ---- layer 3 ----
  hipLaunchKernelGGL(gemm3_kernel, dim3((N + 3) / 4), dim3(256), 0, stream, Bbuf, W3, h3, N);
  hipLaunchKernelGGL(alpha3_kernel, dim3(nhGrid), dim3(256), 0, stream, h3, a3s, a3d, as, ad, N);
  hipLaunchKernelGGL(edge_score_kernel, dim3(edgeGrid), dim3(256), 0, stream, as, ad, src_s, dst_s, escore, Et);
  hipLaunchKernelGGL(softmax_stats_kernel, dim3(nhGrid), dim3(256), 0, stream, escore, offs, m_buf, d_buf, N);
  hipLaunchKernelGGL(aggregate3_kernel, dim3(nhGrid), dim3(256), 0, stream, h3, escore, src_s, offs, m_buf, d_buf, b3, (float*)d_out, N);
}

// Round 7
// 1336.783 us; speedup vs baseline: 4.9041x; 4.9041x over previous
//
#include <hip/hip_runtime.h>

#define NEG_SLOPE 0.2f

constexpr int F = 512;    // heads * channels
constexpr int F_IN = 30;

// ---------------- CSR build ----------------

__global__ void hist_kernel(const int* __restrict__ ei, int* __restrict__ counts,
                            int N, int E) {
  int e = blockIdx.x * blockDim.x + threadIdx.x;
  int Et = E + N;
  if (e >= Et) return;
  int d = (e < E) ? ei[E + e] : (e - E);
  atomicAdd(&counts[d], 1);
}

__global__ void scan_kernel(const int* __restrict__ counts, int* __restrict__ offsets,
                            int* __restrict__ cursor, int n) {
  __shared__ int lds[1024];
  __shared__ int carry_s;
  if (threadIdx.x == 0) carry_s = 0;
  __syncthreads();
  for (int base = 0; base < n; base += 1024) {
    int i = base + threadIdx.x;
    int v = (i < n) ? counts[i] : 0;
    lds[threadIdx.x] = v;
    __syncthreads();
    for (int off = 1; off < 1024; off <<= 1) {
      int t = (threadIdx.x >= off) ? lds[threadIdx.x - off] : 0;
      __syncthreads();
      lds[threadIdx.x] += t;
      __syncthreads();
    }
    int excl = lds[threadIdx.x] - v;
    if (i < n) { int o = carry_s + excl; offsets[i] = o; cursor[i] = o; }
    __syncthreads();
    if (threadIdx.x == 1023) carry_s += lds[1023];
    __syncthreads();
  }
  if (threadIdx.x == 0) offsets[n] = carry_s;
}

__global__ void scatter_kernel(const int* __restrict__ ei, int* __restrict__ cursor,
                               int* __restrict__ src_s, int* __restrict__ dst_s,
                               int N, int E) {
  int e = blockIdx.x * blockDim.x + threadIdx.x;
  int Et = E + N;
  if (e >= Et) return;
  int s, d;
  if (e < E) { s = ei[e]; d = ei[E + e]; } else { s = e - E; d = e - E; }
  int p = atomicAdd(&cursor[d], 1);
  src_s[p] = s;
  dst_s[p] = d;
}

// Canonicalize within-segment order (atomic scatter order varies across
// replays -> FP sums drift). Sort each node's src list ascending.
__global__ void segsort_kernel(int* __restrict__ src_s, const int* __restrict__ off, int N) {
  int n = blockIdx.x * blockDim.x + threadIdx.x;
  if (n >= N) return;
  int p0 = off[n], p1 = off[n + 1];
  for (int i = p0 + 1; i < p1; ++i) {
    int key = src_s[i];
    int j = i - 1;
    while (j >= p0 && src_s[j] > key) { src_s[j + 1] = src_s[j]; --j; }
    src_s[j + 1] = key;
  }
}

// ---------------- GEMM (layer1, K=30):  out[N,512] = X[N,30] @ W[30,512] ----

__global__ void gemm30_kernel(const float* __restrict__ X, const float* __restrict__ W,
                              float* __restrict__ out, int N) {
  __shared__ float xs[16][F_IN];
  int row0 = blockIdx.x * 16;
  int tid = threadIdx.x;
  for (int i = tid; i < 16 * F_IN; i += 256) {
    int r = i / F_IN, k = i - r * F_IN;
    int row = row0 + r;
    xs[r][k] = (row < N) ? X[(size_t)row * F_IN + k] : 0.f;
  }
  __syncthreads();
  int cg = tid & 127;     // 128 col groups of 4
  int rg = tid >> 7;      // 0..1 -> rows rg*8 .. rg*8+7
  int c0 = cg * 4;
  float4 acc[8];
#pragma unroll
  for (int r = 0; r < 8; ++r) acc[r] = make_float4(0.f, 0.f, 0.f, 0.f);
#pragma unroll 2
  for (int k = 0; k < F_IN; ++k) {
    float4 w = *(const float4*)(W + (size_t)k * F + c0);
#pragma unroll
    for (int r = 0; r < 8; ++r) {
      float xv = xs[rg * 8 + r][k];
      acc[r].x += xv * w.x; acc[r].y += xv * w.y;
      acc[r].z += xv * w.z; acc[r].w += xv * w.w;
    }
  }
#pragma unroll
  for (int r = 0; r < 8; ++r) {
    int row = row0 + rg * 8 + r;
    if (row < N) *(float4*)(out + (size_t)row * F + c0) = acc[r];
  }
}

// ---------------- GEMM (layer2, K=512): out[N,512] = X[N,512] @ W[512,512] --
// block = 256 threads; tile = 16 rows x 512 cols; whole K row in LDS (32 KB);
// thread -> 8 rows x 4 cols (acc = 32 VGPR, no launch_bounds -> no spill);
// inner loop: 4 k's per step, 4 independent W float4 loads + broadcast
// ds_read_b128 per row.

__global__ void gemm512_kernel(const float* __restrict__ X, const float* __restrict__ W,
                               float* __restrict__ out, int N) {
  __shared__ float xs[16][512];
  int row0 = blockIdx.x * 16;
  int tid = threadIdx.x;
  // stage 16x512 X tile: 2048 float4s over 256 threads
#pragma unroll
  for (int i = 0; i < 8; ++i) {
    int idx = tid + i * 256;
    int r = idx >> 7;        // 0..15
    int kq = idx & 127;      // float4 index within row
    int row = row0 + r;
    float4 v = make_float4(0.f, 0.f, 0.f, 0.f);
    if (row < N) v = *(const float4*)(X + (size_t)row * F + kq * 4);
    *(float4*)(&xs[r][kq * 4]) = v;
  }
  __syncthreads();
  int cg = tid & 127;     // col group of 4
  int rg = tid >> 7;      // 0..1 -> rows rg*8 .. +7
  int c0 = cg * 4;
  float4 acc[8];
#pragma unroll
  for (int r = 0; r < 8; ++r) acc[r] = make_float4(0.f, 0.f, 0.f, 0.f);
#pragma unroll 2
  for (int k4 = 0; k4 < 512; k4 += 4) {
    float4 w0 = *(const float4*)(W + (size_t)(k4 + 0) * F + c0);
    float4 w1 = *(const float4*)(W + (size_t)(k4 + 1) * F + c0);
    float4 w2 = *(const float4*)(W + (size_t)(k4 + 2) * F + c0);
    float4 w3 = *(const float4*)(W + (size_t)(k4 + 3) * F + c0);
#pragma unroll
    for (int r = 0; r < 8; ++r) {
      float4 xv = *(const float4*)(&xs[rg * 8 + r][k4]);   // wave-uniform addr: broadcast
      acc[r].x += xv.x * w0.x + xv.y * w1.x + xv.z * w2.x + xv.w * w3.x;
      acc[r].y += xv.x * w0.y + xv.y * w1.y + xv.z * w2.y + xv.w * w3.y;
      acc[r].z += xv.x * w0.z + xv.y * w1.z + xv.z * w2.z + xv.w * w3.z;
      acc[r].w += xv.x * w0.w + xv.y * w1.w + xv.z * w2.w + xv.w * w3.w;
    }
  }
#pragma unroll
  for (int r = 0; r < 8; ++r) {
    int row = row0 + rg * 8 + r;
    if (row < N) *(float4*)(out + (size_t)row * F + c0) = acc[r];
  }
}

// GEMM for layer3: out[N,4] = X[N,512] @ W3[512,4]; one wave per node
__global__ void gemm3_kernel(const float* __restrict__ X, const float* __restrict__ W3,
                             float* __restrict__ h3, int N) {
  int n = blockIdx.x * 4 + (threadIdx.x >> 6);
  int lane = threadIdx.x & 63;
  if (n >= N) return;
  float acc[4] = {0.f, 0.f, 0.f, 0.f};
  for (int k = lane; k < F; k += 64) {
    float xv = X[(size_t)n * F + k];
#pragma unroll
    for (int j = 0; j < 4; ++j) acc[j] += xv * W3[k * 4 + j];
  }
#pragma unroll
  for (int j = 0; j < 4; ++j)
    for (int off = 32; off > 0; off >>= 1) acc[j] += __shfl_down(acc[j], off);
  if (lane == 0) {
    float4 o; o.x = acc[0]; o.y = acc[1]; o.z = acc[2]; o.w = acc[3];
    *(float4*)(h3 + (size_t)n * 4) = o;
  }
}

// ---------------- alpha dots ----------------
// block = 128 threads = 1 node; thread tid -> channels 4*tid.., head = tid>>5

__global__ void alpha_kernel(const float* __restrict__ h, const float* __restrict__ asrc,
                             const float* __restrict__ adst, float* __restrict__ as,
                             float* __restrict__ ad) {
  int n = blockIdx.x;
  int tid = threadIdx.x;
  int c0 = tid * 4;
  float4 hv = *(const float4*)(h + (size_t)n * F + c0);
  float4 sa = *(const float4*)(asrc + c0);
  float4 da = *(const float4*)(adst + c0);
  float ps = hv.x * sa.x + hv.y * sa.y + hv.z * sa.z + hv.w * sa.w;
  float pd = hv.x * da.x + hv.y * da.y + hv.z * da.z + hv.w * da.w;
#pragma unroll
  for (int off = 16; off > 0; off >>= 1) {
    ps += __shfl_down(ps, off);
    pd += __shfl_down(pd, off);
  }
  if ((tid & 31) == 0) {
    int head = tid >> 5;
    as[n * 4 + head] = ps;
    ad[n * 4 + head] = pd;
  }
}

// layer3: C=1 -> as[n,h] = h3[n,h]*a3s[h]
__global__ void alpha3_kernel(const float* __restrict__ h3, const float* __restrict__ a3s,
                              const float* __restrict__ a3d, float* __restrict__ as,
                              float* __restrict__ ad, int N) {
  int t = blockIdx.x * blockDim.x + threadIdx.x;
  if (t >= N * 4) return;
  int hh = t & 3;
  float v = h3[t];
  as[t] = v * a3s[hh];
  ad[t] = v * a3d[hh];
}

// ---------------- edge scores (sorted order) ----------------

__device__ __forceinline__ float leaky(float v) { return v > 0.f ? v : NEG_SLOPE * v; }

__global__ void edge_score_kernel(const float* __restrict__ as, const float* __restrict__ ad,
                                  const int* __restrict__ src_s, const int* __restrict__ dst_s,
                                  float* __restrict__ escore, int Et) {
  int p = blockIdx.x * blockDim.x + threadIdx.x;
  if (p >= Et) return;
  int s = src_s[p], d = dst_s[p];
  float4 a = *(const float4*)(as + (size_t)s * 4);
  float4 b = *(const float4*)(ad + (size_t)d * 4);
  float4 e;
  e.x = leaky(a.x + b.x);
  e.y = leaky(a.y + b.y);
  e.z = leaky(a.z + b.z);
  e.w = leaky(a.w + b.w);
  *(float4*)(escore + (size_t)p * 4) = e;
}

// ---------------- segment softmax stats ----------------
// one thread per (node, head); online max+sum in a single pass

__global__ void softmax_stats_kernel(const float* __restrict__ escore, const int* __restrict__ off,
                                     float* __restrict__ m_out, float* __restrict__ d_out_, int N) {
  int t = blockIdx.x * blockDim.x + threadIdx.x;
  if (t >= N * 4) return;
  int n = t >> 2, h = t & 3;
  int p0 = off[n], p1 = off[n + 1];
  float m = -1e30f, s = 0.f;
  for (int p = p0; p < p1; ++p) {
    float e = escore[(size_t)p * 4 + h];
    if (e > m) { s *= __expf(m - e); m = e; }
    s += __expf(e - m);
  }
  m_out[t] = m;
  d_out_[t] = s + 1e-16f;
}

// ---------------- aggregate: single pass, alpha computed inline ----------------
// block = 128 threads, one node per block; thread tid -> channels 4*tid..

template <bool RELU>
__global__ void aggregate_kernel(const float* __restrict__ hsrc, const float* __restrict__ escore,
                                 const int* __restrict__ src_s, const int* __restrict__ off,
                                 const float* __restrict__ m_buf, const float* __restrict__ d_buf,
                                 const float* __restrict__ bias, float* __restrict__ out) {
  int n = blockIdx.x;
  int tid = threadIdx.x;
  int c0 = tid * 4;
  int head = tid >> 5;
  int p0 = off[n], p1 = off[n + 1];
  float mh = m_buf[n * 4 + head];
  float inv = 1.f / d_buf[n * 4 + head];
  float4 acc = make_float4(0.f, 0.f, 0.f, 0.f);
  for (int p = p0; p < p1; ++p) {
    float a = __expf(escore[(size_t)p * 4 + head] - mh) * inv;
    int s = src_s[p];
    float4 hv = *(const float4*)(hsrc + (size_t)s * F + c0);
    acc.x += a * hv.x; acc.y += a * hv.y;
    acc.z += a * hv.z; acc.w += a * hv.w;
  }
  float4 bv = *(const float4*)(bias + c0);
  acc.x += bv.x; acc.y += bv.y; acc.z += bv.z; acc.w += bv.w;
  if (RELU) {
    acc.x = fmaxf(acc.x, 0.f); acc.y = fmaxf(acc.y, 0.f);
    acc.z = fmaxf(acc.z, 0.f); acc.w = fmaxf(acc.w, 0.f);
  }
  *(float4*)(out + (size_t)n * F + c0) = acc;
}

// layer3: one thread per (node, head); single pass; reduce 4 heads via shfl
__global__ void aggregate3_kernel(const float* __restrict__ h3, const float* __restrict__ escore,
                                  const int* __restrict__ src_s, const int* __restrict__ off,
                                  const float* __restrict__ m_buf, const float* __restrict__ d_buf,
                                  const float* __restrict__ b3, float* __restrict__ out, int N) {
  int t = blockIdx.x * blockDim.x + threadIdx.x;
  if (t >= N * 4) return;
  int n = t >> 2, head = t & 3;
  int p0 = off[n], p1 = off[n + 1];
  float mh = m_buf[t];
  float inv = 1.f / d_buf[t];
  float acc = 0.f;
  for (int p = p0; p < p1; ++p) {
    float a = __expf(escore[(size_t)p * 4 + head] - mh) * inv;
    acc += a * h3[(size_t)src_s[p] * 4 + head];
  }
  acc += __shfl_down(acc, 1);
  acc += __shfl_down(acc, 2);
  if (head == 0) out[n] = acc * 0.25f + b3[0];
}

// ---------------- host orchestration ----------------

extern "C" void kernel_launch(void* const* d_in, const int* in_sizes, int n_in,
                              void* d_out, int out_size, void* d_ws, size_t ws_size,
                              hipStream_t stream) {
  const float* x   = (const float*)d_in[0];
  const int*   ei  = (const int*)d_in[1];
  const float* W1  = (const float*)d_in[2];
  const float* a1s = (const float*)d_in[3];
  const float* a1d = (const float*)d_in[4];
  const float* b1  = (const float*)d_in[5];
  const float* W2  = (const float*)d_in[6];
  const float* a2s = (const float*)d_in[7];
  const float* a2d = (const float*)d_in[8];
  const float* b2  = (const float*)d_in[9];
  const float* W3  = (const float*)d_in[10];
  const float* a3s = (const float*)d_in[11];
  const float* a3d = (const float*)d_in[12];
  const float* b3  = (const float*)d_in[13];

  const int N = in_sizes[0] / F_IN;
  const int E = in_sizes[1] / 2;
  const int Et = E + N;

  char* base = (char*)d_ws;
  size_t off = 0;
  auto alloc = [&](size_t bytes) {
    void* p = base + off;
    off = (off + bytes + 255) & ~(size_t)255;
    return p;
  };
  float* A      = (float*)alloc((size_t)N * F * sizeof(float));
  float* Bbuf   = (float*)alloc((size_t)N * F * sizeof(float));
  float* escore = (float*)alloc((size_t)Et * 4 * sizeof(float));
  int*   src_s  = (int*)alloc((size_t)Et * sizeof(int));
  int*   dst_s  = (int*)alloc((size_t)Et * sizeof(int));
  int*   counts = (int*)alloc((size_t)N * sizeof(int));
  int*   offs   = (int*)alloc((size_t)(N + 1) * sizeof(int));
  int*   cursor = (int*)alloc((size_t)N * sizeof(int));
  float* as     = (float*)alloc((size_t)N * 4 * sizeof(float));
  float* ad     = (float*)alloc((size_t)N * 4 * sizeof(float));
  float* m_buf  = (float*)alloc((size_t)N * 4 * sizeof(float));
  float* d_buf  = (float*)alloc((size_t)N * 4 * sizeof(float));
  float* h3     = (float*)alloc((size_t)N * 4 * sizeof(float));

  // ---- CSR build (graph fixed across layers) ----
  hipMemsetAsync(counts, 0, (size_t)N * sizeof(int), stream);
  {
    int g = (Et + 255) / 256;
    hipLaunchKernelGGL(hist_kernel, dim3(g), dim3(256), 0, stream, ei, counts, N, E);
    hipLaunchKernelGGL(scan_kernel, dim3(1), dim3(1024), 0, stream, counts, offs, cursor, N);
    hipLaunchKernelGGL(scatter_kernel, dim3(g), dim3(256), 0, stream, ei, cursor, src_s, dst_s, N, E);
    hipLaunchKernelGGL(segsort_kernel, dim3((N + 255) / 256), dim3(256), 0, stream, src_s, offs, N);
  }

  int edgeGrid = (Et + 255) / 256;
  int nhGrid   = (N * 4 + 255) / 256;

  // ---- layer 1 ----
  hipLaunchKernelGGL(gemm30_kernel, dim3((N + 15) / 16), dim3(256), 0, stream, x, W1, A, N);
  hipLaunchKernelGGL(alpha_kernel, dim3(N), dim3(128), 0, stream, A, a1s, a1d, as, ad);
  hipLaunchKernelGGL(edge_score_kernel, dim3(edgeGrid), dim3(256), 0, stream, as, ad, src_s, dst_s, escore, Et);
  hipLaunchKernelGGL(softmax_stats_kernel, dim3(nhGrid), dim3(256), 0, stream, escore, offs, m_buf, d_buf, N);
  hipLaunchKernelGGL((aggregate_kernel<true>), dim3(N), dim3(128), 0, stream, A, escore, src_s, offs, m_buf, d_buf, b1, Bbuf);

  // ---- layer 2 ----
  hipLaunchKernelGGL(gemm512_kernel, dim3((N + 15) / 16), dim3(256), 0, stream, Bbuf, W2, A, N);
  hipLaunchKernelGGL(alpha_kernel, dim3(N), dim3(128), 0, stream, A, a2s, a2d, as, ad);
  hipLaunchKernelGGL(edge_score_kernel, dim3(edgeGrid), dim3(256), 0, stream, as, ad, src_s, dst_s, escore, Et);
  hipLaunchKernelGGL(softmax_stats_kernel, dim3(nhGrid), dim3(256), 0, stream, escore, offs, m_buf, d_buf, N);
  hipLaunchKernelGGL((aggregate_kernel<true>), dim3(N), dim3(128), 0, stream, A, escore, src_s, offs, m_buf, d_buf, b2, Bbuf);

  // ---- layer 3 ----
  hipLaunchKernelGGL(gemm3_kernel, dim3((N + 3) / 4), dim3(256), 0, stream, Bbuf, W3, h3, N);
  hipLaunchKernelGGL(alpha3_kernel, dim3(nhGrid), dim3(256), 0, stream, h3, a3s, a3d, as, ad, N);
  hipLaunchKernelGGL(edge_score_kernel, dim3(edgeGrid), dim3(256), 0, stream, as, ad, src_s, dst_s, escore, Et);
  hipLaunchKernelGGL(softmax_stats_kernel, dim3(nhGrid), dim3(256), 0, stream, escore, offs, m_buf, d_buf, N);
  hipLaunchKernelGGL(aggregate3_kernel, dim3(nhGrid), dim3(256), 0, stream, h3, escore, src_s, offs, m_buf, d_buf, b3, (float*)d_out, N);
}

// Round 8
// 1044.605 us; speedup vs baseline: 6.2758x; 1.2797x over previous
//
#include <hip/hip_runtime.h>

#define NEG_SLOPE 0.2f

constexpr int F = 512;    // heads * channels
constexpr int F_IN = 30;

typedef short bfrag __attribute__((ext_vector_type(8)));   // 8 bf16 = 4 VGPR
typedef float f32x4 __attribute__((ext_vector_type(4)));

__device__ __forceinline__ unsigned short bf16_rne(float v) {
  unsigned u = __float_as_uint(v);
  u += 0x7FFF + ((u >> 16) & 1);
  return (unsigned short)(u >> 16);
}
__device__ __forceinline__ float bf16f(unsigned short h) {
  return __uint_as_float(((unsigned)h) << 16);
}

// ---------------- CSR build ----------------

__global__ void hist_kernel(const int* __restrict__ ei, int* __restrict__ counts,
                            int N, int E) {
  int e = blockIdx.x * blockDim.x + threadIdx.x;
  int Et = E + N;
  if (e >= Et) return;
  int d = (e < E) ? ei[E + e] : (e - E);
  atomicAdd(&counts[d], 1);
}

__global__ void scan_kernel(const int* __restrict__ counts, int* __restrict__ offsets,
                            int* __restrict__ cursor, int n) {
  __shared__ int lds[1024];
  __shared__ int carry_s;
  if (threadIdx.x == 0) carry_s = 0;
  __syncthreads();
  for (int base = 0; base < n; base += 1024) {
    int i = base + threadIdx.x;
    int v = (i < n) ? counts[i] : 0;
    lds[threadIdx.x] = v;
    __syncthreads();
    for (int off = 1; off < 1024; off <<= 1) {
      int t = (threadIdx.x >= off) ? lds[threadIdx.x - off] : 0;
      __syncthreads();
      lds[threadIdx.x] += t;
      __syncthreads();
    }
    int excl = lds[threadIdx.x] - v;
    if (i < n) { int o = carry_s + excl; offsets[i] = o; cursor[i] = o; }
    __syncthreads();
    if (threadIdx.x == 1023) carry_s += lds[1023];
    __syncthreads();
  }
  if (threadIdx.x == 0) offsets[n] = carry_s;
}

__global__ void scatter_kernel(const int* __restrict__ ei, int* __restrict__ cursor,
                               int* __restrict__ src_s, int* __restrict__ dst_s,
                               int N, int E) {
  int e = blockIdx.x * blockDim.x + threadIdx.x;
  int Et = E + N;
  if (e >= Et) return;
  int s, d;
  if (e < E) { s = ei[e]; d = ei[E + e]; } else { s = e - E; d = e - E; }
  int p = atomicAdd(&cursor[d], 1);
  src_s[p] = s;
  dst_s[p] = d;
}

// Canonicalize within-segment order for determinism across graph replays.
__global__ void segsort_kernel(int* __restrict__ src_s, const int* __restrict__ off, int N) {
  int n = blockIdx.x * blockDim.x + threadIdx.x;
  if (n >= N) return;
  int p0 = off[n], p1 = off[n + 1];
  for (int i = p0 + 1; i < p1; ++i) {
    int key = src_s[i];
    int j = i - 1;
    while (j >= p0 && src_s[j] > key) { src_s[j + 1] = src_s[j]; --j; }
    src_s[j + 1] = key;
  }
}

// ---------------- GEMM (layer1, K=30):  out[N,512] = X[N,30] @ W[30,512] ----

__global__ void gemm30_kernel(const float* __restrict__ X, const float* __restrict__ W,
                              float* __restrict__ out, int N) {
  __shared__ float xs[16][F_IN];
  int row0 = blockIdx.x * 16;
  int tid = threadIdx.x;
  for (int i = tid; i < 16 * F_IN; i += 256) {
    int r = i / F_IN, k = i - r * F_IN;
    int row = row0 + r;
    xs[r][k] = (row < N) ? X[(size_t)row * F_IN + k] : 0.f;
  }
  __syncthreads();
  int cg = tid & 127;
  int rg = tid >> 7;
  int c0 = cg * 4;
  float4 acc[8];
#pragma unroll
  for (int r = 0; r < 8; ++r) acc[r] = make_float4(0.f, 0.f, 0.f, 0.f);
#pragma unroll 2
  for (int k = 0; k < F_IN; ++k) {
    float4 w = *(const float4*)(W + (size_t)k * F + c0);
#pragma unroll
    for (int r = 0; r < 8; ++r) {
      float xv = xs[rg * 8 + r][k];
      acc[r].x += xv * w.x; acc[r].y += xv * w.y;
      acc[r].z += xv * w.z; acc[r].w += xv * w.w;
    }
  }
#pragma unroll
  for (int r = 0; r < 8; ++r) {
    int row = row0 + rg * 8 + r;
    if (row < N) *(float4*)(out + (size_t)row * F + c0) = acc[r];
  }
}

// ---------------- W2 split + transpose:  Wt_hi/Wt_lo[col][k] = split(W[k][col])

__global__ void wsplit_kernel(const float* __restrict__ W,
                              unsigned short* __restrict__ Wth,
                              unsigned short* __restrict__ Wtl) {
  __shared__ float t[64][65];
  int bx = blockIdx.x & 7, by = blockIdx.x >> 3;
  int tid = threadIdx.x;
#pragma unroll
  for (int i = 0; i < 16; ++i) {
    int idx = tid + i * 256;
    int r = idx >> 6, c = idx & 63;
    t[r][c] = W[(size_t)(by * 64 + r) * 512 + bx * 64 + c];
  }
  __syncthreads();
#pragma unroll
  for (int i = 0; i < 16; ++i) {
    int idx = tid + i * 256;
    int r = idx >> 6, c = idx & 63;
    float v = t[c][r];                       // Wt[col][k] = W[k][col]
    unsigned short hi = bf16_rne(v);
    unsigned short lo = bf16_rne(v - bf16f(hi));
    size_t o = (size_t)(bx * 64 + r) * 512 + by * 64 + c;
    Wth[o] = hi; Wtl[o] = lo;
  }
}

// ---------------- GEMM (layer2, K=512) via MFMA, fp32-emulated with bf16 hi/lo
// tile 128x128, 256 threads = 4 waves (2x2), BK=32, 16x16x32 bf16 MFMA.
// X*W ~= Xhi*Whi + Xhi*Wlo + Xlo*Whi  (rel err ~2^-16)
// LDS: Ahi[128][32] | Alo | Bt_hi[128cols][32k] | Bt_lo, 8KB each, 16B-chunk
// swizzle (chunk ^= (row>>1)&3) for conflict-free ds_read_b128.

__global__ void gemm512_mfma(const unsigned short* __restrict__ Xhi,
                             const unsigned short* __restrict__ Xlo,
                             const unsigned short* __restrict__ Wth,
                             const unsigned short* __restrict__ Wtl,
                             float* __restrict__ out, int N) {
  __shared__ int4 lds4[2048];               // 32 KB
  char* lds = (char*)lds4;
  const int tid = threadIdx.x;
  const int wid = tid >> 6;
  const int lane = tid & 63;
  const int row0 = blockIdx.x * 128;
  const int col0 = blockIdx.y * 128;
  const int wr = wid >> 1, wc = wid & 1;

  // staging: wave wid stages {0:Ahi,1:Alo,2:Bhi,3:Blo}; LDS dest is linear,
  // the swizzle lives in the per-lane GLOBAL source chunk index.
  const unsigned short* sb = (wid == 0) ? Xhi : (wid == 1) ? Xlo : (wid == 2) ? Wth : Wtl;
  const int tile0 = (wid < 2) ? row0 : col0;
  const int chunk = (lane & 3) ^ ((lane >> 3) & 3);
  const unsigned short* lanesrc = sb + (size_t)(tile0 + (lane >> 2)) * 512 + chunk * 8;
  char* ldst = lds + wid * 8192;            // wave-uniform base

  // ds_read byte offsets (loop-invariant): row r, k-group g=lane>>4
  const int g = lane >> 4;
  int aoff[4], boff[4];
#pragma unroll
  for (int m = 0; m < 4; ++m) {
    int r = wr * 64 + m * 16 + (lane & 15);
    aoff[m] = r * 64 + ((g ^ ((r >> 1) & 3)) << 4);
    int c = wc * 64 + m * 16 + (lane & 15);
    boff[m] = c * 64 + ((g ^ ((c >> 1) & 3)) << 4);
  }

  f32x4 acc[4][4];
#pragma unroll
  for (int m = 0; m < 4; ++m)
#pragma unroll
    for (int n = 0; n < 4; ++n) acc[m][n] = f32x4{0.f, 0.f, 0.f, 0.f};

  for (int kc = 0; kc < 16; ++kc) {
#pragma unroll
    for (int i = 0; i < 8; ++i) {
      __builtin_amdgcn_global_load_lds(
          (const __attribute__((address_space(1))) void*)(lanesrc + i * 8192 + kc * 32),
          (__attribute__((address_space(3))) void*)(ldst + i * 1024), 16, 0, 0);
    }
    __syncthreads();   // drains vmcnt before barrier (compiler-inserted)
    bfrag ah[4], al[4], bh[4], bl[4];
#pragma unroll
    for (int m = 0; m < 4; ++m) {
      ah[m] = *(const bfrag*)(lds + aoff[m]);
      al[m] = *(const bfrag*)(lds + 8192 + aoff[m]);
      bh[m] = *(const bfrag*)(lds + 16384 + boff[m]);
      bl[m] = *(const bfrag*)(lds + 24576 + boff[m]);
    }
#pragma unroll
    for (int m = 0; m < 4; ++m)
#pragma unroll
      for (int n = 0; n < 4; ++n) {
        acc[m][n] = __builtin_amdgcn_mfma_f32_16x16x32_bf16(al[m], bh[n], acc[m][n], 0, 0, 0);
        acc[m][n] = __builtin_amdgcn_mfma_f32_16x16x32_bf16(ah[m], bl[n], acc[m][n], 0, 0, 0);
        acc[m][n] = __builtin_amdgcn_mfma_f32_16x16x32_bf16(ah[m], bh[n], acc[m][n], 0, 0, 0);
      }
    __syncthreads();
  }

  // C/D layout: col = lane&15, row = (lane>>4)*4 + reg  [m89-verified]
  const int crow = (lane >> 4) * 4, ccol = lane & 15;
#pragma unroll
  for (int m = 0; m < 4; ++m) {
    int Rb = row0 + wr * 64 + m * 16 + crow;
#pragma unroll
    for (int n = 0; n < 4; ++n) {
      int C = col0 + wc * 64 + n * 16 + ccol;
#pragma unroll
      for (int q = 0; q < 4; ++q) {
        int R = Rb + q;
        if (R < N) out[(size_t)R * F + C] = acc[m][n][q];
      }
    }
  }
}

// GEMM for layer3: out[N,4] = X[N,512] @ W3[512,4]; one wave per node
__global__ void gemm3_kernel(const float* __restrict__ X, const float* __restrict__ W3,
                             float* __restrict__ h3, int N) {
  int n = blockIdx.x * 4 + (threadIdx.x >> 6);
  int lane = threadIdx.x & 63;
  if (n >= N) return;
  float acc[4] = {0.f, 0.f, 0.f, 0.f};
  for (int k = lane; k < F; k += 64) {
    float xv = X[(size_t)n * F + k];
#pragma unroll
    for (int j = 0; j < 4; ++j) acc[j] += xv * W3[k * 4 + j];
  }
#pragma unroll
  for (int j = 0; j < 4; ++j)
    for (int off = 32; off > 0; off >>= 1) acc[j] += __shfl_down(acc[j], off);
  if (lane == 0) {
    float4 o; o.x = acc[0]; o.y = acc[1]; o.z = acc[2]; o.w = acc[3];
    *(float4*)(h3 + (size_t)n * 4) = o;
  }
}

// ---------------- alpha dots ----------------

__global__ void alpha_kernel(const float* __restrict__ h, const float* __restrict__ asrc,
                             const float* __restrict__ adst, float* __restrict__ as,
                             float* __restrict__ ad) {
  int n = blockIdx.x;
  int tid = threadIdx.x;
  int c0 = tid * 4;
  float4 hv = *(const float4*)(h + (size_t)n * F + c0);
  float4 sa = *(const float4*)(asrc + c0);
  float4 da = *(const float4*)(adst + c0);
  float ps = hv.x * sa.x + hv.y * sa.y + hv.z * sa.z + hv.w * sa.w;
  float pd = hv.x * da.x + hv.y * da.y + hv.z * da.z + hv.w * da.w;
#pragma unroll
  for (int off = 16; off > 0; off >>= 1) {
    ps += __shfl_down(ps, off);
    pd += __shfl_down(pd, off);
  }
  if ((tid & 31) == 0) {
    int head = tid >> 5;
    as[n * 4 + head] = ps;
    ad[n * 4 + head] = pd;
  }
}

__global__ void alpha3_kernel(const float* __restrict__ h3, const float* __restrict__ a3s,
                              const float* __restrict__ a3d, float* __restrict__ as,
                              float* __restrict__ ad, int N) {
  int t = blockIdx.x * blockDim.x + threadIdx.x;
  if (t >= N * 4) return;
  int hh = t & 3;
  float v = h3[t];
  as[t] = v * a3s[hh];
  ad[t] = v * a3d[hh];
}

// ---------------- edge scores ----------------

__device__ __forceinline__ float leaky(float v) { return v > 0.f ? v : NEG_SLOPE * v; }

__global__ void edge_score_kernel(const float* __restrict__ as, const float* __restrict__ ad,
                                  const int* __restrict__ src_s, const int* __restrict__ dst_s,
                                  float* __restrict__ escore, int Et) {
  int p = blockIdx.x * blockDim.x + threadIdx.x;
  if (p >= Et) return;
  int s = src_s[p], d = dst_s[p];
  float4 a = *(const float4*)(as + (size_t)s * 4);
  float4 b = *(const float4*)(ad + (size_t)d * 4);
  float4 e;
  e.x = leaky(a.x + b.x);
  e.y = leaky(a.y + b.y);
  e.z = leaky(a.z + b.z);
  e.w = leaky(a.w + b.w);
  *(float4*)(escore + (size_t)p * 4) = e;
}

// ---------------- segment softmax stats ----------------

__global__ void softmax_stats_kernel(const float* __restrict__ escore, const int* __restrict__ off,
                                     float* __restrict__ m_out, float* __restrict__ d_out_, int N) {
  int t = blockIdx.x * blockDim.x + threadIdx.x;
  if (t >= N * 4) return;
  int n = t >> 2, h = t & 3;
  int p0 = off[n], p1 = off[n + 1];
  float m = -1e30f, s = 0.f;
  for (int p = p0; p < p1; ++p) {
    float e = escore[(size_t)p * 4 + h];
    if (e > m) { s *= __expf(m - e); m = e; }
    s += __expf(e - m);
  }
  m_out[t] = m;
  d_out_[t] = s + 1e-16f;
}

// ---------------- aggregate: single pass, alpha inline ----------------
// SPLIT: write bf16 hi/lo (feeds MFMA GEMM) instead of fp32.

template <bool RELU, bool SPLIT>
__global__ void aggregate_kernel(const float* __restrict__ hsrc, const float* __restrict__ escore,
                                 const int* __restrict__ src_s, const int* __restrict__ off,
                                 const float* __restrict__ m_buf, const float* __restrict__ d_buf,
                                 const float* __restrict__ bias, float* __restrict__ out,
                                 unsigned short* __restrict__ oh, unsigned short* __restrict__ ol) {
  int n = blockIdx.x;
  int tid = threadIdx.x;
  int c0 = tid * 4;
  int head = tid >> 5;
  int p0 = off[n], p1 = off[n + 1];
  float mh = m_buf[n * 4 + head];
  float inv = 1.f / d_buf[n * 4 + head];
  float4 acc = make_float4(0.f, 0.f, 0.f, 0.f);
  for (int p = p0; p < p1; ++p) {
    float a = __expf(escore[(size_t)p * 4 + head] - mh) * inv;
    int s = src_s[p];
    float4 hv = *(const float4*)(hsrc + (size_t)s * F + c0);
    acc.x += a * hv.x; acc.y += a * hv.y;
    acc.z += a * hv.z; acc.w += a * hv.w;
  }
  float4 bv = *(const float4*)(bias + c0);
  acc.x += bv.x; acc.y += bv.y; acc.z += bv.z; acc.w += bv.w;
  if (RELU) {
    acc.x = fmaxf(acc.x, 0.f); acc.y = fmaxf(acc.y, 0.f);
    acc.z = fmaxf(acc.z, 0.f); acc.w = fmaxf(acc.w, 0.f);
  }
  if (SPLIT) {
    ushort4 hv4, lv4;
    hv4.x = bf16_rne(acc.x); lv4.x = bf16_rne(acc.x - bf16f(hv4.x));
    hv4.y = bf16_rne(acc.y); lv4.y = bf16_rne(acc.y - bf16f(hv4.y));
    hv4.z = bf16_rne(acc.z); lv4.z = bf16_rne(acc.z - bf16f(hv4.z));
    hv4.w = bf16_rne(acc.w); lv4.w = bf16_rne(acc.w - bf16f(hv4.w));
    *(ushort4*)(oh + (size_t)n * F + c0) = hv4;
    *(ushort4*)(ol + (size_t)n * F + c0) = lv4;
  } else {
    *(float4*)(out + (size_t)n * F + c0) = acc;
  }
}

__global__ void aggregate3_kernel(const float* __restrict__ h3, const float* __restrict__ escore,
                                  const int* __restrict__ src_s, const int* __restrict__ off,
                                  const float* __restrict__ m_buf, const float* __restrict__ d_buf,
                                  const float* __restrict__ b3, float* __restrict__ out, int N) {
  int t = blockIdx.x * blockDim.x + threadIdx.x;
  if (t >= N * 4) return;
  int n = t >> 2, head = t & 3;
  int p0 = off[n], p1 = off[n + 1];
  float mh = m_buf[t];
  float inv = 1.f / d_buf[t];
  float acc = 0.f;
  for (int p = p0; p < p1; ++p) {
    float a = __expf(escore[(size_t)p * 4 + head] - mh) * inv;
    acc += a * h3[(size_t)src_s[p] * 4 + head];
  }
  acc += __shfl_down(acc, 1);
  acc += __shfl_down(acc, 2);
  if (head == 0) out[n] = acc * 0.25f + b3[0];
}

// ---------------- host orchestration ----------------

extern "C" void kernel_launch(void* const* d_in, const int* in_sizes, int n_in,
                              void* d_out, int out_size, void* d_ws, size_t ws_size,
                              hipStream_t stream) {
  const float* x   = (const float*)d_in[0];
  const int*   ei  = (const int*)d_in[1];
  const float* W1  = (const float*)d_in[2];
  const float* a1s = (const float*)d_in[3];
  const float* a1d = (const float*)d_in[4];
  const float* b1  = (const float*)d_in[5];
  const float* W2  = (const float*)d_in[6];
  const float* a2s = (const float*)d_in[7];
  const float* a2d = (const float*)d_in[8];
  const float* b2  = (const float*)d_in[9];
  const float* W3  = (const float*)d_in[10];
  const float* a3s = (const float*)d_in[11];
  const float* a3d = (const float*)d_in[12];
  const float* b3  = (const float*)d_in[13];

  const int N = in_sizes[0] / F_IN;
  const int E = in_sizes[1] / 2;
  const int Et = E + N;
  const int Npad = (N + 127) & ~127;

  char* base = (char*)d_ws;
  size_t off = 0;
  auto alloc = [&](size_t bytes) {
    void* p = base + off;
    off = (off + bytes + 255) & ~(size_t)255;
    return p;
  };
  float* A      = (float*)alloc((size_t)N * F * sizeof(float));
  // U region: serves as {Xhi,Xlo} (layer1 split out -> gemm512 in), then as
  // Bbuf (layer2 aggregate out -> gemm3 in). Lifetimes don't overlap.
  float* U      = (float*)alloc((size_t)Npad * F * sizeof(float));
  unsigned short* Xhi = (unsigned short*)U;
  unsigned short* Xlo = Xhi + (size_t)Npad * F;
  float* Bbuf   = U;
  float* escore = (float*)alloc((size_t)Et * 4 * sizeof(float));
  int*   src_s  = (int*)alloc((size_t)Et * sizeof(int));
  int*   dst_s  = (int*)alloc((size_t)Et * sizeof(int));
  int*   counts = (int*)alloc((size_t)N * sizeof(int));
  int*   offs   = (int*)alloc((size_t)(N + 1) * sizeof(int));
  int*   cursor = (int*)alloc((size_t)N * sizeof(int));
  float* as     = (float*)alloc((size_t)N * 4 * sizeof(float));
  float* ad     = (float*)alloc((size_t)N * 4 * sizeof(float));
  float* m_buf  = (float*)alloc((size_t)N * 4 * sizeof(float));
  float* d_buf  = (float*)alloc((size_t)N * 4 * sizeof(float));
  float* h3     = (float*)alloc((size_t)N * 4 * sizeof(float));
  unsigned short* Wth = (unsigned short*)alloc((size_t)512 * 512 * sizeof(unsigned short));
  unsigned short* Wtl = (unsigned short*)alloc((size_t)512 * 512 * sizeof(unsigned short));

  // ---- CSR build + W2 split (both independent of layer outputs) ----
  hipMemsetAsync(counts, 0, (size_t)N * sizeof(int), stream);
  {
    int gg = (Et + 255) / 256;
    hipLaunchKernelGGL(hist_kernel, dim3(gg), dim3(256), 0, stream, ei, counts, N, E);
    hipLaunchKernelGGL(scan_kernel, dim3(1), dim3(1024), 0, stream, counts, offs, cursor, N);
    hipLaunchKernelGGL(scatter_kernel, dim3(gg), dim3(256), 0, stream, ei, cursor, src_s, dst_s, N, E);
    hipLaunchKernelGGL(segsort_kernel, dim3((N + 255) / 256), dim3(256), 0, stream, src_s, offs, N);
    hipLaunchKernelGGL(wsplit_kernel, dim3(64), dim3(256), 0, stream, W2, Wth, Wtl);
  }

  int edgeGrid = (Et + 255) / 256;
  int nhGrid   = (N * 4 + 255) / 256;

  // ---- layer 1 ----
  hipLaunchKernelGGL(gemm30_kernel, dim3((N + 15) / 16), dim3(256), 0, stream, x, W1, A, N);
  hipLaunchKernelGGL(alpha_kernel, dim3(N), dim3(128), 0, stream, A, a1s, a1d, as, ad);
  hipLaunchKernelGGL(edge_score_kernel, dim3(edgeGrid), dim3(256), 0, stream, as, ad, src_s, dst_s, escore, Et);
  hipLaunchKernelGGL(softmax_stats_kernel, dim3(nhGrid), dim3(256), 0, stream, escore, offs, m_buf, d_buf, N);
  hipLaunchKernelGGL((aggregate_kernel<true, true>), dim3(N), dim3(128), 0, stream,
                     A, escore, src_s, offs, m_buf, d_buf, b1, (float*)nullptr, Xhi, Xlo);

  // ---- layer 2 ----
  hipLaunchKernelGGL(gemm512_mfma, dim3((N + 127) / 128, 4), dim3(256), 0, stream,
                     Xhi, Xlo, Wth, Wtl, A, N);
  hipLaunchKernelGGL(alpha_kernel, dim3(N), dim3(128), 0, stream, A, a2s, a2d, as, ad);
  hipLaunchKernelGGL(edge_score_kernel, dim3(edgeGrid), dim3(256), 0, stream, as, ad, src_s, dst_s, escore, Et);
  hipLaunchKernelGGL(softmax_stats_kernel, dim3(nhGrid), dim3(256), 0, stream, escore, offs, m_buf, d_buf, N);
  hipLaunchKernelGGL((aggregate_kernel<true, false>), dim3(N), dim3(128), 0, stream,
                     A, escore, src_s, offs, m_buf, d_buf, b2, Bbuf,
                     (unsigned short*)nullptr, (unsigned short*)nullptr);

  // ---- layer 3 ----
  hipLaunchKernelGGL(gemm3_kernel, dim3((N + 3) / 4), dim3(256), 0, stream, Bbuf, W3, h3, N);
  hipLaunchKernelGGL(alpha3_kernel, dim3(nhGrid), dim3(256), 0, stream, h3, a3s, a3d, as, ad, N);
  hipLaunchKernelGGL(edge_score_kernel, dim3(edgeGrid), dim3(256), 0, stream, as, ad, src_s, dst_s, escore, Et);
  hipLaunchKernelGGL(softmax_stats_kernel, dim3(nhGrid), dim3(256), 0, stream, escore, offs, m_buf, d_buf, N);
  hipLaunchKernelGGL(aggregate3_kernel, dim3(nhGrid), dim3(256), 0, stream, h3, escore, src_s, offs, m_buf, d_buf, b3, (float*)d_out, N);
}

// Round 9
// 1018.719 us; speedup vs baseline: 6.4353x; 1.0254x over previous
//
#include <hip/hip_runtime.h>

#define NEG_SLOPE 0.2f

constexpr int F = 512;    // heads * channels
constexpr int F_IN = 30;

typedef short bfrag __attribute__((ext_vector_type(8)));   // 8 bf16 = 4 VGPR
typedef float f32x4 __attribute__((ext_vector_type(4)));

__device__ __forceinline__ unsigned short bf16_rne(float v) {
  unsigned u = __float_as_uint(v);
  u += 0x7FFF + ((u >> 16) & 1);
  return (unsigned short)(u >> 16);
}
__device__ __forceinline__ float bf16f(unsigned short h) {
  return __uint_as_float(((unsigned)h) << 16);
}

// ---------------- CSR build ----------------

__global__ void hist_kernel(const int* __restrict__ ei, int* __restrict__ counts,
                            int N, int E) {
  int e = blockIdx.x * blockDim.x + threadIdx.x;
  int Et = E + N;
  if (e >= Et) return;
  int d = (e < E) ? ei[E + e] : (e - E);
  atomicAdd(&counts[d], 1);
}

// 1024-thread single-block scan, shuffle-based (3 barriers per 1024-chunk)
__global__ void scan_kernel(const int* __restrict__ counts, int* __restrict__ offsets,
                            int* __restrict__ cursor, int n) {
  __shared__ int wsum[16];
  __shared__ int carry_s;
  int tid = threadIdx.x;
  int lane = tid & 63, wid = tid >> 6;
  if (tid == 0) carry_s = 0;
  __syncthreads();
  for (int base = 0; base < n; base += 1024) {
    int i = base + tid;
    int v = (i < n) ? counts[i] : 0;
    int x = v;
#pragma unroll
    for (int d = 1; d < 64; d <<= 1) {
      int t2 = __shfl_up(x, d);
      if (lane >= d) x += t2;
    }
    if (lane == 63) wsum[wid] = x;
    __syncthreads();
    if (wid == 0) {
      int ws = (lane < 16) ? wsum[lane] : 0;
#pragma unroll
      for (int d = 1; d < 16; d <<= 1) {
        int t2 = __shfl_up(ws, d);
        if (lane >= d) ws += t2;
      }
      if (lane < 16) wsum[lane] = ws;
    }
    __syncthreads();
    int wpre = (wid > 0) ? wsum[wid - 1] : 0;
    int excl = carry_s + wpre + x - v;
    if (i < n) { offsets[i] = excl; cursor[i] = excl; }
    __syncthreads();                 // all reads of carry_s/wsum done
    if (tid == 0) carry_s += wsum[15];
    __syncthreads();
  }
  if (threadIdx.x == 0) offsets[n] = carry_s;
}

__global__ void scatter_kernel(const int* __restrict__ ei, int* __restrict__ cursor,
                               int* __restrict__ src_s, int N, int E) {
  int e = blockIdx.x * blockDim.x + threadIdx.x;
  int Et = E + N;
  if (e >= Et) return;
  int s, d;
  if (e < E) { s = ei[e]; d = ei[E + e]; } else { s = e - E; d = e - E; }
  int p = atomicAdd(&cursor[d], 1);
  src_s[p] = s;
}

// Canonicalize within-segment order for determinism across graph replays.
__global__ void segsort_kernel(int* __restrict__ src_s, const int* __restrict__ off, int N) {
  int n = blockIdx.x * blockDim.x + threadIdx.x;
  if (n >= N) return;
  int p0 = off[n], p1 = off[n + 1];
  for (int i = p0 + 1; i < p1; ++i) {
    int key = src_s[i];
    int j = i - 1;
    while (j >= p0 && src_s[j] > key) { src_s[j + 1] = src_s[j]; --j; }
    src_s[j + 1] = key;
  }
}

// ---------------- GEMM (layer1, K=30):  out[N,512] = X[N,30] @ W[30,512] ----

__global__ void gemm30_kernel(const float* __restrict__ X, const float* __restrict__ W,
                              float* __restrict__ out, int N) {
  __shared__ float xs[16][F_IN];
  int row0 = blockIdx.x * 16;
  int tid = threadIdx.x;
  for (int i = tid; i < 16 * F_IN; i += 256) {
    int r = i / F_IN, k = i - r * F_IN;
    int row = row0 + r;
    xs[r][k] = (row < N) ? X[(size_t)row * F_IN + k] : 0.f;
  }
  __syncthreads();
  int cg = tid & 127;
  int rg = tid >> 7;
  int c0 = cg * 4;
  float4 acc[8];
#pragma unroll
  for (int r = 0; r < 8; ++r) acc[r] = make_float4(0.f, 0.f, 0.f, 0.f);
#pragma unroll 2
  for (int k = 0; k < F_IN; ++k) {
    float4 w = *(const float4*)(W + (size_t)k * F + c0);
#pragma unroll
    for (int r = 0; r < 8; ++r) {
      float xv = xs[rg * 8 + r][k];
      acc[r].x += xv * w.x; acc[r].y += xv * w.y;
      acc[r].z += xv * w.z; acc[r].w += xv * w.w;
    }
  }
#pragma unroll
  for (int r = 0; r < 8; ++r) {
    int row = row0 + rg * 8 + r;
    if (row < N) *(float4*)(out + (size_t)row * F + c0) = acc[r];
  }
}

// ---------------- W2 split + transpose:  Wt_hi/Wt_lo[col][k] = split(W[k][col])

__global__ void wsplit_kernel(const float* __restrict__ W,
                              unsigned short* __restrict__ Wth,
                              unsigned short* __restrict__ Wtl) {
  __shared__ float t[64][65];
  int bx = blockIdx.x & 7, by = blockIdx.x >> 3;
  int tid = threadIdx.x;
#pragma unroll
  for (int i = 0; i < 16; ++i) {
    int idx = tid + i * 256;
    int r = idx >> 6, c = idx & 63;
    t[r][c] = W[(size_t)(by * 64 + r) * 512 + bx * 64 + c];
  }
  __syncthreads();
#pragma unroll
  for (int i = 0; i < 16; ++i) {
    int idx = tid + i * 256;
    int r = idx >> 6, c = idx & 63;
    float v = t[c][r];                       // Wt[col][k] = W[k][col]
    unsigned short hi = bf16_rne(v);
    unsigned short lo = bf16_rne(v - bf16f(hi));
    size_t o = (size_t)(bx * 64 + r) * 512 + by * 64 + c;
    Wth[o] = hi; Wtl[o] = lo;
  }
}

// ---------------- GEMM (layer2, K=512) via MFMA, fp32-emulated with bf16 hi/lo

__global__ void gemm512_mfma(const unsigned short* __restrict__ Xhi,
                             const unsigned short* __restrict__ Xlo,
                             const unsigned short* __restrict__ Wth,
                             const unsigned short* __restrict__ Wtl,
                             float* __restrict__ out, int N) {
  __shared__ int4 lds4[2048];               // 32 KB
  char* lds = (char*)lds4;
  const int tid = threadIdx.x;
  const int wid = tid >> 6;
  const int lane = tid & 63;
  const int row0 = blockIdx.x * 128;
  const int col0 = blockIdx.y * 128;
  const int wr = wid >> 1, wc = wid & 1;

  const unsigned short* sb = (wid == 0) ? Xhi : (wid == 1) ? Xlo : (wid == 2) ? Wth : Wtl;
  const int tile0 = (wid < 2) ? row0 : col0;
  const int chunk = (lane & 3) ^ ((lane >> 3) & 3);
  const unsigned short* lanesrc = sb + (size_t)(tile0 + (lane >> 2)) * 512 + chunk * 8;
  char* ldst = lds + wid * 8192;            // wave-uniform base

  const int g = lane >> 4;
  int aoff[4], boff[4];
#pragma unroll
  for (int m = 0; m < 4; ++m) {
    int r = wr * 64 + m * 16 + (lane & 15);
    aoff[m] = r * 64 + ((g ^ ((r >> 1) & 3)) << 4);
    int c = wc * 64 + m * 16 + (lane & 15);
    boff[m] = c * 64 + ((g ^ ((c >> 1) & 3)) << 4);
  }

  f32x4 acc[4][4];
#pragma unroll
  for (int m = 0; m < 4; ++m)
#pragma unroll
    for (int n = 0; n < 4; ++n) acc[m][n] = f32x4{0.f, 0.f, 0.f, 0.f};

  for (int kc = 0; kc < 16; ++kc) {
#pragma unroll
    for (int i = 0; i < 8; ++i) {
      __builtin_amdgcn_global_load_lds(
          (const __attribute__((address_space(1))) void*)(lanesrc + i * 8192 + kc * 32),
          (__attribute__((address_space(3))) void*)(ldst + i * 1024), 16, 0, 0);
    }
    __syncthreads();
    bfrag ah[4], al[4], bh[4], bl[4];
#pragma unroll
    for (int m = 0; m < 4; ++m) {
      ah[m] = *(const bfrag*)(lds + aoff[m]);
      al[m] = *(const bfrag*)(lds + 8192 + aoff[m]);
      bh[m] = *(const bfrag*)(lds + 16384 + boff[m]);
      bl[m] = *(const bfrag*)(lds + 24576 + boff[m]);
    }
#pragma unroll
    for (int m = 0; m < 4; ++m)
#pragma unroll
      for (int n = 0; n < 4; ++n) {
        acc[m][n] = __builtin_amdgcn_mfma_f32_16x16x32_bf16(al[m], bh[n], acc[m][n], 0, 0, 0);
        acc[m][n] = __builtin_amdgcn_mfma_f32_16x16x32_bf16(ah[m], bl[n], acc[m][n], 0, 0, 0);
        acc[m][n] = __builtin_amdgcn_mfma_f32_16x16x32_bf16(ah[m], bh[n], acc[m][n], 0, 0, 0);
      }
    __syncthreads();
  }

  const int crow = (lane >> 4) * 4, ccol = lane & 15;
#pragma unroll
  for (int m = 0; m < 4; ++m) {
    int Rb = row0 + wr * 64 + m * 16 + crow;
#pragma unroll
    for (int n = 0; n < 4; ++n) {
      int C = col0 + wc * 64 + n * 16 + ccol;
#pragma unroll
      for (int q = 0; q < 4; ++q) {
        int R = Rb + q;
        if (R < N) out[(size_t)R * F + C] = acc[m][n][q];
      }
    }
  }
}

// GEMM for layer3: out[N,4] = X[N,512] @ W3[512,4]; one wave per node
__global__ void gemm3_kernel(const float* __restrict__ X, const float* __restrict__ W3,
                             float* __restrict__ h3, int N) {
  int n = blockIdx.x * 4 + (threadIdx.x >> 6);
  int lane = threadIdx.x & 63;
  if (n >= N) return;
  float acc[4] = {0.f, 0.f, 0.f, 0.f};
  for (int k = lane; k < F; k += 64) {
    float xv = X[(size_t)n * F + k];
#pragma unroll
    for (int j = 0; j < 4; ++j) acc[j] += xv * W3[k * 4 + j];
  }
#pragma unroll
  for (int j = 0; j < 4; ++j)
    for (int off = 32; off > 0; off >>= 1) acc[j] += __shfl_down(acc[j], off);
  if (lane == 0) {
    float4 o; o.x = acc[0]; o.y = acc[1]; o.z = acc[2]; o.w = acc[3];
    *(float4*)(h3 + (size_t)n * 4) = o;
  }
}

// ---------------- alpha dots ----------------

__global__ void alpha_kernel(const float* __restrict__ h, const float* __restrict__ asrc,
                             const float* __restrict__ adst, float* __restrict__ as,
                             float* __restrict__ ad) {
  int n = blockIdx.x;
  int tid = threadIdx.x;
  int c0 = tid * 4;
  float4 hv = *(const float4*)(h + (size_t)n * F + c0);
  float4 sa = *(const float4*)(asrc + c0);
  float4 da = *(const float4*)(adst + c0);
  float ps = hv.x * sa.x + hv.y * sa.y + hv.z * sa.z + hv.w * sa.w;
  float pd = hv.x * da.x + hv.y * da.y + hv.z * da.z + hv.w * da.w;
#pragma unroll
  for (int off = 16; off > 0; off >>= 1) {
    ps += __shfl_down(ps, off);
    pd += __shfl_down(pd, off);
  }
  if ((tid & 31) == 0) {
    int head = tid >> 5;
    as[n * 4 + head] = ps;
    ad[n * 4 + head] = pd;
  }
}

__global__ void alpha3_kernel(const float* __restrict__ h3, const float* __restrict__ a3s,
                              const float* __restrict__ a3d, float* __restrict__ as,
                              float* __restrict__ ad, int N) {
  int t = blockIdx.x * blockDim.x + threadIdx.x;
  if (t >= N * 4) return;
  int hh = t & 3;
  float v = h3[t];
  as[t] = v * a3s[hh];
  ad[t] = v * a3d[hh];
}

// ---------------- fused edge score + segment softmax stats ----------------
// one thread per (node, head); the 4 head-lanes of a node read as[s] as one
// coalesced 16B line; computes e inline, writes escore, tracks online m/s.

__device__ __forceinline__ float leaky(float v) { return v > 0.f ? v : NEG_SLOPE * v; }

__global__ void edge_stats_kernel(const float* __restrict__ as, const float* __restrict__ ad,
                                  const int* __restrict__ src_s, const int* __restrict__ off,
                                  float* __restrict__ escore,
                                  float* __restrict__ m_out, float* __restrict__ d_out_, int N) {
  int t = blockIdx.x * blockDim.x + threadIdx.x;
  if (t >= N * 4) return;
  int n = t >> 2, h = t & 3;
  int p0 = off[n], p1 = off[n + 1];
  float adv = ad[n * 4 + h];
  float m = -1e30f, s = 0.f;
  for (int p = p0; p < p1; ++p) {
    int si = src_s[p];
    float e = leaky(as[si * 4 + h] + adv);
    escore[(size_t)p * 4 + h] = e;
    if (e > m) { s *= __expf(m - e); m = e; }
    s += __expf(e - m);
  }
  m_out[t] = m;
  d_out_[t] = s + 1e-16f;
}

// ---------------- aggregate: single pass, alpha inline ----------------

template <bool RELU, bool SPLIT>
__global__ void aggregate_kernel(const float* __restrict__ hsrc, const float* __restrict__ escore,
                                 const int* __restrict__ src_s, const int* __restrict__ off,
                                 const float* __restrict__ m_buf, const float* __restrict__ d_buf,
                                 const float* __restrict__ bias, float* __restrict__ out,
                                 unsigned short* __restrict__ oh, unsigned short* __restrict__ ol) {
  int n = blockIdx.x;
  int tid = threadIdx.x;
  int c0 = tid * 4;
  int head = tid >> 5;
  int p0 = off[n], p1 = off[n + 1];
  float mh = m_buf[n * 4 + head];
  float inv = 1.f / d_buf[n * 4 + head];
  float4 acc = make_float4(0.f, 0.f, 0.f, 0.f);
#pragma unroll 2
  for (int p = p0; p < p1; ++p) {
    float a = __expf(escore[(size_t)p * 4 + head] - mh) * inv;
    int s = src_s[p];
    float4 hv = *(const float4*)(hsrc + (size_t)s * F + c0);
    acc.x += a * hv.x; acc.y += a * hv.y;
    acc.z += a * hv.z; acc.w += a * hv.w;
  }
  float4 bv = *(const float4*)(bias + c0);
  acc.x += bv.x; acc.y += bv.y; acc.z += bv.z; acc.w += bv.w;
  if (RELU) {
    acc.x = fmaxf(acc.x, 0.f); acc.y = fmaxf(acc.y, 0.f);
    acc.z = fmaxf(acc.z, 0.f); acc.w = fmaxf(acc.w, 0.f);
  }
  if (SPLIT) {
    ushort4 hv4, lv4;
    hv4.x = bf16_rne(acc.x); lv4.x = bf16_rne(acc.x - bf16f(hv4.x));
    hv4.y = bf16_rne(acc.y); lv4.y = bf16_rne(acc.y - bf16f(hv4.y));
    hv4.z = bf16_rne(acc.z); lv4.z = bf16_rne(acc.z - bf16f(hv4.z));
    hv4.w = bf16_rne(acc.w); lv4.w = bf16_rne(acc.w - bf16f(hv4.w));
    *(ushort4*)(oh + (size_t)n * F + c0) = hv4;
    *(ushort4*)(ol + (size_t)n * F + c0) = lv4;
  } else {
    *(float4*)(out + (size_t)n * F + c0) = acc;
  }
}

__global__ void aggregate3_kernel(const float* __restrict__ h3, const float* __restrict__ escore,
                                  const int* __restrict__ src_s, const int* __restrict__ off,
                                  const float* __restrict__ m_buf, const float* __restrict__ d_buf,
                                  const float* __restrict__ b3, float* __restrict__ out, int N) {
  int t = blockIdx.x * blockDim.x + threadIdx.x;
  if (t >= N * 4) return;
  int n = t >> 2, head = t & 3;
  int p0 = off[n], p1 = off[n + 1];
  float mh = m_buf[t];
  float inv = 1.f / d_buf[t];
  float acc = 0.f;
  for (int p = p0; p < p1; ++p) {
    float a = __expf(escore[(size_t)p * 4 + head] - mh) * inv;
    acc += a * h3[(size_t)src_s[p] * 4 + head];
  }
  acc += __shfl_down(acc, 1);
  acc += __shfl_down(acc, 2);
  if (head == 0) out[n] = acc * 0.25f + b3[0];
}

// ---------------- host orchestration ----------------

extern "C" void kernel_launch(void* const* d_in, const int* in_sizes, int n_in,
                              void* d_out, int out_size, void* d_ws, size_t ws_size,
                              hipStream_t stream) {
  const float* x   = (const float*)d_in[0];
  const int*   ei  = (const int*)d_in[1];
  const float* W1  = (const float*)d_in[2];
  const float* a1s = (const float*)d_in[3];
  const float* a1d = (const float*)d_in[4];
  const float* b1  = (const float*)d_in[5];
  const float* W2  = (const float*)d_in[6];
  const float* a2s = (const float*)d_in[7];
  const float* a2d = (const float*)d_in[8];
  const float* b2  = (const float*)d_in[9];
  const float* W3  = (const float*)d_in[10];
  const float* a3s = (const float*)d_in[11];
  const float* a3d = (const float*)d_in[12];
  const float* b3  = (const float*)d_in[13];

  const int N = in_sizes[0] / F_IN;
  const int E = in_sizes[1] / 2;
  const int Et = E + N;
  const int Npad = (N + 127) & ~127;

  char* base = (char*)d_ws;
  size_t off = 0;
  auto alloc = [&](size_t bytes) {
    void* p = base + off;
    off = (off + bytes + 255) & ~(size_t)255;
    return p;
  };
  float* A      = (float*)alloc((size_t)N * F * sizeof(float));
  // U region: serves as {Xhi,Xlo} (layer1 split out -> gemm512 in), then as
  // Bbuf (layer2 aggregate out -> gemm3 in). Lifetimes don't overlap.
  float* U      = (float*)alloc((size_t)Npad * F * sizeof(float));
  unsigned short* Xhi = (unsigned short*)U;
  unsigned short* Xlo = Xhi + (size_t)Npad * F;
  float* Bbuf   = U;
  float* escore = (float*)alloc((size_t)Et * 4 * sizeof(float));
  int*   src_s  = (int*)alloc((size_t)Et * sizeof(int));
  int*   counts = (int*)alloc((size_t)N * sizeof(int));
  int*   offs   = (int*)alloc((size_t)(N + 1) * sizeof(int));
  int*   cursor = (int*)alloc((size_t)N * sizeof(int));
  float* as     = (float*)alloc((size_t)N * 4 * sizeof(float));
  float* ad     = (float*)alloc((size_t)N * 4 * sizeof(float));
  float* m_buf  = (float*)alloc((size_t)N * 4 * sizeof(float));
  float* d_buf  = (float*)alloc((size_t)N * 4 * sizeof(float));
  float* h3     = (float*)alloc((size_t)N * 4 * sizeof(float));
  unsigned short* Wth = (unsigned short*)alloc((size_t)512 * 512 * sizeof(unsigned short));
  unsigned short* Wtl = (unsigned short*)alloc((size_t)512 * 512 * sizeof(unsigned short));

  // ---- CSR build + W2 split ----
  hipMemsetAsync(counts, 0, (size_t)N * sizeof(int), stream);
  {
    int gg = (Et + 255) / 256;
    hipLaunchKernelGGL(hist_kernel, dim3(gg), dim3(256), 0, stream, ei, counts, N, E);
    hipLaunchKernelGGL(scan_kernel, dim3(1), dim3(1024), 0, stream, counts, offs, cursor, N);
    hipLaunchKernelGGL(scatter_kernel, dim3(gg), dim3(256), 0, stream, ei, cursor, src_s, N, E);
    hipLaunchKernelGGL(segsort_kernel, dim3((N + 255) / 256), dim3(256), 0, stream, src_s, offs, N);
    hipLaunchKernelGGL(wsplit_kernel, dim3(64), dim3(256), 0, stream, W2, Wth, Wtl);
  }

  int nhGrid = (N * 4 + 255) / 256;

  // ---- layer 1 ----
  hipLaunchKernelGGL(gemm30_kernel, dim3((N + 15) / 16), dim3(256), 0, stream, x, W1, A, N);
  hipLaunchKernelGGL(alpha_kernel, dim3(N), dim3(128), 0, stream, A, a1s, a1d, as, ad);
  hipLaunchKernelGGL(edge_stats_kernel, dim3(nhGrid), dim3(256), 0, stream, as, ad, src_s, offs, escore, m_buf, d_buf, N);
  hipLaunchKernelGGL((aggregate_kernel<true, true>), dim3(N), dim3(128), 0, stream,
                     A, escore, src_s, offs, m_buf, d_buf, b1, (float*)nullptr, Xhi, Xlo);

  // ---- layer 2 ----
  hipLaunchKernelGGL(gemm512_mfma, dim3((N + 127) / 128, 4), dim3(256), 0, stream,
                     Xhi, Xlo, Wth, Wtl, A, N);
  hipLaunchKernelGGL(alpha_kernel, dim3(N), dim3(128), 0, stream, A, a2s, a2d, as, ad);
  hipLaunchKernelGGL(edge_stats_kernel, dim3(nhGrid), dim3(256), 0, stream, as, ad, src_s, offs, escore, m_buf, d_buf, N);
  hipLaunchKernelGGL((aggregate_kernel<true, false>), dim3(N), dim3(128), 0, stream,
                     A, escore, src_s, offs, m_buf, d_buf, b2, Bbuf,
                     (unsigned short*)nullptr, (unsigned short*)nullptr);

  // ---- layer 3 ----
  hipLaunchKernelGGL(gemm3_kernel, dim3((N + 3) / 4), dim3(256), 0, stream, Bbuf, W3, h3, N);
  hipLaunchKernelGGL(alpha3_kernel, dim3(nhGrid), dim3(256), 0, stream, h3, a3s, a3d, as, ad, N);
  hipLaunchKernelGGL(edge_stats_kernel, dim3(nhGrid), dim3(256), 0, stream, as, ad, src_s, offs, escore, m_buf, d_buf, N);
  hipLaunchKernelGGL(aggregate3_kernel, dim3(nhGrid), dim3(256), 0, stream, h3, escore, src_s, offs, m_buf, d_buf, b3, (float*)d_out, N);
}

// Round 10
// 993.606 us; speedup vs baseline: 6.5979x; 1.0253x over previous
//
#include <hip/hip_runtime.h>

#define NEG_SLOPE 0.2f

constexpr int F = 512;    // heads * channels
constexpr int F_IN = 30;

typedef short bfrag __attribute__((ext_vector_type(8)));   // 8 bf16 = 4 VGPR
typedef float f32x4 __attribute__((ext_vector_type(4)));

__device__ __forceinline__ unsigned short bf16_rne(float v) {
  unsigned u = __float_as_uint(v);
  u += 0x7FFF + ((u >> 16) & 1);
  return (unsigned short)(u >> 16);
}
__device__ __forceinline__ float bf16f(unsigned short h) {
  return __uint_as_float(((unsigned)h) << 16);
}

// ---------------- CSR build ----------------

__global__ void hist_kernel(const int* __restrict__ ei, int* __restrict__ counts,
                            int N, int E) {
  int e = blockIdx.x * blockDim.x + threadIdx.x;
  int Et = E + N;
  if (e >= Et) return;
  int d = (e < E) ? ei[E + e] : (e - E);
  atomicAdd(&counts[d], 1);
}

// 1024-thread single-block scan, shuffle-based
__global__ void scan_kernel(const int* __restrict__ counts, int* __restrict__ offsets,
                            int* __restrict__ cursor, int n) {
  __shared__ int wsum[16];
  __shared__ int carry_s;
  int tid = threadIdx.x;
  int lane = tid & 63, wid = tid >> 6;
  if (tid == 0) carry_s = 0;
  __syncthreads();
  for (int base = 0; base < n; base += 1024) {
    int i = base + tid;
    int v = (i < n) ? counts[i] : 0;
    int x = v;
#pragma unroll
    for (int d = 1; d < 64; d <<= 1) {
      int t2 = __shfl_up(x, d);
      if (lane >= d) x += t2;
    }
    if (lane == 63) wsum[wid] = x;
    __syncthreads();
    if (wid == 0) {
      int ws = (lane < 16) ? wsum[lane] : 0;
#pragma unroll
      for (int d = 1; d < 16; d <<= 1) {
        int t2 = __shfl_up(ws, d);
        if (lane >= d) ws += t2;
      }
      if (lane < 16) wsum[lane] = ws;
    }
    __syncthreads();
    int wpre = (wid > 0) ? wsum[wid - 1] : 0;
    int excl = carry_s + wpre + x - v;
    if (i < n) { offsets[i] = excl; cursor[i] = excl; }
    __syncthreads();
    if (tid == 0) carry_s += wsum[15];
    __syncthreads();
  }
  if (threadIdx.x == 0) offsets[n] = carry_s;
}

__global__ void scatter_kernel(const int* __restrict__ ei, int* __restrict__ cursor,
                               int* __restrict__ src_s, int N, int E) {
  int e = blockIdx.x * blockDim.x + threadIdx.x;
  int Et = E + N;
  if (e >= Et) return;
  int s, d;
  if (e < E) { s = ei[e]; d = ei[E + e]; } else { s = e - E; d = e - E; }
  int p = atomicAdd(&cursor[d], 1);
  src_s[p] = s;
}

// Canonicalize within-segment order for determinism across graph replays.
__global__ void segsort_kernel(int* __restrict__ src_s, const int* __restrict__ off, int N) {
  int n = blockIdx.x * blockDim.x + threadIdx.x;
  if (n >= N) return;
  int p0 = off[n], p1 = off[n + 1];
  for (int i = p0 + 1; i < p1; ++i) {
    int key = src_s[i];
    int j = i - 1;
    while (j >= p0 && src_s[j] > key) { src_s[j + 1] = src_s[j]; --j; }
    src_s[j + 1] = key;
  }
}

// ---------------- GEMM (layer1, K=30) ----------------

__global__ void gemm30_kernel(const float* __restrict__ X, const float* __restrict__ W,
                              float* __restrict__ out, int N) {
  __shared__ float xs[16][F_IN];
  int row0 = blockIdx.x * 16;
  int tid = threadIdx.x;
  for (int i = tid; i < 16 * F_IN; i += 256) {
    int r = i / F_IN, k = i - r * F_IN;
    int row = row0 + r;
    xs[r][k] = (row < N) ? X[(size_t)row * F_IN + k] : 0.f;
  }
  __syncthreads();
  int cg = tid & 127;
  int rg = tid >> 7;
  int c0 = cg * 4;
  float4 acc[8];
#pragma unroll
  for (int r = 0; r < 8; ++r) acc[r] = make_float4(0.f, 0.f, 0.f, 0.f);
#pragma unroll 2
  for (int k = 0; k < F_IN; ++k) {
    float4 w = *(const float4*)(W + (size_t)k * F + c0);
#pragma unroll
    for (int r = 0; r < 8; ++r) {
      float xv = xs[rg * 8 + r][k];
      acc[r].x += xv * w.x; acc[r].y += xv * w.y;
      acc[r].z += xv * w.z; acc[r].w += xv * w.w;
    }
  }
#pragma unroll
  for (int r = 0; r < 8; ++r) {
    int row = row0 + rg * 8 + r;
    if (row < N) *(float4*)(out + (size_t)row * F + c0) = acc[r];
  }
}

// ---------------- W2 split + transpose ----------------

__global__ void wsplit_kernel(const float* __restrict__ W,
                              unsigned short* __restrict__ Wth,
                              unsigned short* __restrict__ Wtl) {
  __shared__ float t[64][65];
  int bx = blockIdx.x & 7, by = blockIdx.x >> 3;
  int tid = threadIdx.x;
#pragma unroll
  for (int i = 0; i < 16; ++i) {
    int idx = tid + i * 256;
    int r = idx >> 6, c = idx & 63;
    t[r][c] = W[(size_t)(by * 64 + r) * 512 + bx * 64 + c];
  }
  __syncthreads();
#pragma unroll
  for (int i = 0; i < 16; ++i) {
    int idx = tid + i * 256;
    int r = idx >> 6, c = idx & 63;
    float v = t[c][r];
    unsigned short hi = bf16_rne(v);
    unsigned short lo = bf16_rne(v - bf16f(hi));
    size_t o = (size_t)(bx * 64 + r) * 512 + by * 64 + c;
    Wth[o] = hi; Wtl[o] = lo;
  }
}

// ---------------- GEMM (layer2, K=512) via MFMA, split-bf16 fp32 emulation --

__global__ void gemm512_mfma(const unsigned short* __restrict__ Xhi,
                             const unsigned short* __restrict__ Xlo,
                             const unsigned short* __restrict__ Wth,
                             const unsigned short* __restrict__ Wtl,
                             float* __restrict__ out, int N) {
  __shared__ int4 lds4[2048];               // 32 KB
  char* lds = (char*)lds4;
  const int tid = threadIdx.x;
  const int wid = tid >> 6;
  const int lane = tid & 63;
  const int row0 = blockIdx.x * 128;
  const int col0 = blockIdx.y * 128;
  const int wr = wid >> 1, wc = wid & 1;

  const unsigned short* sb = (wid == 0) ? Xhi : (wid == 1) ? Xlo : (wid == 2) ? Wth : Wtl;
  const int tile0 = (wid < 2) ? row0 : col0;
  const int chunk = (lane & 3) ^ ((lane >> 3) & 3);
  const unsigned short* lanesrc = sb + (size_t)(tile0 + (lane >> 2)) * 512 + chunk * 8;
  char* ldst = lds + wid * 8192;

  const int g = lane >> 4;
  int aoff[4], boff[4];
#pragma unroll
  for (int m = 0; m < 4; ++m) {
    int r = wr * 64 + m * 16 + (lane & 15);
    aoff[m] = r * 64 + ((g ^ ((r >> 1) & 3)) << 4);
    int c = wc * 64 + m * 16 + (lane & 15);
    boff[m] = c * 64 + ((g ^ ((c >> 1) & 3)) << 4);
  }

  f32x4 acc[4][4];
#pragma unroll
  for (int m = 0; m < 4; ++m)
#pragma unroll
    for (int n = 0; n < 4; ++n) acc[m][n] = f32x4{0.f, 0.f, 0.f, 0.f};

  for (int kc = 0; kc < 16; ++kc) {
#pragma unroll
    for (int i = 0; i < 8; ++i) {
      __builtin_amdgcn_global_load_lds(
          (const __attribute__((address_space(1))) void*)(lanesrc + i * 8192 + kc * 32),
          (__attribute__((address_space(3))) void*)(ldst + i * 1024), 16, 0, 0);
    }
    __syncthreads();
    bfrag ah[4], al[4], bh[4], bl[4];
#pragma unroll
    for (int m = 0; m < 4; ++m) {
      ah[m] = *(const bfrag*)(lds + aoff[m]);
      al[m] = *(const bfrag*)(lds + 8192 + aoff[m]);
      bh[m] = *(const bfrag*)(lds + 16384 + boff[m]);
      bl[m] = *(const bfrag*)(lds + 24576 + boff[m]);
    }
#pragma unroll
    for (int m = 0; m < 4; ++m)
#pragma unroll
      for (int n = 0; n < 4; ++n) {
        acc[m][n] = __builtin_amdgcn_mfma_f32_16x16x32_bf16(al[m], bh[n], acc[m][n], 0, 0, 0);
        acc[m][n] = __builtin_amdgcn_mfma_f32_16x16x32_bf16(ah[m], bl[n], acc[m][n], 0, 0, 0);
        acc[m][n] = __builtin_amdgcn_mfma_f32_16x16x32_bf16(ah[m], bh[n], acc[m][n], 0, 0, 0);
      }
    __syncthreads();
  }

  const int crow = (lane >> 4) * 4, ccol = lane & 15;
#pragma unroll
  for (int m = 0; m < 4; ++m) {
    int Rb = row0 + wr * 64 + m * 16 + crow;
#pragma unroll
    for (int n = 0; n < 4; ++n) {
      int C = col0 + wc * 64 + n * 16 + ccol;
#pragma unroll
      for (int q = 0; q < 4; ++q) {
        int R = Rb + q;
        if (R < N) out[(size_t)R * F + C] = acc[m][n][q];
      }
    }
  }
}

// GEMM for layer3
__global__ void gemm3_kernel(const float* __restrict__ X, const float* __restrict__ W3,
                             float* __restrict__ h3, int N) {
  int n = blockIdx.x * 4 + (threadIdx.x >> 6);
  int lane = threadIdx.x & 63;
  if (n >= N) return;
  float acc[4] = {0.f, 0.f, 0.f, 0.f};
  for (int k = lane; k < F; k += 64) {
    float xv = X[(size_t)n * F + k];
#pragma unroll
    for (int j = 0; j < 4; ++j) acc[j] += xv * W3[k * 4 + j];
  }
#pragma unroll
  for (int j = 0; j < 4; ++j)
    for (int off = 32; off > 0; off >>= 1) acc[j] += __shfl_down(acc[j], off);
  if (lane == 0) {
    float4 o; o.x = acc[0]; o.y = acc[1]; o.z = acc[2]; o.w = acc[3];
    *(float4*)(h3 + (size_t)n * 4) = o;
  }
}

// ---------------- alpha dots ----------------

__global__ void alpha_kernel(const float* __restrict__ h, const float* __restrict__ asrc,
                             const float* __restrict__ adst, float* __restrict__ as,
                             float* __restrict__ ad) {
  int n = blockIdx.x;
  int tid = threadIdx.x;
  int c0 = tid * 4;
  float4 hv = *(const float4*)(h + (size_t)n * F + c0);
  float4 sa = *(const float4*)(asrc + c0);
  float4 da = *(const float4*)(adst + c0);
  float ps = hv.x * sa.x + hv.y * sa.y + hv.z * sa.z + hv.w * sa.w;
  float pd = hv.x * da.x + hv.y * da.y + hv.z * da.z + hv.w * da.w;
#pragma unroll
  for (int off = 16; off > 0; off >>= 1) {
    ps += __shfl_down(ps, off);
    pd += __shfl_down(pd, off);
  }
  if ((tid & 31) == 0) {
    int head = tid >> 5;
    as[n * 4 + head] = ps;
    ad[n * 4 + head] = pd;
  }
}

__global__ void alpha3_kernel(const float* __restrict__ h3, const float* __restrict__ a3s,
                              const float* __restrict__ a3d, float* __restrict__ as,
                              float* __restrict__ ad, int N) {
  int t = blockIdx.x * blockDim.x + threadIdx.x;
  if (t >= N * 4) return;
  int hh = t & 3;
  float v = h3[t];
  as[t] = v * a3s[hh];
  ad[t] = v * a3d[hh];
}

// ---------------- fused edge score + softmax stats, 4-wide prefetch ----------

__device__ __forceinline__ float leaky(float v) { return v > 0.f ? v : NEG_SLOPE * v; }

__global__ void edge_stats_kernel(const float* __restrict__ as, const float* __restrict__ ad,
                                  const int* __restrict__ src_s, const int* __restrict__ off,
                                  float* __restrict__ escore,
                                  float* __restrict__ m_out, float* __restrict__ d_out_, int N) {
  int t = blockIdx.x * blockDim.x + threadIdx.x;
  if (t >= N * 4) return;
  int n = t >> 2, h = t & 3;
  int p0 = off[n], p1 = off[n + 1];
  float adv = ad[n * 4 + h];
  float m = -1e30f, s = 0.f;
  int p = p0;
  for (; p + 4 <= p1; p += 4) {
    int s0 = src_s[p], s1 = src_s[p + 1], s2 = src_s[p + 2], s3 = src_s[p + 3];
    float v0 = as[s0 * 4 + h], v1 = as[s1 * 4 + h];
    float v2 = as[s2 * 4 + h], v3 = as[s3 * 4 + h];
    float e0 = leaky(v0 + adv), e1 = leaky(v1 + adv);
    float e2 = leaky(v2 + adv), e3 = leaky(v3 + adv);
    escore[(size_t)(p + 0) * 4 + h] = e0;
    escore[(size_t)(p + 1) * 4 + h] = e1;
    escore[(size_t)(p + 2) * 4 + h] = e2;
    escore[(size_t)(p + 3) * 4 + h] = e3;
    if (e0 > m) { s *= __expf(m - e0); m = e0; } s += __expf(e0 - m);
    if (e1 > m) { s *= __expf(m - e1); m = e1; } s += __expf(e1 - m);
    if (e2 > m) { s *= __expf(m - e2); m = e2; } s += __expf(e2 - m);
    if (e3 > m) { s *= __expf(m - e3); m = e3; } s += __expf(e3 - m);
  }
  for (; p < p1; ++p) {
    int si = src_s[p];
    float e = leaky(as[si * 4 + h] + adv);
    escore[(size_t)p * 4 + h] = e;
    if (e > m) { s *= __expf(m - e); m = e; }
    s += __expf(e - m);
  }
  m_out[t] = m;
  d_out_[t] = s + 1e-16f;
}

// ---------------- aggregate: 4-edge software pipeline ----------------

__device__ __forceinline__ void fma4(float4& a, float s, const float4& b) {
  a.x += s * b.x; a.y += s * b.y; a.z += s * b.z; a.w += s * b.w;
}

template <bool RELU, bool SPLIT>
__global__ void aggregate_kernel(const float* __restrict__ hsrc, const float* __restrict__ escore,
                                 const int* __restrict__ src_s, const int* __restrict__ off,
                                 const float* __restrict__ m_buf, const float* __restrict__ d_buf,
                                 const float* __restrict__ bias, float* __restrict__ out,
                                 unsigned short* __restrict__ oh, unsigned short* __restrict__ ol) {
  int n = blockIdx.x;
  int tid = threadIdx.x;
  int c0 = tid * 4;
  int head = tid >> 5;
  int p0 = off[n], p1 = off[n + 1];
  float mh = m_buf[n * 4 + head];
  float inv = 1.f / d_buf[n * 4 + head];
  float4 acc0 = make_float4(0.f, 0.f, 0.f, 0.f);
  float4 acc1 = acc0, acc2 = acc0, acc3 = acc0;
  int p = p0;
  for (; p + 4 <= p1; p += 4) {
    int s0 = src_s[p], s1 = src_s[p + 1], s2 = src_s[p + 2], s3 = src_s[p + 3];
    float e0 = escore[(size_t)(p + 0) * 4 + head];
    float e1 = escore[(size_t)(p + 1) * 4 + head];
    float e2 = escore[(size_t)(p + 2) * 4 + head];
    float e3 = escore[(size_t)(p + 3) * 4 + head];
    float4 h0 = *(const float4*)(hsrc + (size_t)s0 * F + c0);
    float4 h1 = *(const float4*)(hsrc + (size_t)s1 * F + c0);
    float4 h2 = *(const float4*)(hsrc + (size_t)s2 * F + c0);
    float4 h3v = *(const float4*)(hsrc + (size_t)s3 * F + c0);
    fma4(acc0, __expf(e0 - mh) * inv, h0);
    fma4(acc1, __expf(e1 - mh) * inv, h1);
    fma4(acc2, __expf(e2 - mh) * inv, h2);
    fma4(acc3, __expf(e3 - mh) * inv, h3v);
  }
  for (; p < p1; ++p) {
    float a = __expf(escore[(size_t)p * 4 + head] - mh) * inv;
    int s = src_s[p];
    float4 hv = *(const float4*)(hsrc + (size_t)s * F + c0);
    fma4(acc0, a, hv);
  }
  float4 acc;
  acc.x = (acc0.x + acc1.x) + (acc2.x + acc3.x);
  acc.y = (acc0.y + acc1.y) + (acc2.y + acc3.y);
  acc.z = (acc0.z + acc1.z) + (acc2.z + acc3.z);
  acc.w = (acc0.w + acc1.w) + (acc2.w + acc3.w);
  float4 bv = *(const float4*)(bias + c0);
  acc.x += bv.x; acc.y += bv.y; acc.z += bv.z; acc.w += bv.w;
  if (RELU) {
    acc.x = fmaxf(acc.x, 0.f); acc.y = fmaxf(acc.y, 0.f);
    acc.z = fmaxf(acc.z, 0.f); acc.w = fmaxf(acc.w, 0.f);
  }
  if (SPLIT) {
    ushort4 hv4, lv4;
    hv4.x = bf16_rne(acc.x); lv4.x = bf16_rne(acc.x - bf16f(hv4.x));
    hv4.y = bf16_rne(acc.y); lv4.y = bf16_rne(acc.y - bf16f(hv4.y));
    hv4.z = bf16_rne(acc.z); lv4.z = bf16_rne(acc.z - bf16f(hv4.z));
    hv4.w = bf16_rne(acc.w); lv4.w = bf16_rne(acc.w - bf16f(hv4.w));
    *(ushort4*)(oh + (size_t)n * F + c0) = hv4;
    *(ushort4*)(ol + (size_t)n * F + c0) = lv4;
  } else {
    *(float4*)(out + (size_t)n * F + c0) = acc;
  }
}

__global__ void aggregate3_kernel(const float* __restrict__ h3, const float* __restrict__ escore,
                                  const int* __restrict__ src_s, const int* __restrict__ off,
                                  const float* __restrict__ m_buf, const float* __restrict__ d_buf,
                                  const float* __restrict__ b3, float* __restrict__ out, int N) {
  int t = blockIdx.x * blockDim.x + threadIdx.x;
  if (t >= N * 4) return;
  int n = t >> 2, head = t & 3;
  int p0 = off[n], p1 = off[n + 1];
  float mh = m_buf[t];
  float inv = 1.f / d_buf[t];
  float a0 = 0.f, a1 = 0.f, a2 = 0.f, a3 = 0.f;
  int p = p0;
  for (; p + 4 <= p1; p += 4) {
    int s0 = src_s[p], s1 = src_s[p + 1], s2 = src_s[p + 2], s3 = src_s[p + 3];
    float e0 = escore[(size_t)(p + 0) * 4 + head];
    float e1 = escore[(size_t)(p + 1) * 4 + head];
    float e2 = escore[(size_t)(p + 2) * 4 + head];
    float e3 = escore[(size_t)(p + 3) * 4 + head];
    float h0 = h3[(size_t)s0 * 4 + head], h1 = h3[(size_t)s1 * 4 + head];
    float h2 = h3[(size_t)s2 * 4 + head], h3v = h3[(size_t)s3 * 4 + head];
    a0 += __expf(e0 - mh) * inv * h0;
    a1 += __expf(e1 - mh) * inv * h1;
    a2 += __expf(e2 - mh) * inv * h2;
    a3 += __expf(e3 - mh) * inv * h3v;
  }
  for (; p < p1; ++p) {
    float a = __expf(escore[(size_t)p * 4 + head] - mh) * inv;
    a0 += a * h3[(size_t)src_s[p] * 4 + head];
  }
  float acc = (a0 + a1) + (a2 + a3);
  acc += __shfl_down(acc, 1);
  acc += __shfl_down(acc, 2);
  if (head == 0) out[n] = acc * 0.25f + b3[0];
}

// ---------------- host orchestration ----------------

extern "C" void kernel_launch(void* const* d_in, const int* in_sizes, int n_in,
                              void* d_out, int out_size, void* d_ws, size_t ws_size,
                              hipStream_t stream) {
  const float* x   = (const float*)d_in[0];
  const int*   ei  = (const int*)d_in[1];
  const float* W1  = (const float*)d_in[2];
  const float* a1s = (const float*)d_in[3];
  const float* a1d = (const float*)d_in[4];
  const float* b1  = (const float*)d_in[5];
  const float* W2  = (const float*)d_in[6];
  const float* a2s = (const float*)d_in[7];
  const float* a2d = (const float*)d_in[8];
  const float* b2  = (const float*)d_in[9];
  const float* W3  = (const float*)d_in[10];
  const float* a3s = (const float*)d_in[11];
  const float* a3d = (const float*)d_in[12];
  const float* b3  = (const float*)d_in[13];

  const int N = in_sizes[0] / F_IN;
  const int E = in_sizes[1] / 2;
  const int Et = E + N;
  const int Npad = (N + 127) & ~127;

  char* base = (char*)d_ws;
  size_t off = 0;
  auto alloc = [&](size_t bytes) {
    void* p = base + off;
    off = (off + bytes + 255) & ~(size_t)255;
    return p;
  };
  float* A      = (float*)alloc((size_t)N * F * sizeof(float));
  float* U      = (float*)alloc((size_t)Npad * F * sizeof(float));
  unsigned short* Xhi = (unsigned short*)U;
  unsigned short* Xlo = Xhi + (size_t)Npad * F;
  float* Bbuf   = U;
  float* escore = (float*)alloc((size_t)Et * 4 * sizeof(float));
  int*   src_s  = (int*)alloc((size_t)Et * sizeof(int));
  int*   counts = (int*)alloc((size_t)N * sizeof(int));
  int*   offs   = (int*)alloc((size_t)(N + 1) * sizeof(int));
  int*   cursor = (int*)alloc((size_t)N * sizeof(int));
  float* as     = (float*)alloc((size_t)N * 4 * sizeof(float));
  float* ad     = (float*)alloc((size_t)N * 4 * sizeof(float));
  float* m_buf  = (float*)alloc((size_t)N * 4 * sizeof(float));
  float* d_buf  = (float*)alloc((size_t)N * 4 * sizeof(float));
  float* h3     = (float*)alloc((size_t)N * 4 * sizeof(float));
  unsigned short* Wth = (unsigned short*)alloc((size_t)512 * 512 * sizeof(unsigned short));
  unsigned short* Wtl = (unsigned short*)alloc((size_t)512 * 512 * sizeof(unsigned short));

  // ---- CSR build + W2 split ----
  hipMemsetAsync(counts, 0, (size_t)N * sizeof(int), stream);
  {
    int gg = (Et + 255) / 256;
    hipLaunchKernelGGL(hist_kernel, dim3(gg), dim3(256), 0, stream, ei, counts, N, E);
    hipLaunchKernelGGL(scan_kernel, dim3(1), dim3(1024), 0, stream, counts, offs, cursor, N);
    hipLaunchKernelGGL(scatter_kernel, dim3(gg), dim3(256), 0, stream, ei, cursor, src_s, N, E);
    hipLaunchKernelGGL(segsort_kernel, dim3((N + 255) / 256), dim3(256), 0, stream, src_s, offs, N);
    hipLaunchKernelGGL(wsplit_kernel, dim3(64), dim3(256), 0, stream, W2, Wth, Wtl);
  }

  int nhGrid = (N * 4 + 255) / 256;

  // ---- layer 1 ----
  hipLaunchKernelGGL(gemm30_kernel, dim3((N + 15) / 16), dim3(256), 0, stream, x, W1, A, N);
  hipLaunchKernelGGL(alpha_kernel, dim3(N), dim3(128), 0, stream, A, a1s, a1d, as, ad);
  hipLaunchKernelGGL(edge_stats_kernel, dim3(nhGrid), dim3(256), 0, stream, as, ad, src_s, offs, escore, m_buf, d_buf, N);
  hipLaunchKernelGGL((aggregate_kernel<true, true>), dim3(N), dim3(128), 0, stream,
                     A, escore, src_s, offs, m_buf, d_buf, b1, (float*)nullptr, Xhi, Xlo);

  // ---- layer 2 ----
  hipLaunchKernelGGL(gemm512_mfma, dim3((N + 127) / 128, 4), dim3(256), 0, stream,
                     Xhi, Xlo, Wth, Wtl, A, N);
  hipLaunchKernelGGL(alpha_kernel, dim3(N), dim3(128), 0, stream, A, a2s, a2d, as, ad);
  hipLaunchKernelGGL(edge_stats_kernel, dim3(nhGrid), dim3(256), 0, stream, as, ad, src_s, offs, escore, m_buf, d_buf, N);
  hipLaunchKernelGGL((aggregate_kernel<true, false>), dim3(N), dim3(128), 0, stream,
                     A, escore, src_s, offs, m_buf, d_buf, b2, Bbuf,
                     (unsigned short*)nullptr, (unsigned short*)nullptr);

  // ---- layer 3 ----
  hipLaunchKernelGGL(gemm3_kernel, dim3((N + 3) / 4), dim3(256), 0, stream, Bbuf, W3, h3, N);
  hipLaunchKernelGGL(alpha3_kernel, dim3(nhGrid), dim3(256), 0, stream, h3, a3s, a3d, as, ad, N);
  hipLaunchKernelGGL(edge_stats_kernel, dim3(nhGrid), dim3(256), 0, stream, as, ad, src_s, offs, escore, m_buf, d_buf, N);
  hipLaunchKernelGGL(aggregate3_kernel, dim3(nhGrid), dim3(256), 0, stream, h3, escore, src_s, offs, m_buf, d_buf, b3, (float*)d_out, N);
}

// Round 11
// 990.677 us; speedup vs baseline: 6.6174x; 1.0030x over previous
//
#include <hip/hip_runtime.h>

#define NEG_SLOPE 0.2f

constexpr int F = 512;    // heads * channels
constexpr int F_IN = 30;

typedef short bfrag __attribute__((ext_vector_type(8)));   // 8 bf16 = 4 VGPR
typedef float f32x4 __attribute__((ext_vector_type(4)));

__device__ __forceinline__ unsigned short bf16_rne(float v) {
  unsigned u = __float_as_uint(v);
  u += 0x7FFF + ((u >> 16) & 1);
  return (unsigned short)(u >> 16);
}
__device__ __forceinline__ float bf16f(unsigned short h) {
  return __uint_as_float(((unsigned)h) << 16);
}

// ---------------- CSR build ----------------

__global__ void hist_kernel(const int* __restrict__ ei, int* __restrict__ counts,
                            int N, int E) {
  int e = blockIdx.x * blockDim.x + threadIdx.x;
  int Et = E + N;
  if (e >= Et) return;
  int d = (e < E) ? ei[E + e] : (e - E);
  atomicAdd(&counts[d], 1);
}

// 1024-thread single-block scan, shuffle-based
__global__ void scan_kernel(const int* __restrict__ counts, int* __restrict__ offsets,
                            int* __restrict__ cursor, int n) {
  __shared__ int wsum[16];
  __shared__ int carry_s;
  int tid = threadIdx.x;
  int lane = tid & 63, wid = tid >> 6;
  if (tid == 0) carry_s = 0;
  __syncthreads();
  for (int base = 0; base < n; base += 1024) {
    int i = base + tid;
    int v = (i < n) ? counts[i] : 0;
    int x = v;
#pragma unroll
    for (int d = 1; d < 64; d <<= 1) {
      int t2 = __shfl_up(x, d);
      if (lane >= d) x += t2;
    }
    if (lane == 63) wsum[wid] = x;
    __syncthreads();
    if (wid == 0) {
      int ws = (lane < 16) ? wsum[lane] : 0;
#pragma unroll
      for (int d = 1; d < 16; d <<= 1) {
        int t2 = __shfl_up(ws, d);
        if (lane >= d) ws += t2;
      }
      if (lane < 16) wsum[lane] = ws;
    }
    __syncthreads();
    int wpre = (wid > 0) ? wsum[wid - 1] : 0;
    int excl = carry_s + wpre + x - v;
    if (i < n) { offsets[i] = excl; cursor[i] = excl; }
    __syncthreads();
    if (tid == 0) carry_s += wsum[15];
    __syncthreads();
  }
  if (threadIdx.x == 0) offsets[n] = carry_s;
}

__global__ void scatter_kernel(const int* __restrict__ ei, int* __restrict__ cursor,
                               int* __restrict__ src_s, int N, int E) {
  int e = blockIdx.x * blockDim.x + threadIdx.x;
  int Et = E + N;
  if (e >= Et) return;
  int s, d;
  if (e < E) { s = ei[e]; d = ei[E + e]; } else { s = e - E; d = e - E; }
  int p = atomicAdd(&cursor[d], 1);
  src_s[p] = s;
}

// Canonicalize within-segment order for determinism across graph replays.
__global__ void segsort_kernel(int* __restrict__ src_s, const int* __restrict__ off, int N) {
  int n = blockIdx.x * blockDim.x + threadIdx.x;
  if (n >= N) return;
  int p0 = off[n], p1 = off[n + 1];
  for (int i = p0 + 1; i < p1; ++i) {
    int key = src_s[i];
    int j = i - 1;
    while (j >= p0 && src_s[j] > key) { src_s[j + 1] = src_s[j]; --j; }
    src_s[j + 1] = key;
  }
}

// ---------------- GEMM (layer1, K=30) ----------------

__global__ void gemm30_kernel(const float* __restrict__ X, const float* __restrict__ W,
                              float* __restrict__ out, int N) {
  __shared__ float xs[16][F_IN];
  int row0 = blockIdx.x * 16;
  int tid = threadIdx.x;
  for (int i = tid; i < 16 * F_IN; i += 256) {
    int r = i / F_IN, k = i - r * F_IN;
    int row = row0 + r;
    xs[r][k] = (row < N) ? X[(size_t)row * F_IN + k] : 0.f;
  }
  __syncthreads();
  int cg = tid & 127;
  int rg = tid >> 7;
  int c0 = cg * 4;
  float4 acc[8];
#pragma unroll
  for (int r = 0; r < 8; ++r) acc[r] = make_float4(0.f, 0.f, 0.f, 0.f);
#pragma unroll 2
  for (int k = 0; k < F_IN; ++k) {
    float4 w = *(const float4*)(W + (size_t)k * F + c0);
#pragma unroll
    for (int r = 0; r < 8; ++r) {
      float xv = xs[rg * 8 + r][k];
      acc[r].x += xv * w.x; acc[r].y += xv * w.y;
      acc[r].z += xv * w.z; acc[r].w += xv * w.w;
    }
  }
#pragma unroll
  for (int r = 0; r < 8; ++r) {
    int row = row0 + rg * 8 + r;
    if (row < N) *(float4*)(out + (size_t)row * F + c0) = acc[r];
  }
}

// ---------------- W2 split + transpose ----------------

__global__ void wsplit_kernel(const float* __restrict__ W,
                              unsigned short* __restrict__ Wth,
                              unsigned short* __restrict__ Wtl) {
  __shared__ float t[64][65];
  int bx = blockIdx.x & 7, by = blockIdx.x >> 3;
  int tid = threadIdx.x;
#pragma unroll
  for (int i = 0; i < 16; ++i) {
    int idx = tid + i * 256;
    int r = idx >> 6, c = idx & 63;
    t[r][c] = W[(size_t)(by * 64 + r) * 512 + bx * 64 + c];
  }
  __syncthreads();
#pragma unroll
  for (int i = 0; i < 16; ++i) {
    int idx = tid + i * 256;
    int r = idx >> 6, c = idx & 63;
    float v = t[c][r];
    unsigned short hi = bf16_rne(v);
    unsigned short lo = bf16_rne(v - bf16f(hi));
    size_t o = (size_t)(bx * 64 + r) * 512 + by * 64 + c;
    Wth[o] = hi; Wtl[o] = lo;
  }
}

// ---------------- GEMM (layer2, K=512) via MFMA, split-bf16 fp32 emulation --

__global__ void gemm512_mfma(const unsigned short* __restrict__ Xhi,
                             const unsigned short* __restrict__ Xlo,
                             const unsigned short* __restrict__ Wth,
                             const unsigned short* __restrict__ Wtl,
                             float* __restrict__ out, int N) {
  __shared__ int4 lds4[2048];               // 32 KB
  char* lds = (char*)lds4;
  const int tid = threadIdx.x;
  const int wid = tid >> 6;
  const int lane = tid & 63;
  const int row0 = blockIdx.x * 128;
  const int col0 = blockIdx.y * 128;
  const int wr = wid >> 1, wc = wid & 1;

  const unsigned short* sb = (wid == 0) ? Xhi : (wid == 1) ? Xlo : (wid == 2) ? Wth : Wtl;
  const int tile0 = (wid < 2) ? row0 : col0;
  const int chunk = (lane & 3) ^ ((lane >> 3) & 3);
  const unsigned short* lanesrc = sb + (size_t)(tile0 + (lane >> 2)) * 512 + chunk * 8;
  char* ldst = lds + wid * 8192;

  const int g = lane >> 4;
  int aoff[4], boff[4];
#pragma unroll
  for (int m = 0; m < 4; ++m) {
    int r = wr * 64 + m * 16 + (lane & 15);
    aoff[m] = r * 64 + ((g ^ ((r >> 1) & 3)) << 4);
    int c = wc * 64 + m * 16 + (lane & 15);
    boff[m] = c * 64 + ((g ^ ((c >> 1) & 3)) << 4);
  }

  f32x4 acc[4][4];
#pragma unroll
  for (int m = 0; m < 4; ++m)
#pragma unroll
    for (int n = 0; n < 4; ++n) acc[m][n] = f32x4{0.f, 0.f, 0.f, 0.f};

  for (int kc = 0; kc < 16; ++kc) {
#pragma unroll
    for (int i = 0; i < 8; ++i) {
      __builtin_amdgcn_global_load_lds(
          (const __attribute__((address_space(1))) void*)(lanesrc + i * 8192 + kc * 32),
          (__attribute__((address_space(3))) void*)(ldst + i * 1024), 16, 0, 0);
    }
    __syncthreads();
    bfrag ah[4], al[4], bh[4], bl[4];
#pragma unroll
    for (int m = 0; m < 4; ++m) {
      ah[m] = *(const bfrag*)(lds + aoff[m]);
      al[m] = *(const bfrag*)(lds + 8192 + aoff[m]);
      bh[m] = *(const bfrag*)(lds + 16384 + boff[m]);
      bl[m] = *(const bfrag*)(lds + 24576 + boff[m]);
    }
#pragma unroll
    for (int m = 0; m < 4; ++m)
#pragma unroll
      for (int n = 0; n < 4; ++n) {
        acc[m][n] = __builtin_amdgcn_mfma_f32_16x16x32_bf16(al[m], bh[n], acc[m][n], 0, 0, 0);
        acc[m][n] = __builtin_amdgcn_mfma_f32_16x16x32_bf16(ah[m], bl[n], acc[m][n], 0, 0, 0);
        acc[m][n] = __builtin_amdgcn_mfma_f32_16x16x32_bf16(ah[m], bh[n], acc[m][n], 0, 0, 0);
      }
    __syncthreads();
  }

  const int crow = (lane >> 4) * 4, ccol = lane & 15;
#pragma unroll
  for (int m = 0; m < 4; ++m) {
    int Rb = row0 + wr * 64 + m * 16 + crow;
#pragma unroll
    for (int n = 0; n < 4; ++n) {
      int C = col0 + wc * 64 + n * 16 + ccol;
#pragma unroll
      for (int q = 0; q < 4; ++q) {
        int R = Rb + q;
        if (R < N) out[(size_t)R * F + C] = acc[m][n][q];
      }
    }
  }
}

// GEMM for layer3
__global__ void gemm3_kernel(const float* __restrict__ X, const float* __restrict__ W3,
                             float* __restrict__ h3, int N) {
  int n = blockIdx.x * 4 + (threadIdx.x >> 6);
  int lane = threadIdx.x & 63;
  if (n >= N) return;
  float acc[4] = {0.f, 0.f, 0.f, 0.f};
  for (int k = lane; k < F; k += 64) {
    float xv = X[(size_t)n * F + k];
#pragma unroll
    for (int j = 0; j < 4; ++j) acc[j] += xv * W3[k * 4 + j];
  }
#pragma unroll
  for (int j = 0; j < 4; ++j)
    for (int off = 32; off > 0; off >>= 1) acc[j] += __shfl_down(acc[j], off);
  if (lane == 0) {
    float4 o; o.x = acc[0]; o.y = acc[1]; o.z = acc[2]; o.w = acc[3];
    *(float4*)(h3 + (size_t)n * 4) = o;
  }
}

// ---------------- alpha dots ----------------

__global__ void alpha_kernel(const float* __restrict__ h, const float* __restrict__ asrc,
                             const float* __restrict__ adst, float* __restrict__ as,
                             float* __restrict__ ad) {
  int n = blockIdx.x;
  int tid = threadIdx.x;
  int c0 = tid * 4;
  float4 hv = *(const float4*)(h + (size_t)n * F + c0);
  float4 sa = *(const float4*)(asrc + c0);
  float4 da = *(const float4*)(adst + c0);
  float ps = hv.x * sa.x + hv.y * sa.y + hv.z * sa.z + hv.w * sa.w;
  float pd = hv.x * da.x + hv.y * da.y + hv.z * da.z + hv.w * da.w;
#pragma unroll
  for (int off = 16; off > 0; off >>= 1) {
    ps += __shfl_down(ps, off);
    pd += __shfl_down(pd, off);
  }
  if ((tid & 31) == 0) {
    int head = tid >> 5;
    as[n * 4 + head] = ps;
    ad[n * 4 + head] = pd;
  }
}

__global__ void alpha3_kernel(const float* __restrict__ h3, const float* __restrict__ a3s,
                              const float* __restrict__ a3d, float* __restrict__ as,
                              float* __restrict__ ad, int N) {
  int t = blockIdx.x * blockDim.x + threadIdx.x;
  if (t >= N * 4) return;
  int hh = t & 3;
  float v = h3[t];
  as[t] = v * a3s[hh];
  ad[t] = v * a3d[hh];
}

// ---------------- fused softmax-stats + aggregate ----------------
// block = 128 threads = 1 node; head = tid>>5, 32 lanes per head.
// Phase 1: strided online (m,s) per head + fixed shfl combine tree
// (deterministic: fixed partition, fixed tree, max is order-invariant).
// Phase 2: sequential edge loop, alpha recomputed inline (broadcast reads).

__device__ __forceinline__ float leaky(float v) { return v > 0.f ? v : NEG_SLOPE * v; }

__device__ __forceinline__ void fma4(float4& a, float s, const float4& b) {
  a.x += s * b.x; a.y += s * b.y; a.z += s * b.z; a.w += s * b.w;
}

template <bool RELU, bool SPLIT>
__global__ void fused_aggregate_kernel(const float* __restrict__ hsrc,
                                       const float* __restrict__ as, const float* __restrict__ ad,
                                       const int* __restrict__ src_s, const int* __restrict__ off,
                                       const float* __restrict__ bias, float* __restrict__ out,
                                       unsigned short* __restrict__ oh, unsigned short* __restrict__ ol) {
  int n = blockIdx.x;
  int tid = threadIdx.x;
  int head = tid >> 5;
  int l32 = tid & 31;
  int c0 = tid * 4;
  int p0 = off[n], p1 = off[n + 1];
  float adv = ad[n * 4 + head];

  // phase 1: per-head online stats over strided edge partition
  float m = -1e30f, s = 0.f;
  for (int p = p0 + l32; p < p1; p += 32) {
    float e = leaky(as[src_s[p] * 4 + head] + adv);
    if (e > m) { s *= __expf(m - e); m = e; }
    s += __expf(e - m);
  }
#pragma unroll
  for (int o = 16; o > 0; o >>= 1) {
    float mo = __shfl_down(m, o, 32);
    float so = __shfl_down(s, o, 32);
    float mn = fmaxf(m, mo);
    s = s * __expf(m - mn) + so * __expf(mo - mn);
    m = mn;
  }
  m = __shfl(m, 0, 32);
  s = __shfl(s, 0, 32);
  float inv = 1.f / (s + 1e-16f);

  // phase 2: gather + weighted sum (sequential order -> deterministic)
  float4 acc = make_float4(0.f, 0.f, 0.f, 0.f);
#pragma unroll 2
  for (int p = p0; p < p1; ++p) {
    int sp = src_s[p];
    float a = __expf(leaky(as[sp * 4 + head] + adv) - m) * inv;
    float4 hv = *(const float4*)(hsrc + (size_t)sp * F + c0);
    fma4(acc, a, hv);
  }
  float4 bv = *(const float4*)(bias + c0);
  acc.x += bv.x; acc.y += bv.y; acc.z += bv.z; acc.w += bv.w;
  if (RELU) {
    acc.x = fmaxf(acc.x, 0.f); acc.y = fmaxf(acc.y, 0.f);
    acc.z = fmaxf(acc.z, 0.f); acc.w = fmaxf(acc.w, 0.f);
  }
  if (SPLIT) {
    ushort4 hv4, lv4;
    hv4.x = bf16_rne(acc.x); lv4.x = bf16_rne(acc.x - bf16f(hv4.x));
    hv4.y = bf16_rne(acc.y); lv4.y = bf16_rne(acc.y - bf16f(hv4.y));
    hv4.z = bf16_rne(acc.z); lv4.z = bf16_rne(acc.z - bf16f(hv4.z));
    hv4.w = bf16_rne(acc.w); lv4.w = bf16_rne(acc.w - bf16f(hv4.w));
    *(ushort4*)(oh + (size_t)n * F + c0) = hv4;
    *(ushort4*)(ol + (size_t)n * F + c0) = lv4;
  } else {
    *(float4*)(out + (size_t)n * F + c0) = acc;
  }
}

// layer3: one thread per (node, head); two serial passes (stats, then sum);
// all data tiny (h3 = N x 4) and L1/L2-hot on the second pass.
__global__ void fused_aggregate3_kernel(const float* __restrict__ h3,
                                        const float* __restrict__ as, const float* __restrict__ ad,
                                        const int* __restrict__ src_s, const int* __restrict__ off,
                                        const float* __restrict__ b3, float* __restrict__ out, int N) {
  int t = blockIdx.x * blockDim.x + threadIdx.x;
  if (t >= N * 4) return;
  int n = t >> 2, head = t & 3;
  int p0 = off[n], p1 = off[n + 1];
  float adv = ad[t];
  float m = -1e30f, s = 0.f;
  for (int p = p0; p < p1; ++p) {
    float e = leaky(as[src_s[p] * 4 + head] + adv);
    if (e > m) { s *= __expf(m - e); m = e; }
    s += __expf(e - m);
  }
  float inv = 1.f / (s + 1e-16f);
  float acc = 0.f;
  for (int p = p0; p < p1; ++p) {
    int sp = src_s[p];
    float a = __expf(leaky(as[sp * 4 + head] + adv) - m) * inv;
    acc += a * h3[(size_t)sp * 4 + head];
  }
  acc += __shfl_down(acc, 1);
  acc += __shfl_down(acc, 2);
  if (head == 0) out[n] = acc * 0.25f + b3[0];
}

// ---------------- host orchestration ----------------

extern "C" void kernel_launch(void* const* d_in, const int* in_sizes, int n_in,
                              void* d_out, int out_size, void* d_ws, size_t ws_size,
                              hipStream_t stream) {
  const float* x   = (const float*)d_in[0];
  const int*   ei  = (const int*)d_in[1];
  const float* W1  = (const float*)d_in[2];
  const float* a1s = (const float*)d_in[3];
  const float* a1d = (const float*)d_in[4];
  const float* b1  = (const float*)d_in[5];
  const float* W2  = (const float*)d_in[6];
  const float* a2s = (const float*)d_in[7];
  const float* a2d = (const float*)d_in[8];
  const float* b2  = (const float*)d_in[9];
  const float* W3  = (const float*)d_in[10];
  const float* a3s = (const float*)d_in[11];
  const float* a3d = (const float*)d_in[12];
  const float* b3  = (const float*)d_in[13];

  const int N = in_sizes[0] / F_IN;
  const int E = in_sizes[1] / 2;
  const int Et = E + N;
  const int Npad = (N + 127) & ~127;

  char* base = (char*)d_ws;
  size_t off = 0;
  auto alloc = [&](size_t bytes) {
    void* p = base + off;
    off = (off + bytes + 255) & ~(size_t)255;
    return p;
  };
  float* A      = (float*)alloc((size_t)N * F * sizeof(float));
  float* U      = (float*)alloc((size_t)Npad * F * sizeof(float));
  unsigned short* Xhi = (unsigned short*)U;
  unsigned short* Xlo = Xhi + (size_t)Npad * F;
  float* Bbuf   = U;
  int*   src_s  = (int*)alloc((size_t)Et * sizeof(int));
  int*   counts = (int*)alloc((size_t)N * sizeof(int));
  int*   offs   = (int*)alloc((size_t)(N + 1) * sizeof(int));
  int*   cursor = (int*)alloc((size_t)N * sizeof(int));
  float* as     = (float*)alloc((size_t)N * 4 * sizeof(float));
  float* ad     = (float*)alloc((size_t)N * 4 * sizeof(float));
  float* h3     = (float*)alloc((size_t)N * 4 * sizeof(float));
  unsigned short* Wth = (unsigned short*)alloc((size_t)512 * 512 * sizeof(unsigned short));
  unsigned short* Wtl = (unsigned short*)alloc((size_t)512 * 512 * sizeof(unsigned short));

  // ---- CSR build + W2 split ----
  hipMemsetAsync(counts, 0, (size_t)N * sizeof(int), stream);
  {
    int gg = (Et + 255) / 256;
    hipLaunchKernelGGL(hist_kernel, dim3(gg), dim3(256), 0, stream, ei, counts, N, E);
    hipLaunchKernelGGL(scan_kernel, dim3(1), dim3(1024), 0, stream, counts, offs, cursor, N);
    hipLaunchKernelGGL(scatter_kernel, dim3(gg), dim3(256), 0, stream, ei, cursor, src_s, N, E);
    hipLaunchKernelGGL(segsort_kernel, dim3((N + 255) / 256), dim3(256), 0, stream, src_s, offs, N);
    hipLaunchKernelGGL(wsplit_kernel, dim3(64), dim3(256), 0, stream, W2, Wth, Wtl);
  }

  int nhGrid = (N * 4 + 255) / 256;

  // ---- layer 1 ----
  hipLaunchKernelGGL(gemm30_kernel, dim3((N + 15) / 16), dim3(256), 0, stream, x, W1, A, N);
  hipLaunchKernelGGL(alpha_kernel, dim3(N), dim3(128), 0, stream, A, a1s, a1d, as, ad);
  hipLaunchKernelGGL((fused_aggregate_kernel<true, true>), dim3(N), dim3(128), 0, stream,
                     A, as, ad, src_s, offs, b1, (float*)nullptr, Xhi, Xlo);

  // ---- layer 2 ----
  hipLaunchKernelGGL(gemm512_mfma, dim3((N + 127) / 128, 4), dim3(256), 0, stream,
                     Xhi, Xlo, Wth, Wtl, A, N);
  hipLaunchKernelGGL(alpha_kernel, dim3(N), dim3(128), 0, stream, A, a2s, a2d, as, ad);
  hipLaunchKernelGGL((fused_aggregate_kernel<true, false>), dim3(N), dim3(128), 0, stream,
                     A, as, ad, src_s, offs, b2, Bbuf,
                     (unsigned short*)nullptr, (unsigned short*)nullptr);

  // ---- layer 3 ----
  hipLaunchKernelGGL(gemm3_kernel, dim3((N + 3) / 4), dim3(256), 0, stream, Bbuf, W3, h3, N);
  hipLaunchKernelGGL(alpha3_kernel, dim3(nhGrid), dim3(256), 0, stream, h3, a3s, a3d, as, ad, N);
  hipLaunchKernelGGL(fused_aggregate3_kernel, dim3(nhGrid), dim3(256), 0, stream,
                     h3, as, ad, src_s, offs, b3, (float*)d_out, N);
}

// Round 12
// 924.594 us; speedup vs baseline: 7.0904x; 1.0715x over previous
//
#include <hip/hip_runtime.h>

#define NEG_SLOPE 0.2f

constexpr int F = 512;    // heads * channels
constexpr int F_IN = 30;

typedef short bfrag __attribute__((ext_vector_type(8)));   // 8 bf16 = 4 VGPR
typedef float f32x4 __attribute__((ext_vector_type(4)));

__device__ __forceinline__ unsigned short bf16_rne(float v) {
  unsigned u = __float_as_uint(v);
  u += 0x7FFF + ((u >> 16) & 1);
  return (unsigned short)(u >> 16);
}
__device__ __forceinline__ float bf16f(unsigned short h) {
  return __uint_as_float(((unsigned)h) << 16);
}

// ---------------- CSR build ----------------

__global__ void hist_kernel(const int* __restrict__ ei, int* __restrict__ counts,
                            int N, int E) {
  int e = blockIdx.x * blockDim.x + threadIdx.x;
  int Et = E + N;
  if (e >= Et) return;
  int d = (e < E) ? ei[E + e] : (e - E);
  atomicAdd(&counts[d], 1);
}

// hierarchical scan: per-block scan -> scan of block sums -> add
__global__ void blockscan_kernel(const int* __restrict__ counts, int* __restrict__ offsets,
                                 int* __restrict__ bsums, int n) {
  __shared__ int wsum[16];
  int tid = threadIdx.x;
  int lane = tid & 63, wid = tid >> 6;
  int i = blockIdx.x * 1024 + tid;
  int v = (i < n) ? counts[i] : 0;
  int x = v;
#pragma unroll
  for (int d = 1; d < 64; d <<= 1) {
    int t2 = __shfl_up(x, d);
    if (lane >= d) x += t2;
  }
  if (lane == 63) wsum[wid] = x;
  __syncthreads();
  if (wid == 0) {
    int ws = (lane < 16) ? wsum[lane] : 0;
#pragma unroll
    for (int d = 1; d < 16; d <<= 1) {
      int t2 = __shfl_up(ws, d);
      if (lane >= d) ws += t2;
    }
    if (lane < 16) wsum[lane] = ws;
  }
  __syncthreads();
  int excl = ((wid > 0) ? wsum[wid - 1] : 0) + x - v;
  if (i < n) offsets[i] = excl;
  if (tid == 0) bsums[blockIdx.x] = wsum[15];
}

__global__ void sumscan_kernel(const int* __restrict__ bsums, int* __restrict__ boffs, int nb) {
  __shared__ int wsum[16];
  int tid = threadIdx.x;
  int lane = tid & 63, wid = tid >> 6;
  int v = (tid < nb) ? bsums[tid] : 0;
  int x = v;
#pragma unroll
  for (int d = 1; d < 64; d <<= 1) {
    int t2 = __shfl_up(x, d);
    if (lane >= d) x += t2;
  }
  if (lane == 63) wsum[wid] = x;
  __syncthreads();
  if (wid == 0) {
    int ws = (lane < 16) ? wsum[lane] : 0;
#pragma unroll
    for (int d = 1; d < 16; d <<= 1) {
      int t2 = __shfl_up(ws, d);
      if (lane >= d) ws += t2;
    }
    if (lane < 16) wsum[lane] = ws;
  }
  __syncthreads();
  int excl = ((wid > 0) ? wsum[wid - 1] : 0) + x - v;
  if (tid <= nb) boffs[tid] = (tid < nb) ? excl : wsum[15];
  if (tid == 0 && nb == 1024) boffs[1024] = wsum[15];
}

__global__ void scanadd_kernel(int* __restrict__ offsets, const int* __restrict__ boffs,
                               int* __restrict__ cursor, int n, int nb) {
  int i = blockIdx.x * blockDim.x + threadIdx.x;
  if (i < n) {
    int o = offsets[i] + boffs[i >> 10];
    offsets[i] = o;
    cursor[i] = o;
  } else if (i == n) {
    offsets[n] = boffs[nb];
  }
}

__global__ void scatter_kernel(const int* __restrict__ ei, int* __restrict__ cursor,
                               int* __restrict__ src_s, int N, int E) {
  int e = blockIdx.x * blockDim.x + threadIdx.x;
  int Et = E + N;
  if (e >= Et) return;
  int s, d;
  if (e < E) { s = ei[e]; d = ei[E + e]; } else { s = e - E; d = e - E; }
  int p = atomicAdd(&cursor[d], 1);
  src_s[p] = s;
}

// Canonicalize within-segment order for determinism across graph replays.
__global__ void segsort_kernel(int* __restrict__ src_s, const int* __restrict__ off, int N) {
  int n = blockIdx.x * blockDim.x + threadIdx.x;
  if (n >= N) return;
  int p0 = off[n], p1 = off[n + 1];
  for (int i = p0 + 1; i < p1; ++i) {
    int key = src_s[i];
    int j = i - 1;
    while (j >= p0 && src_s[j] > key) { src_s[j + 1] = src_s[j]; --j; }
    src_s[j + 1] = key;
  }
}

// ---------------- GEMM (layer1, K=30) + fused alpha epilogue ----------------
// block = 16 rows x 512 cols; 32-lane groups align with heads -> shfl reduce.

__global__ void gemm30_kernel(const float* __restrict__ X, const float* __restrict__ W,
                              const float* __restrict__ a_s, const float* __restrict__ a_d,
                              float* __restrict__ out,
                              float* __restrict__ as_o, float* __restrict__ ad_o, int N) {
  __shared__ float xs[16][F_IN];
  int row0 = blockIdx.x * 16;
  int tid = threadIdx.x;
  for (int i = tid; i < 16 * F_IN; i += 256) {
    int r = i / F_IN, k = i - r * F_IN;
    int row = row0 + r;
    xs[r][k] = (row < N) ? X[(size_t)row * F_IN + k] : 0.f;
  }
  __syncthreads();
  int cg = tid & 127;
  int rg = tid >> 7;
  int c0 = cg * 4;
  float4 acc[8];
#pragma unroll
  for (int r = 0; r < 8; ++r) acc[r] = make_float4(0.f, 0.f, 0.f, 0.f);
#pragma unroll 2
  for (int k = 0; k < F_IN; ++k) {
    float4 w = *(const float4*)(W + (size_t)k * F + c0);
#pragma unroll
    for (int r = 0; r < 8; ++r) {
      float xv = xs[rg * 8 + r][k];
      acc[r].x += xv * w.x; acc[r].y += xv * w.y;
      acc[r].z += xv * w.z; acc[r].w += xv * w.w;
    }
  }
#pragma unroll
  for (int r = 0; r < 8; ++r) {
    int row = row0 + rg * 8 + r;
    if (row < N) *(float4*)(out + (size_t)row * F + c0) = acc[r];
  }
  // fused alpha: cols c0..c0+3 lie in head hd; reduce over the 32-lane group
  int hd = cg >> 5;
  float4 s4 = *(const float4*)(a_s + c0);     // a_src flat[512] indexed by col
  float4 d4 = *(const float4*)(a_d + c0);
#pragma unroll
  for (int r = 0; r < 8; ++r) {
    float ps = acc[r].x * s4.x + acc[r].y * s4.y + acc[r].z * s4.z + acc[r].w * s4.w;
    float pd = acc[r].x * d4.x + acc[r].y * d4.y + acc[r].z * d4.z + acc[r].w * d4.w;
#pragma unroll
    for (int o = 1; o < 32; o <<= 1) {
      ps += __shfl_xor(ps, o, 32);
      pd += __shfl_xor(pd, o, 32);
    }
    if ((tid & 31) == 0) {
      int row = row0 + rg * 8 + r;
      if (row < N) { as_o[row * 4 + hd] = ps; ad_o[row * 4 + hd] = pd; }
    }
  }
}

// ---------------- W2 split + transpose ----------------

__global__ void wsplit_kernel(const float* __restrict__ W,
                              unsigned short* __restrict__ Wth,
                              unsigned short* __restrict__ Wtl) {
  __shared__ float t[64][65];
  int bx = blockIdx.x & 7, by = blockIdx.x >> 3;
  int tid = threadIdx.x;
#pragma unroll
  for (int i = 0; i < 16; ++i) {
    int idx = tid + i * 256;
    int r = idx >> 6, c = idx & 63;
    t[r][c] = W[(size_t)(by * 64 + r) * 512 + bx * 64 + c];
  }
  __syncthreads();
#pragma unroll
  for (int i = 0; i < 16; ++i) {
    int idx = tid + i * 256;
    int r = idx >> 6, c = idx & 63;
    float v = t[c][r];
    unsigned short hi = bf16_rne(v);
    unsigned short lo = bf16_rne(v - bf16f(hi));
    size_t o = (size_t)(bx * 64 + r) * 512 + by * 64 + c;
    Wth[o] = hi; Wtl[o] = lo;
  }
}

// ---------------- GEMM (layer2, K=512) via MFMA + fused alpha epilogue ------
// block cols (col0 = by*128) == head `by` exactly -> in-block alpha reduce.

__global__ void gemm512_mfma(const unsigned short* __restrict__ Xhi,
                             const unsigned short* __restrict__ Xlo,
                             const unsigned short* __restrict__ Wth,
                             const unsigned short* __restrict__ Wtl,
                             const float* __restrict__ a_s, const float* __restrict__ a_d,
                             float* __restrict__ out,
                             float* __restrict__ as_o, float* __restrict__ ad_o, int N) {
  __shared__ int4 lds4[2048];               // 32 KB
  char* lds = (char*)lds4;
  const int tid = threadIdx.x;
  const int wid = tid >> 6;
  const int lane = tid & 63;
  const int row0 = blockIdx.x * 128;
  const int by = blockIdx.y;
  const int col0 = by * 128;
  const int wr = wid >> 1, wc = wid & 1;

  const unsigned short* sb = (wid == 0) ? Xhi : (wid == 1) ? Xlo : (wid == 2) ? Wth : Wtl;
  const int tile0 = (wid < 2) ? row0 : col0;
  const int chunk = (lane & 3) ^ ((lane >> 3) & 3);
  const unsigned short* lanesrc = sb + (size_t)(tile0 + (lane >> 2)) * 512 + chunk * 8;
  char* ldst = lds + wid * 8192;

  const int g = lane >> 4;
  int aoff[4], boff[4];
#pragma unroll
  for (int m = 0; m < 4; ++m) {
    int r = wr * 64 + m * 16 + (lane & 15);
    aoff[m] = r * 64 + ((g ^ ((r >> 1) & 3)) << 4);
    int c = wc * 64 + m * 16 + (lane & 15);
    boff[m] = c * 64 + ((g ^ ((c >> 1) & 3)) << 4);
  }

  f32x4 acc[4][4];
#pragma unroll
  for (int m = 0; m < 4; ++m)
#pragma unroll
    for (int n = 0; n < 4; ++n) acc[m][n] = f32x4{0.f, 0.f, 0.f, 0.f};

  for (int kc = 0; kc < 16; ++kc) {
#pragma unroll
    for (int i = 0; i < 8; ++i) {
      __builtin_amdgcn_global_load_lds(
          (const __attribute__((address_space(1))) void*)(lanesrc + i * 8192 + kc * 32),
          (__attribute__((address_space(3))) void*)(ldst + i * 1024), 16, 0, 0);
    }
    __syncthreads();
    bfrag ah[4], al[4], bh[4], bl[4];
#pragma unroll
    for (int m = 0; m < 4; ++m) {
      ah[m] = *(const bfrag*)(lds + aoff[m]);
      al[m] = *(const bfrag*)(lds + 8192 + aoff[m]);
      bh[m] = *(const bfrag*)(lds + 16384 + boff[m]);
      bl[m] = *(const bfrag*)(lds + 24576 + boff[m]);
    }
#pragma unroll
    for (int m = 0; m < 4; ++m)
#pragma unroll
      for (int n = 0; n < 4; ++n) {
        acc[m][n] = __builtin_amdgcn_mfma_f32_16x16x32_bf16(al[m], bh[n], acc[m][n], 0, 0, 0);
        acc[m][n] = __builtin_amdgcn_mfma_f32_16x16x32_bf16(ah[m], bl[n], acc[m][n], 0, 0, 0);
        acc[m][n] = __builtin_amdgcn_mfma_f32_16x16x32_bf16(ah[m], bh[n], acc[m][n], 0, 0, 0);
      }
    __syncthreads();
  }

  const int crow = (lane >> 4) * 4, ccol = lane & 15;
#pragma unroll
  for (int m = 0; m < 4; ++m) {
    int Rb = row0 + wr * 64 + m * 16 + crow;
#pragma unroll
    for (int n = 0; n < 4; ++n) {
      int C = col0 + wc * 64 + n * 16 + ccol;
#pragma unroll
      for (int q = 0; q < 4; ++q) {
        int R = Rb + q;
        if (R < N) out[(size_t)R * F + C] = acc[m][n][q];
      }
    }
  }

  // fused alpha epilogue (head == by): per-row dot over this block's 128 cols
  float cs[4], cd[4];
#pragma unroll
  for (int n = 0; n < 4; ++n) {
    cs[n] = a_s[col0 + wc * 64 + n * 16 + (lane & 15)];
    cd[n] = a_d[col0 + wc * 64 + n * 16 + (lane & 15)];
  }
  float* red = (float*)lds;
#pragma unroll
  for (int m = 0; m < 4; ++m) {
#pragma unroll
    for (int q = 0; q < 4; ++q) {
      float ps = 0.f, pd = 0.f;
#pragma unroll
      for (int n = 0; n < 4; ++n) {
        ps += acc[m][n][q] * cs[n];
        pd += acc[m][n][q] * cd[n];
      }
#pragma unroll
      for (int o = 1; o < 16; o <<= 1) {
        ps += __shfl_xor(ps, o, 16);
        pd += __shfl_xor(pd, o, 16);
      }
      if ((lane & 15) == 0) {
        int rl = m * 16 + (lane >> 4) * 4 + q;   // 0..63 within wr's row group
        red[((wr * 2 + wc) * 64 + rl) * 2 + 0] = ps;
        red[((wr * 2 + wc) * 64 + rl) * 2 + 1] = pd;
      }
    }
  }
  __syncthreads();
  if (tid < 128) {
    int wrr = tid >> 6, rl = tid & 63;
    float vs = red[((wrr * 2 + 0) * 64 + rl) * 2] + red[((wrr * 2 + 1) * 64 + rl) * 2];
    float vd = red[((wrr * 2 + 0) * 64 + rl) * 2 + 1] + red[((wrr * 2 + 1) * 64 + rl) * 2 + 1];
    int row = row0 + wrr * 64 + rl;
    if (row < N) { as_o[row * 4 + by] = vs; ad_o[row * 4 + by] = vd; }
  }
}

// GEMM for layer3 + fused alpha3 epilogue
__global__ void gemm3_kernel(const float* __restrict__ X, const float* __restrict__ W3,
                             const float* __restrict__ a3s, const float* __restrict__ a3d,
                             float* __restrict__ h3,
                             float* __restrict__ as_o, float* __restrict__ ad_o, int N) {
  int n = blockIdx.x * 4 + (threadIdx.x >> 6);
  int lane = threadIdx.x & 63;
  if (n >= N) return;
  float acc[4] = {0.f, 0.f, 0.f, 0.f};
  for (int k = lane; k < F; k += 64) {
    float xv = X[(size_t)n * F + k];
#pragma unroll
    for (int j = 0; j < 4; ++j) acc[j] += xv * W3[k * 4 + j];
  }
#pragma unroll
  for (int j = 0; j < 4; ++j)
    for (int off = 32; off > 0; off >>= 1) acc[j] += __shfl_down(acc[j], off);
  if (lane == 0) {
    float4 o; o.x = acc[0]; o.y = acc[1]; o.z = acc[2]; o.w = acc[3];
    *(float4*)(h3 + (size_t)n * 4) = o;
    float4 so, dd;
    so.x = acc[0] * a3s[0]; so.y = acc[1] * a3s[1];
    so.z = acc[2] * a3s[2]; so.w = acc[3] * a3s[3];
    dd.x = acc[0] * a3d[0]; dd.y = acc[1] * a3d[1];
    dd.z = acc[2] * a3d[2]; dd.w = acc[3] * a3d[3];
    *(float4*)(as_o + (size_t)n * 4) = so;
    *(float4*)(ad_o + (size_t)n * 4) = dd;
  }
}

// ---------------- fused softmax-stats + aggregate ----------------

__device__ __forceinline__ float leaky(float v) { return v > 0.f ? v : NEG_SLOPE * v; }

__device__ __forceinline__ void fma4(float4& a, float s, const float4& b) {
  a.x += s * b.x; a.y += s * b.y; a.z += s * b.z; a.w += s * b.w;
}

template <bool RELU, bool SPLIT>
__global__ void fused_aggregate_kernel(const float* __restrict__ hsrc,
                                       const float* __restrict__ as, const float* __restrict__ ad,
                                       const int* __restrict__ src_s, const int* __restrict__ off,
                                       const float* __restrict__ bias, float* __restrict__ out,
                                       unsigned short* __restrict__ oh, unsigned short* __restrict__ ol) {
  int n = blockIdx.x;
  int tid = threadIdx.x;
  int head = tid >> 5;
  int l32 = tid & 31;
  int c0 = tid * 4;
  int p0 = off[n], p1 = off[n + 1];
  float adv = ad[n * 4 + head];

  // phase 1: per-head online stats over strided edge partition
  float m = -1e30f, s = 0.f;
  for (int p = p0 + l32; p < p1; p += 32) {
    float e = leaky(as[src_s[p] * 4 + head] + adv);
    if (e > m) { s *= __expf(m - e); m = e; }
    s += __expf(e - m);
  }
#pragma unroll
  for (int o = 16; o > 0; o >>= 1) {
    float mo = __shfl_down(m, o, 32);
    float so = __shfl_down(s, o, 32);
    float mn = fmaxf(m, mo);
    s = s * __expf(m - mn) + so * __expf(mo - mn);
    m = mn;
  }
  m = __shfl(m, 0, 32);
  s = __shfl(s, 0, 32);
  float inv = 1.f / (s + 1e-16f);

  // phase 2: gather + weighted sum (sequential order -> deterministic)
  float4 acc = make_float4(0.f, 0.f, 0.f, 0.f);
#pragma unroll 2
  for (int p = p0; p < p1; ++p) {
    int sp = src_s[p];
    float a = __expf(leaky(as[sp * 4 + head] + adv) - m) * inv;
    float4 hv = *(const float4*)(hsrc + (size_t)sp * F + c0);
    fma4(acc, a, hv);
  }
  float4 bv = *(const float4*)(bias + c0);
  acc.x += bv.x; acc.y += bv.y; acc.z += bv.z; acc.w += bv.w;
  if (RELU) {
    acc.x = fmaxf(acc.x, 0.f); acc.y = fmaxf(acc.y, 0.f);
    acc.z = fmaxf(acc.z, 0.f); acc.w = fmaxf(acc.w, 0.f);
  }
  if (SPLIT) {
    ushort4 hv4, lv4;
    hv4.x = bf16_rne(acc.x); lv4.x = bf16_rne(acc.x - bf16f(hv4.x));
    hv4.y = bf16_rne(acc.y); lv4.y = bf16_rne(acc.y - bf16f(hv4.y));
    hv4.z = bf16_rne(acc.z); lv4.z = bf16_rne(acc.z - bf16f(hv4.z));
    hv4.w = bf16_rne(acc.w); lv4.w = bf16_rne(acc.w - bf16f(hv4.w));
    *(ushort4*)(oh + (size_t)n * F + c0) = hv4;
    *(ushort4*)(ol + (size_t)n * F + c0) = lv4;
  } else {
    *(float4*)(out + (size_t)n * F + c0) = acc;
  }
}

// layer3: one thread per (node, head); two serial passes
__global__ void fused_aggregate3_kernel(const float* __restrict__ h3,
                                        const float* __restrict__ as, const float* __restrict__ ad,
                                        const int* __restrict__ src_s, const int* __restrict__ off,
                                        const float* __restrict__ b3, float* __restrict__ out, int N) {
  int t = blockIdx.x * blockDim.x + threadIdx.x;
  if (t >= N * 4) return;
  int n = t >> 2, head = t & 3;
  int p0 = off[n], p1 = off[n + 1];
  float adv = ad[t];
  float m = -1e30f, s = 0.f;
  for (int p = p0; p < p1; ++p) {
    float e = leaky(as[src_s[p] * 4 + head] + adv);
    if (e > m) { s *= __expf(m - e); m = e; }
    s += __expf(e - m);
  }
  float inv = 1.f / (s + 1e-16f);
  float acc = 0.f;
  for (int p = p0; p < p1; ++p) {
    int sp = src_s[p];
    float a = __expf(leaky(as[sp * 4 + head] + adv) - m) * inv;
    acc += a * h3[(size_t)sp * 4 + head];
  }
  acc += __shfl_down(acc, 1);
  acc += __shfl_down(acc, 2);
  if (head == 0) out[n] = acc * 0.25f + b3[0];
}

// ---------------- host orchestration ----------------

extern "C" void kernel_launch(void* const* d_in, const int* in_sizes, int n_in,
                              void* d_out, int out_size, void* d_ws, size_t ws_size,
                              hipStream_t stream) {
  const float* x   = (const float*)d_in[0];
  const int*   ei  = (const int*)d_in[1];
  const float* W1  = (const float*)d_in[2];
  const float* a1s = (const float*)d_in[3];
  const float* a1d = (const float*)d_in[4];
  const float* b1  = (const float*)d_in[5];
  const float* W2  = (const float*)d_in[6];
  const float* a2s = (const float*)d_in[7];
  const float* a2d = (const float*)d_in[8];
  const float* b2  = (const float*)d_in[9];
  const float* W3  = (const float*)d_in[10];
  const float* a3s = (const float*)d_in[11];
  const float* a3d = (const float*)d_in[12];
  const float* b3  = (const float*)d_in[13];

  const int N = in_sizes[0] / F_IN;
  const int E = in_sizes[1] / 2;
  const int Et = E + N;
  const int Npad = (N + 127) & ~127;
  const int nb = (N + 1023) >> 10;

  char* base = (char*)d_ws;
  size_t off = 0;
  auto alloc = [&](size_t bytes) {
    void* p = base + off;
    off = (off + bytes + 255) & ~(size_t)255;
    return p;
  };
  float* A      = (float*)alloc((size_t)N * F * sizeof(float));
  float* U      = (float*)alloc((size_t)Npad * F * sizeof(float));
  unsigned short* Xhi = (unsigned short*)U;
  unsigned short* Xlo = Xhi + (size_t)Npad * F;
  float* Bbuf   = U;
  int*   src_s  = (int*)alloc((size_t)Et * sizeof(int));
  int*   counts = (int*)alloc((size_t)N * sizeof(int));
  int*   offs   = (int*)alloc((size_t)(N + 1) * sizeof(int));
  int*   cursor = (int*)alloc((size_t)N * sizeof(int));
  int*   bsums  = (int*)alloc((size_t)1025 * sizeof(int));
  int*   boffs  = (int*)alloc((size_t)1026 * sizeof(int));
  float* as     = (float*)alloc((size_t)N * 4 * sizeof(float));
  float* ad     = (float*)alloc((size_t)N * 4 * sizeof(float));
  float* h3     = (float*)alloc((size_t)N * 4 * sizeof(float));
  unsigned short* Wth = (unsigned short*)alloc((size_t)512 * 512 * sizeof(unsigned short));
  unsigned short* Wtl = (unsigned short*)alloc((size_t)512 * 512 * sizeof(unsigned short));

  // ---- CSR build + W2 split ----
  hipMemsetAsync(counts, 0, (size_t)N * sizeof(int), stream);
  {
    int gg = (Et + 255) / 256;
    hipLaunchKernelGGL(hist_kernel, dim3(gg), dim3(256), 0, stream, ei, counts, N, E);
    hipLaunchKernelGGL(blockscan_kernel, dim3(nb), dim3(1024), 0, stream, counts, offs, bsums, N);
    hipLaunchKernelGGL(sumscan_kernel, dim3(1), dim3(1024), 0, stream, bsums, boffs, nb);
    hipLaunchKernelGGL(scanadd_kernel, dim3((N + 256) / 256), dim3(256), 0, stream, offs, boffs, cursor, N, nb);
    hipLaunchKernelGGL(scatter_kernel, dim3(gg), dim3(256), 0, stream, ei, cursor, src_s, N, E);
    hipLaunchKernelGGL(segsort_kernel, dim3((N + 255) / 256), dim3(256), 0, stream, src_s, offs, N);
    hipLaunchKernelGGL(wsplit_kernel, dim3(64), dim3(256), 0, stream, W2, Wth, Wtl);
  }

  int nhGrid = (N * 4 + 255) / 256;

  // ---- layer 1 ----
  hipLaunchKernelGGL(gemm30_kernel, dim3((N + 15) / 16), dim3(256), 0, stream,
                     x, W1, a1s, a1d, A, as, ad, N);
  hipLaunchKernelGGL((fused_aggregate_kernel<true, true>), dim3(N), dim3(128), 0, stream,
                     A, as, ad, src_s, offs, b1, (float*)nullptr, Xhi, Xlo);

  // ---- layer 2 ----
  hipLaunchKernelGGL(gemm512_mfma, dim3((N + 127) / 128, 4), dim3(256), 0, stream,
                     Xhi, Xlo, Wth, Wtl, a2s, a2d, A, as, ad, N);
  hipLaunchKernelGGL((fused_aggregate_kernel<true, false>), dim3(N), dim3(128), 0, stream,
                     A, as, ad, src_s, offs, b2, Bbuf,
                     (unsigned short*)nullptr, (unsigned short*)nullptr);

  // ---- layer 3 ----
  hipLaunchKernelGGL(gemm3_kernel, dim3((N + 3) / 4), dim3(256), 0, stream,
                     Bbuf, W3, a3s, a3d, h3, as, ad, N);
  hipLaunchKernelGGL(fused_aggregate3_kernel, dim3(nhGrid), dim3(256), 0, stream,
                     h3, as, ad, src_s, offs, b3, (float*)d_out, N);
}

// Round 13
// 918.704 us; speedup vs baseline: 7.1359x; 1.0064x over previous
//
#include <hip/hip_runtime.h>

#define NEG_SLOPE 0.2f

constexpr int F = 512;    // heads * channels
constexpr int F_IN = 30;
constexpr int DMAX = 512; // LDS-staged max degree (fallback path beyond)

typedef short bfrag __attribute__((ext_vector_type(8)));   // 8 bf16 = 4 VGPR
typedef float f32x4 __attribute__((ext_vector_type(4)));

__device__ __forceinline__ unsigned short bf16_rne(float v) {
  unsigned u = __float_as_uint(v);
  u += 0x7FFF + ((u >> 16) & 1);
  return (unsigned short)(u >> 16);
}
__device__ __forceinline__ float bf16f(unsigned short h) {
  return __uint_as_float(((unsigned)h) << 16);
}

// ---------------- CSR build ----------------

__global__ void hist_kernel(const int* __restrict__ ei, int* __restrict__ counts,
                            int N, int E) {
  int e = blockIdx.x * blockDim.x + threadIdx.x;
  int Et = E + N;
  if (e >= Et) return;
  int d = (e < E) ? ei[E + e] : (e - E);
  atomicAdd(&counts[d], 1);
}

// hierarchical scan: per-block scan -> scan of block sums -> add
__global__ void blockscan_kernel(const int* __restrict__ counts, int* __restrict__ offsets,
                                 int* __restrict__ bsums, int n) {
  __shared__ int wsum[16];
  int tid = threadIdx.x;
  int lane = tid & 63, wid = tid >> 6;
  int i = blockIdx.x * 1024 + tid;
  int v = (i < n) ? counts[i] : 0;
  int x = v;
#pragma unroll
  for (int d = 1; d < 64; d <<= 1) {
    int t2 = __shfl_up(x, d);
    if (lane >= d) x += t2;
  }
  if (lane == 63) wsum[wid] = x;
  __syncthreads();
  if (wid == 0) {
    int ws = (lane < 16) ? wsum[lane] : 0;
#pragma unroll
    for (int d = 1; d < 16; d <<= 1) {
      int t2 = __shfl_up(ws, d);
      if (lane >= d) ws += t2;
    }
    if (lane < 16) wsum[lane] = ws;
  }
  __syncthreads();
  int excl = ((wid > 0) ? wsum[wid - 1] : 0) + x - v;
  if (i < n) offsets[i] = excl;
  if (tid == 0) bsums[blockIdx.x] = wsum[15];
}

__global__ void sumscan_kernel(const int* __restrict__ bsums, int* __restrict__ boffs, int nb) {
  __shared__ int wsum[16];
  int tid = threadIdx.x;
  int lane = tid & 63, wid = tid >> 6;
  int v = (tid < nb) ? bsums[tid] : 0;
  int x = v;
#pragma unroll
  for (int d = 1; d < 64; d <<= 1) {
    int t2 = __shfl_up(x, d);
    if (lane >= d) x += t2;
  }
  if (lane == 63) wsum[wid] = x;
  __syncthreads();
  if (wid == 0) {
    int ws = (lane < 16) ? wsum[lane] : 0;
#pragma unroll
    for (int d = 1; d < 16; d <<= 1) {
      int t2 = __shfl_up(ws, d);
      if (lane >= d) ws += t2;
    }
    if (lane < 16) wsum[lane] = ws;
  }
  __syncthreads();
  int excl = ((wid > 0) ? wsum[wid - 1] : 0) + x - v;
  if (tid <= nb) boffs[tid] = (tid < nb) ? excl : wsum[15];
  if (tid == 0 && nb == 1024) boffs[1024] = wsum[15];
}

__global__ void scanadd_kernel(int* __restrict__ offsets, const int* __restrict__ boffs,
                               int* __restrict__ cursor, int n, int nb) {
  int i = blockIdx.x * blockDim.x + threadIdx.x;
  if (i < n) {
    int o = offsets[i] + boffs[i >> 10];
    offsets[i] = o;
    cursor[i] = o;
  } else if (i == n) {
    offsets[n] = boffs[nb];
  }
}

__global__ void scatter_kernel(const int* __restrict__ ei, int* __restrict__ cursor,
                               int* __restrict__ src_s, int N, int E) {
  int e = blockIdx.x * blockDim.x + threadIdx.x;
  int Et = E + N;
  if (e >= Et) return;
  int s, d;
  if (e < E) { s = ei[e]; d = ei[E + e]; } else { s = e - E; d = e - E; }
  int p = atomicAdd(&cursor[d], 1);
  src_s[p] = s;
}

// Canonicalize within-segment order for determinism across graph replays.
__global__ void segsort_kernel(int* __restrict__ src_s, const int* __restrict__ off, int N) {
  int n = blockIdx.x * blockDim.x + threadIdx.x;
  if (n >= N) return;
  int p0 = off[n], p1 = off[n + 1];
  for (int i = p0 + 1; i < p1; ++i) {
    int key = src_s[i];
    int j = i - 1;
    while (j >= p0 && src_s[j] > key) { src_s[j + 1] = src_s[j]; --j; }
    src_s[j + 1] = key;
  }
}

// ---------------- GEMM (layer1, K=30) + fused alpha epilogue ----------------

__global__ void gemm30_kernel(const float* __restrict__ X, const float* __restrict__ W,
                              const float* __restrict__ a_s, const float* __restrict__ a_d,
                              float* __restrict__ out,
                              float* __restrict__ as_o, float* __restrict__ ad_o, int N) {
  __shared__ float xs[16][F_IN];
  int row0 = blockIdx.x * 16;
  int tid = threadIdx.x;
  for (int i = tid; i < 16 * F_IN; i += 256) {
    int r = i / F_IN, k = i - r * F_IN;
    int row = row0 + r;
    xs[r][k] = (row < N) ? X[(size_t)row * F_IN + k] : 0.f;
  }
  __syncthreads();
  int cg = tid & 127;
  int rg = tid >> 7;
  int c0 = cg * 4;
  float4 acc[8];
#pragma unroll
  for (int r = 0; r < 8; ++r) acc[r] = make_float4(0.f, 0.f, 0.f, 0.f);
#pragma unroll 2
  for (int k = 0; k < F_IN; ++k) {
    float4 w = *(const float4*)(W + (size_t)k * F + c0);
#pragma unroll
    for (int r = 0; r < 8; ++r) {
      float xv = xs[rg * 8 + r][k];
      acc[r].x += xv * w.x; acc[r].y += xv * w.y;
      acc[r].z += xv * w.z; acc[r].w += xv * w.w;
    }
  }
#pragma unroll
  for (int r = 0; r < 8; ++r) {
    int row = row0 + rg * 8 + r;
    if (row < N) *(float4*)(out + (size_t)row * F + c0) = acc[r];
  }
  int hd = cg >> 5;
  float4 s4 = *(const float4*)(a_s + c0);
  float4 d4 = *(const float4*)(a_d + c0);
#pragma unroll
  for (int r = 0; r < 8; ++r) {
    float ps = acc[r].x * s4.x + acc[r].y * s4.y + acc[r].z * s4.z + acc[r].w * s4.w;
    float pd = acc[r].x * d4.x + acc[r].y * d4.y + acc[r].z * d4.z + acc[r].w * d4.w;
#pragma unroll
    for (int o = 1; o < 32; o <<= 1) {
      ps += __shfl_xor(ps, o, 32);
      pd += __shfl_xor(pd, o, 32);
    }
    if ((tid & 31) == 0) {
      int row = row0 + rg * 8 + r;
      if (row < N) { as_o[row * 4 + hd] = ps; ad_o[row * 4 + hd] = pd; }
    }
  }
}

// ---------------- W2 split + transpose ----------------

__global__ void wsplit_kernel(const float* __restrict__ W,
                              unsigned short* __restrict__ Wth,
                              unsigned short* __restrict__ Wtl) {
  __shared__ float t[64][65];
  int bx = blockIdx.x & 7, by = blockIdx.x >> 3;
  int tid = threadIdx.x;
#pragma unroll
  for (int i = 0; i < 16; ++i) {
    int idx = tid + i * 256;
    int r = idx >> 6, c = idx & 63;
    t[r][c] = W[(size_t)(by * 64 + r) * 512 + bx * 64 + c];
  }
  __syncthreads();
#pragma unroll
  for (int i = 0; i < 16; ++i) {
    int idx = tid + i * 256;
    int r = idx >> 6, c = idx & 63;
    float v = t[c][r];
    unsigned short hi = bf16_rne(v);
    unsigned short lo = bf16_rne(v - bf16f(hi));
    size_t o = (size_t)(bx * 64 + r) * 512 + by * 64 + c;
    Wth[o] = hi; Wtl[o] = lo;
  }
}

// ---------------- GEMM (layer2, K=512) via MFMA + fused alpha epilogue ------

__global__ void gemm512_mfma(const unsigned short* __restrict__ Xhi,
                             const unsigned short* __restrict__ Xlo,
                             const unsigned short* __restrict__ Wth,
                             const unsigned short* __restrict__ Wtl,
                             const float* __restrict__ a_s, const float* __restrict__ a_d,
                             float* __restrict__ out,
                             float* __restrict__ as_o, float* __restrict__ ad_o, int N) {
  __shared__ int4 lds4[2048];               // 32 KB
  char* lds = (char*)lds4;
  const int tid = threadIdx.x;
  const int wid = tid >> 6;
  const int lane = tid & 63;
  const int row0 = blockIdx.x * 128;
  const int by = blockIdx.y;
  const int col0 = by * 128;
  const int wr = wid >> 1, wc = wid & 1;

  const unsigned short* sb = (wid == 0) ? Xhi : (wid == 1) ? Xlo : (wid == 2) ? Wth : Wtl;
  const int tile0 = (wid < 2) ? row0 : col0;
  const int chunk = (lane & 3) ^ ((lane >> 3) & 3);
  const unsigned short* lanesrc = sb + (size_t)(tile0 + (lane >> 2)) * 512 + chunk * 8;
  char* ldst = lds + wid * 8192;

  const int g = lane >> 4;
  int aoff[4], boff[4];
#pragma unroll
  for (int m = 0; m < 4; ++m) {
    int r = wr * 64 + m * 16 + (lane & 15);
    aoff[m] = r * 64 + ((g ^ ((r >> 1) & 3)) << 4);
    int c = wc * 64 + m * 16 + (lane & 15);
    boff[m] = c * 64 + ((g ^ ((c >> 1) & 3)) << 4);
  }

  f32x4 acc[4][4];
#pragma unroll
  for (int m = 0; m < 4; ++m)
#pragma unroll
    for (int n = 0; n < 4; ++n) acc[m][n] = f32x4{0.f, 0.f, 0.f, 0.f};

  for (int kc = 0; kc < 16; ++kc) {
#pragma unroll
    for (int i = 0; i < 8; ++i) {
      __builtin_amdgcn_global_load_lds(
          (const __attribute__((address_space(1))) void*)(lanesrc + i * 8192 + kc * 32),
          (__attribute__((address_space(3))) void*)(ldst + i * 1024), 16, 0, 0);
    }
    __syncthreads();
    bfrag ah[4], al[4], bh[4], bl[4];
#pragma unroll
    for (int m = 0; m < 4; ++m) {
      ah[m] = *(const bfrag*)(lds + aoff[m]);
      al[m] = *(const bfrag*)(lds + 8192 + aoff[m]);
      bh[m] = *(const bfrag*)(lds + 16384 + boff[m]);
      bl[m] = *(const bfrag*)(lds + 24576 + boff[m]);
    }
#pragma unroll
    for (int m = 0; m < 4; ++m)
#pragma unroll
      for (int n = 0; n < 4; ++n) {
        acc[m][n] = __builtin_amdgcn_mfma_f32_16x16x32_bf16(al[m], bh[n], acc[m][n], 0, 0, 0);
        acc[m][n] = __builtin_amdgcn_mfma_f32_16x16x32_bf16(ah[m], bl[n], acc[m][n], 0, 0, 0);
        acc[m][n] = __builtin_amdgcn_mfma_f32_16x16x32_bf16(ah[m], bh[n], acc[m][n], 0, 0, 0);
      }
    __syncthreads();
  }

  const int crow = (lane >> 4) * 4, ccol = lane & 15;
#pragma unroll
  for (int m = 0; m < 4; ++m) {
    int Rb = row0 + wr * 64 + m * 16 + crow;
#pragma unroll
    for (int n = 0; n < 4; ++n) {
      int C = col0 + wc * 64 + n * 16 + ccol;
#pragma unroll
      for (int q = 0; q < 4; ++q) {
        int R = Rb + q;
        if (R < N) out[(size_t)R * F + C] = acc[m][n][q];
      }
    }
  }

  // fused alpha epilogue (head == by)
  float cs[4], cd[4];
#pragma unroll
  for (int n = 0; n < 4; ++n) {
    cs[n] = a_s[col0 + wc * 64 + n * 16 + (lane & 15)];
    cd[n] = a_d[col0 + wc * 64 + n * 16 + (lane & 15)];
  }
  float* red = (float*)lds;
#pragma unroll
  for (int m = 0; m < 4; ++m) {
#pragma unroll
    for (int q = 0; q < 4; ++q) {
      float ps = 0.f, pd = 0.f;
#pragma unroll
      for (int n = 0; n < 4; ++n) {
        ps += acc[m][n][q] * cs[n];
        pd += acc[m][n][q] * cd[n];
      }
#pragma unroll
      for (int o = 1; o < 16; o <<= 1) {
        ps += __shfl_xor(ps, o, 16);
        pd += __shfl_xor(pd, o, 16);
      }
      if ((lane & 15) == 0) {
        int rl = m * 16 + (lane >> 4) * 4 + q;
        red[((wr * 2 + wc) * 64 + rl) * 2 + 0] = ps;
        red[((wr * 2 + wc) * 64 + rl) * 2 + 1] = pd;
      }
    }
  }
  __syncthreads();
  if (tid < 128) {
    int wrr = tid >> 6, rl = tid & 63;
    float vs = red[((wrr * 2 + 0) * 64 + rl) * 2] + red[((wrr * 2 + 1) * 64 + rl) * 2];
    float vd = red[((wrr * 2 + 0) * 64 + rl) * 2 + 1] + red[((wrr * 2 + 1) * 64 + rl) * 2 + 1];
    int row = row0 + wrr * 64 + rl;
    if (row < N) { as_o[row * 4 + by] = vs; ad_o[row * 4 + by] = vd; }
  }
}

// GEMM for layer3 + fused alpha3 epilogue
__global__ void gemm3_kernel(const float* __restrict__ X, const float* __restrict__ W3,
                             const float* __restrict__ a3s, const float* __restrict__ a3d,
                             float* __restrict__ h3,
                             float* __restrict__ as_o, float* __restrict__ ad_o, int N) {
  int n = blockIdx.x * 4 + (threadIdx.x >> 6);
  int lane = threadIdx.x & 63;
  if (n >= N) return;
  float acc[4] = {0.f, 0.f, 0.f, 0.f};
  for (int k = lane; k < F; k += 64) {
    float xv = X[(size_t)n * F + k];
#pragma unroll
    for (int j = 0; j < 4; ++j) acc[j] += xv * W3[k * 4 + j];
  }
#pragma unroll
  for (int j = 0; j < 4; ++j)
    for (int off = 32; off > 0; off >>= 1) acc[j] += __shfl_down(acc[j], off);
  if (lane == 0) {
    float4 o; o.x = acc[0]; o.y = acc[1]; o.z = acc[2]; o.w = acc[3];
    *(float4*)(h3 + (size_t)n * 4) = o;
    float4 so, dd;
    so.x = acc[0] * a3s[0]; so.y = acc[1] * a3s[1];
    so.z = acc[2] * a3s[2]; so.w = acc[3] * a3s[3];
    dd.x = acc[0] * a3d[0]; dd.y = acc[1] * a3d[1];
    dd.z = acc[2] * a3d[2]; dd.w = acc[3] * a3d[3];
    *(float4*)(as_o + (size_t)n * 4) = so;
    *(float4*)(ad_o + (size_t)n * 4) = dd;
  }
}

// ---------------- fused softmax-stats + aggregate (LDS-staged scores) -------
// Phase A: 128 threads gather as[src] once per edge (float4), store e[h] to
//   LDS (4 padded arrays, conflict-free).
// Phase B: per-head online (m,s) from LDS, same strided partition + fixed
//   shfl tree as before (bit-identical).
// Phase C: alpha from LDS (broadcast), h-row gather + fma, sequential order.
// deg > DMAX falls back to the gather-twice path (correctness guaranteed).

__device__ __forceinline__ float leaky(float v) { return v > 0.f ? v : NEG_SLOPE * v; }

__device__ __forceinline__ void fma4(float4& a, float s, const float4& b) {
  a.x += s * b.x; a.y += s * b.y; a.z += s * b.z; a.w += s * b.w;
}

template <bool RELU, bool SPLIT>
__global__ void fused_aggregate_kernel(const float* __restrict__ hsrc,
                                       const float* __restrict__ as, const float* __restrict__ ad,
                                       const int* __restrict__ src_s, const int* __restrict__ off,
                                       const float* __restrict__ bias, float* __restrict__ out,
                                       unsigned short* __restrict__ oh, unsigned short* __restrict__ ol) {
  __shared__ float esc[4][DMAX + 8];
  int n = blockIdx.x;
  int tid = threadIdx.x;
  int head = tid >> 5;
  int l32 = tid & 31;
  int c0 = tid * 4;
  int p0 = off[n], p1 = off[n + 1];
  int deg = p1 - p0;
  float4 adv4 = *(const float4*)(ad + (size_t)n * 4);
  float adv = (head == 0) ? adv4.x : (head == 1) ? adv4.y : (head == 2) ? adv4.z : adv4.w;

  float m = -1e30f, s = 0.f;
  float4 acc = make_float4(0.f, 0.f, 0.f, 0.f);

  if (deg <= DMAX) {
    // phase A: one float4 as-gather per edge
    for (int i = tid; i < deg; i += 128) {
      int sp = src_s[p0 + i];
      float4 a4 = *(const float4*)(as + (size_t)sp * 4);
      esc[0][i] = leaky(a4.x + adv4.x);
      esc[1][i] = leaky(a4.y + adv4.y);
      esc[2][i] = leaky(a4.z + adv4.z);
      esc[3][i] = leaky(a4.w + adv4.w);
    }
    __syncthreads();
    // phase B: per-head online stats (strided 32, fixed tree)
    for (int i = l32; i < deg; i += 32) {
      float e = esc[head][i];
      if (e > m) { s *= __expf(m - e); m = e; }
      s += __expf(e - m);
    }
#pragma unroll
    for (int o = 16; o > 0; o >>= 1) {
      float mo = __shfl_down(m, o, 32);
      float so = __shfl_down(s, o, 32);
      float mn = fmaxf(m, mo);
      s = s * __expf(m - mn) + so * __expf(mo - mn);
      m = mn;
    }
    m = __shfl(m, 0, 32);
    s = __shfl(s, 0, 32);
    float inv = 1.f / (s + 1e-16f);
    // phase C: alpha from LDS, gather h rows
#pragma unroll 2
    for (int i = 0; i < deg; ++i) {
      int sp = src_s[p0 + i];
      float a = __expf(esc[head][i] - m) * inv;
      float4 hv = *(const float4*)(hsrc + (size_t)sp * F + c0);
      fma4(acc, a, hv);
    }
  } else {
    // fallback: original gather-twice path
    for (int p = p0 + l32; p < p1; p += 32) {
      float e = leaky(as[src_s[p] * 4 + head] + adv);
      if (e > m) { s *= __expf(m - e); m = e; }
      s += __expf(e - m);
    }
#pragma unroll
    for (int o = 16; o > 0; o >>= 1) {
      float mo = __shfl_down(m, o, 32);
      float so = __shfl_down(s, o, 32);
      float mn = fmaxf(m, mo);
      s = s * __expf(m - mn) + so * __expf(mo - mn);
      m = mn;
    }
    m = __shfl(m, 0, 32);
    s = __shfl(s, 0, 32);
    float inv = 1.f / (s + 1e-16f);
    for (int p = p0; p < p1; ++p) {
      int sp = src_s[p];
      float a = __expf(leaky(as[sp * 4 + head] + adv) - m) * inv;
      float4 hv = *(const float4*)(hsrc + (size_t)sp * F + c0);
      fma4(acc, a, hv);
    }
  }

  float4 bv = *(const float4*)(bias + c0);
  acc.x += bv.x; acc.y += bv.y; acc.z += bv.z; acc.w += bv.w;
  if (RELU) {
    acc.x = fmaxf(acc.x, 0.f); acc.y = fmaxf(acc.y, 0.f);
    acc.z = fmaxf(acc.z, 0.f); acc.w = fmaxf(acc.w, 0.f);
  }
  if (SPLIT) {
    ushort4 hv4, lv4;
    hv4.x = bf16_rne(acc.x); lv4.x = bf16_rne(acc.x - bf16f(hv4.x));
    hv4.y = bf16_rne(acc.y); lv4.y = bf16_rne(acc.y - bf16f(hv4.y));
    hv4.z = bf16_rne(acc.z); lv4.z = bf16_rne(acc.z - bf16f(hv4.z));
    hv4.w = bf16_rne(acc.w); lv4.w = bf16_rne(acc.w - bf16f(hv4.w));
    *(ushort4*)(oh + (size_t)n * F + c0) = hv4;
    *(ushort4*)(ol + (size_t)n * F + c0) = lv4;
  } else {
    *(float4*)(out + (size_t)n * F + c0) = acc;
  }
}

// layer3: one thread per (node, head); two serial passes (small L2-hot data)
__global__ void fused_aggregate3_kernel(const float* __restrict__ h3,
                                        const float* __restrict__ as, const float* __restrict__ ad,
                                        const int* __restrict__ src_s, const int* __restrict__ off,
                                        const float* __restrict__ b3, float* __restrict__ out, int N) {
  int t = blockIdx.x * blockDim.x + threadIdx.x;
  if (t >= N * 4) return;
  int n = t >> 2, head = t & 3;
  int p0 = off[n], p1 = off[n + 1];
  float adv = ad[t];
  float m = -1e30f, s = 0.f;
  for (int p = p0; p < p1; ++p) {
    float e = leaky(as[src_s[p] * 4 + head] + adv);
    if (e > m) { s *= __expf(m - e); m = e; }
    s += __expf(e - m);
  }
  float inv = 1.f / (s + 1e-16f);
  float acc = 0.f;
  for (int p = p0; p < p1; ++p) {
    int sp = src_s[p];
    float a = __expf(leaky(as[sp * 4 + head] + adv) - m) * inv;
    acc += a * h3[(size_t)sp * 4 + head];
  }
  acc += __shfl_down(acc, 1);
  acc += __shfl_down(acc, 2);
  if (head == 0) out[n] = acc * 0.25f + b3[0];
}

// ---------------- host orchestration ----------------

extern "C" void kernel_launch(void* const* d_in, const int* in_sizes, int n_in,
                              void* d_out, int out_size, void* d_ws, size_t ws_size,
                              hipStream_t stream) {
  const float* x   = (const float*)d_in[0];
  const int*   ei  = (const int*)d_in[1];
  const float* W1  = (const float*)d_in[2];
  const float* a1s = (const float*)d_in[3];
  const float* a1d = (const float*)d_in[4];
  const float* b1  = (const float*)d_in[5];
  const float* W2  = (const float*)d_in[6];
  const float* a2s = (const float*)d_in[7];
  const float* a2d = (const float*)d_in[8];
  const float* b2  = (const float*)d_in[9];
  const float* W3  = (const float*)d_in[10];
  const float* a3s = (const float*)d_in[11];
  const float* a3d = (const float*)d_in[12];
  const float* b3  = (const float*)d_in[13];

  const int N = in_sizes[0] / F_IN;
  const int E = in_sizes[1] / 2;
  const int Et = E + N;
  const int Npad = (N + 127) & ~127;
  const int nb = (N + 1023) >> 10;

  char* base = (char*)d_ws;
  size_t off = 0;
  auto alloc = [&](size_t bytes) {
    void* p = base + off;
    off = (off + bytes + 255) & ~(size_t)255;
    return p;
  };
  float* A      = (float*)alloc((size_t)N * F * sizeof(float));
  float* U      = (float*)alloc((size_t)Npad * F * sizeof(float));
  unsigned short* Xhi = (unsigned short*)U;
  unsigned short* Xlo = Xhi + (size_t)Npad * F;
  float* Bbuf   = U;
  int*   src_s  = (int*)alloc((size_t)Et * sizeof(int));
  int*   counts = (int*)alloc((size_t)N * sizeof(int));
  int*   offs   = (int*)alloc((size_t)(N + 1) * sizeof(int));
  int*   cursor = (int*)alloc((size_t)N * sizeof(int));
  int*   bsums  = (int*)alloc((size_t)1025 * sizeof(int));
  int*   boffs  = (int*)alloc((size_t)1026 * sizeof(int));
  float* as     = (float*)alloc((size_t)N * 4 * sizeof(float));
  float* ad     = (float*)alloc((size_t)N * 4 * sizeof(float));
  float* h3     = (float*)alloc((size_t)N * 4 * sizeof(float));
  unsigned short* Wth = (unsigned short*)alloc((size_t)512 * 512 * sizeof(unsigned short));
  unsigned short* Wtl = (unsigned short*)alloc((size_t)512 * 512 * sizeof(unsigned short));

  // ---- CSR build + W2 split ----
  hipMemsetAsync(counts, 0, (size_t)N * sizeof(int), stream);
  {
    int gg = (Et + 255) / 256;
    hipLaunchKernelGGL(hist_kernel, dim3(gg), dim3(256), 0, stream, ei, counts, N, E);
    hipLaunchKernelGGL(blockscan_kernel, dim3(nb), dim3(1024), 0, stream, counts, offs, bsums, N);
    hipLaunchKernelGGL(sumscan_kernel, dim3(1), dim3(1024), 0, stream, bsums, boffs, nb);
    hipLaunchKernelGGL(scanadd_kernel, dim3((N + 256) / 256), dim3(256), 0, stream, offs, boffs, cursor, N, nb);
    hipLaunchKernelGGL(scatter_kernel, dim3(gg), dim3(256), 0, stream, ei, cursor, src_s, N, E);
    hipLaunchKernelGGL(segsort_kernel, dim3((N + 255) / 256), dim3(256), 0, stream, src_s, offs, N);
    hipLaunchKernelGGL(wsplit_kernel, dim3(64), dim3(256), 0, stream, W2, Wth, Wtl);
  }

  int nhGrid = (N * 4 + 255) / 256;

  // ---- layer 1 ----
  hipLaunchKernelGGL(gemm30_kernel, dim3((N + 15) / 16), dim3(256), 0, stream,
                     x, W1, a1s, a1d, A, as, ad, N);
  hipLaunchKernelGGL((fused_aggregate_kernel<true, true>), dim3(N), dim3(128), 0, stream,
                     A, as, ad, src_s, offs, b1, (float*)nullptr, Xhi, Xlo);

  // ---- layer 2 ----
  hipLaunchKernelGGL(gemm512_mfma, dim3((N + 127) / 128, 4), dim3(256), 0, stream,
                     Xhi, Xlo, Wth, Wtl, a2s, a2d, A, as, ad, N);
  hipLaunchKernelGGL((fused_aggregate_kernel<true, false>), dim3(N), dim3(128), 0, stream,
                     A, as, ad, src_s, offs, b2, Bbuf,
                     (unsigned short*)nullptr, (unsigned short*)nullptr);

  // ---- layer 3 ----
  hipLaunchKernelGGL(gemm3_kernel, dim3((N + 3) / 4), dim3(256), 0, stream,
                     Bbuf, W3, a3s, a3d, h3, as, ad, N);
  hipLaunchKernelGGL(fused_aggregate3_kernel, dim3(nhGrid), dim3(256), 0, stream,
                     h3, as, ad, src_s, offs, b3, (float*)d_out, N);
}

// Round 14
// 870.294 us; speedup vs baseline: 7.5328x; 1.0556x over previous
//
#include <hip/hip_runtime.h>

#define NEG_SLOPE 0.2f

constexpr int F = 512;    // heads * channels
constexpr int F_IN = 30;
constexpr int DMAX = 512; // LDS-staged max degree (fallback path beyond)

typedef short bfrag __attribute__((ext_vector_type(8)));   // 8 bf16 = 4 VGPR
typedef float f32x4 __attribute__((ext_vector_type(4)));

__device__ __forceinline__ unsigned short bf16_rne(float v) {
  unsigned u = __float_as_uint(v);
  u += 0x7FFF + ((u >> 16) & 1);
  return (unsigned short)(u >> 16);
}
__device__ __forceinline__ float bf16f(unsigned short h) {
  return __uint_as_float(((unsigned)h) << 16);
}

// ---------------- CSR build ----------------

__global__ void hist_kernel(const int* __restrict__ ei, int* __restrict__ counts,
                            int N, int E) {
  int e = blockIdx.x * blockDim.x + threadIdx.x;
  int Et = E + N;
  if (e >= Et) return;
  int d = (e < E) ? ei[E + e] : (e - E);
  atomicAdd(&counts[d], 1);
}

// hierarchical scan: per-block scan -> scan of block sums -> add
__global__ void blockscan_kernel(const int* __restrict__ counts, int* __restrict__ offsets,
                                 int* __restrict__ bsums, int n) {
  __shared__ int wsum[16];
  int tid = threadIdx.x;
  int lane = tid & 63, wid = tid >> 6;
  int i = blockIdx.x * 1024 + tid;
  int v = (i < n) ? counts[i] : 0;
  int x = v;
#pragma unroll
  for (int d = 1; d < 64; d <<= 1) {
    int t2 = __shfl_up(x, d);
    if (lane >= d) x += t2;
  }
  if (lane == 63) wsum[wid] = x;
  __syncthreads();
  if (wid == 0) {
    int ws = (lane < 16) ? wsum[lane] : 0;
#pragma unroll
    for (int d = 1; d < 16; d <<= 1) {
      int t2 = __shfl_up(ws, d);
      if (lane >= d) ws += t2;
    }
    if (lane < 16) wsum[lane] = ws;
  }
  __syncthreads();
  int excl = ((wid > 0) ? wsum[wid - 1] : 0) + x - v;
  if (i < n) offsets[i] = excl;
  if (tid == 0) bsums[blockIdx.x] = wsum[15];
}

__global__ void sumscan_kernel(const int* __restrict__ bsums, int* __restrict__ boffs, int nb) {
  __shared__ int wsum[16];
  int tid = threadIdx.x;
  int lane = tid & 63, wid = tid >> 6;
  int v = (tid < nb) ? bsums[tid] : 0;
  int x = v;
#pragma unroll
  for (int d = 1; d < 64; d <<= 1) {
    int t2 = __shfl_up(x, d);
    if (lane >= d) x += t2;
  }
  if (lane == 63) wsum[wid] = x;
  __syncthreads();
  if (wid == 0) {
    int ws = (lane < 16) ? wsum[lane] : 0;
#pragma unroll
    for (int d = 1; d < 16; d <<= 1) {
      int t2 = __shfl_up(ws, d);
      if (lane >= d) ws += t2;
    }
    if (lane < 16) wsum[lane] = ws;
  }
  __syncthreads();
  int excl = ((wid > 0) ? wsum[wid - 1] : 0) + x - v;
  if (tid <= nb) boffs[tid] = (tid < nb) ? excl : wsum[15];
  if (tid == 0 && nb == 1024) boffs[1024] = wsum[15];
}

__global__ void scanadd_kernel(int* __restrict__ offsets, const int* __restrict__ boffs,
                               int* __restrict__ cursor, int n, int nb) {
  int i = blockIdx.x * blockDim.x + threadIdx.x;
  if (i < n) {
    int o = offsets[i] + boffs[i >> 10];
    offsets[i] = o;
    cursor[i] = o;
  } else if (i == n) {
    offsets[n] = boffs[nb];
  }
}

__global__ void scatter_kernel(const int* __restrict__ ei, int* __restrict__ cursor,
                               int* __restrict__ src_s, int N, int E) {
  int e = blockIdx.x * blockDim.x + threadIdx.x;
  int Et = E + N;
  if (e >= Et) return;
  int s, d;
  if (e < E) { s = ei[e]; d = ei[E + e]; } else { s = e - E; d = e - E; }
  int p = atomicAdd(&cursor[d], 1);
  src_s[p] = s;
}

// Canonicalize within-segment order for determinism across graph replays.
__global__ void segsort_kernel(int* __restrict__ src_s, const int* __restrict__ off, int N) {
  int n = blockIdx.x * blockDim.x + threadIdx.x;
  if (n >= N) return;
  int p0 = off[n], p1 = off[n + 1];
  for (int i = p0 + 1; i < p1; ++i) {
    int key = src_s[i];
    int j = i - 1;
    while (j >= p0 && src_s[j] > key) { src_s[j + 1] = src_s[j]; --j; }
    src_s[j + 1] = key;
  }
}

// ---------------- GEMM (layer1, K=30) + fused alpha epilogue ----------------

__global__ void gemm30_kernel(const float* __restrict__ X, const float* __restrict__ W,
                              const float* __restrict__ a_s, const float* __restrict__ a_d,
                              float* __restrict__ out,
                              float* __restrict__ as_o, float* __restrict__ ad_o, int N) {
  __shared__ float xs[16][F_IN];
  int row0 = blockIdx.x * 16;
  int tid = threadIdx.x;
  for (int i = tid; i < 16 * F_IN; i += 256) {
    int r = i / F_IN, k = i - r * F_IN;
    int row = row0 + r;
    xs[r][k] = (row < N) ? X[(size_t)row * F_IN + k] : 0.f;
  }
  __syncthreads();
  int cg = tid & 127;
  int rg = tid >> 7;
  int c0 = cg * 4;
  float4 acc[8];
#pragma unroll
  for (int r = 0; r < 8; ++r) acc[r] = make_float4(0.f, 0.f, 0.f, 0.f);
#pragma unroll 2
  for (int k = 0; k < F_IN; ++k) {
    float4 w = *(const float4*)(W + (size_t)k * F + c0);
#pragma unroll
    for (int r = 0; r < 8; ++r) {
      float xv = xs[rg * 8 + r][k];
      acc[r].x += xv * w.x; acc[r].y += xv * w.y;
      acc[r].z += xv * w.z; acc[r].w += xv * w.w;
    }
  }
#pragma unroll
  for (int r = 0; r < 8; ++r) {
    int row = row0 + rg * 8 + r;
    if (row < N) *(float4*)(out + (size_t)row * F + c0) = acc[r];
  }
  int hd = cg >> 5;
  float4 s4 = *(const float4*)(a_s + c0);
  float4 d4 = *(const float4*)(a_d + c0);
#pragma unroll
  for (int r = 0; r < 8; ++r) {
    float ps = acc[r].x * s4.x + acc[r].y * s4.y + acc[r].z * s4.z + acc[r].w * s4.w;
    float pd = acc[r].x * d4.x + acc[r].y * d4.y + acc[r].z * d4.z + acc[r].w * d4.w;
#pragma unroll
    for (int o = 1; o < 32; o <<= 1) {
      ps += __shfl_xor(ps, o, 32);
      pd += __shfl_xor(pd, o, 32);
    }
    if ((tid & 31) == 0) {
      int row = row0 + rg * 8 + r;
      if (row < N) { as_o[row * 4 + hd] = ps; ad_o[row * 4 + hd] = pd; }
    }
  }
}

// ---------------- W2 split + transpose ----------------

__global__ void wsplit_kernel(const float* __restrict__ W,
                              unsigned short* __restrict__ Wth,
                              unsigned short* __restrict__ Wtl) {
  __shared__ float t[64][65];
  int bx = blockIdx.x & 7, by = blockIdx.x >> 3;
  int tid = threadIdx.x;
#pragma unroll
  for (int i = 0; i < 16; ++i) {
    int idx = tid + i * 256;
    int r = idx >> 6, c = idx & 63;
    t[r][c] = W[(size_t)(by * 64 + r) * 512 + bx * 64 + c];
  }
  __syncthreads();
#pragma unroll
  for (int i = 0; i < 16; ++i) {
    int idx = tid + i * 256;
    int r = idx >> 6, c = idx & 63;
    float v = t[c][r];
    unsigned short hi = bf16_rne(v);
    unsigned short lo = bf16_rne(v - bf16f(hi));
    size_t o = (size_t)(bx * 64 + r) * 512 + by * 64 + c;
    Wth[o] = hi; Wtl[o] = lo;
  }
}

// ---------------- GEMM (layer2, K=512) via MFMA + fused alpha epilogue ------

__global__ void gemm512_mfma(const unsigned short* __restrict__ Xhi,
                             const unsigned short* __restrict__ Xlo,
                             const unsigned short* __restrict__ Wth,
                             const unsigned short* __restrict__ Wtl,
                             const float* __restrict__ a_s, const float* __restrict__ a_d,
                             float* __restrict__ out,
                             float* __restrict__ as_o, float* __restrict__ ad_o, int N) {
  __shared__ int4 lds4[2048];               // 32 KB
  char* lds = (char*)lds4;
  const int tid = threadIdx.x;
  const int wid = tid >> 6;
  const int lane = tid & 63;
  const int row0 = blockIdx.x * 128;
  const int by = blockIdx.y;
  const int col0 = by * 128;
  const int wr = wid >> 1, wc = wid & 1;

  const unsigned short* sb = (wid == 0) ? Xhi : (wid == 1) ? Xlo : (wid == 2) ? Wth : Wtl;
  const int tile0 = (wid < 2) ? row0 : col0;
  const int chunk = (lane & 3) ^ ((lane >> 3) & 3);
  const unsigned short* lanesrc = sb + (size_t)(tile0 + (lane >> 2)) * 512 + chunk * 8;
  char* ldst = lds + wid * 8192;

  const int g = lane >> 4;
  int aoff[4], boff[4];
#pragma unroll
  for (int m = 0; m < 4; ++m) {
    int r = wr * 64 + m * 16 + (lane & 15);
    aoff[m] = r * 64 + ((g ^ ((r >> 1) & 3)) << 4);
    int c = wc * 64 + m * 16 + (lane & 15);
    boff[m] = c * 64 + ((g ^ ((c >> 1) & 3)) << 4);
  }

  f32x4 acc[4][4];
#pragma unroll
  for (int m = 0; m < 4; ++m)
#pragma unroll
    for (int n = 0; n < 4; ++n) acc[m][n] = f32x4{0.f, 0.f, 0.f, 0.f};

  for (int kc = 0; kc < 16; ++kc) {
#pragma unroll
    for (int i = 0; i < 8; ++i) {
      __builtin_amdgcn_global_load_lds(
          (const __attribute__((address_space(1))) void*)(lanesrc + i * 8192 + kc * 32),
          (__attribute__((address_space(3))) void*)(ldst + i * 1024), 16, 0, 0);
    }
    __syncthreads();
    bfrag ah[4], al[4], bh[4], bl[4];
#pragma unroll
    for (int m = 0; m < 4; ++m) {
      ah[m] = *(const bfrag*)(lds + aoff[m]);
      al[m] = *(const bfrag*)(lds + 8192 + aoff[m]);
      bh[m] = *(const bfrag*)(lds + 16384 + boff[m]);
      bl[m] = *(const bfrag*)(lds + 24576 + boff[m]);
    }
#pragma unroll
    for (int m = 0; m < 4; ++m)
#pragma unroll
      for (int n = 0; n < 4; ++n) {
        acc[m][n] = __builtin_amdgcn_mfma_f32_16x16x32_bf16(al[m], bh[n], acc[m][n], 0, 0, 0);
        acc[m][n] = __builtin_amdgcn_mfma_f32_16x16x32_bf16(ah[m], bl[n], acc[m][n], 0, 0, 0);
        acc[m][n] = __builtin_amdgcn_mfma_f32_16x16x32_bf16(ah[m], bh[n], acc[m][n], 0, 0, 0);
      }
    __syncthreads();
  }

  const int crow = (lane >> 4) * 4, ccol = lane & 15;
#pragma unroll
  for (int m = 0; m < 4; ++m) {
    int Rb = row0 + wr * 64 + m * 16 + crow;
#pragma unroll
    for (int n = 0; n < 4; ++n) {
      int C = col0 + wc * 64 + n * 16 + ccol;
#pragma unroll
      for (int q = 0; q < 4; ++q) {
        int R = Rb + q;
        if (R < N) out[(size_t)R * F + C] = acc[m][n][q];
      }
    }
  }

  // fused alpha epilogue (head == by)
  float cs[4], cd[4];
#pragma unroll
  for (int n = 0; n < 4; ++n) {
    cs[n] = a_s[col0 + wc * 64 + n * 16 + (lane & 15)];
    cd[n] = a_d[col0 + wc * 64 + n * 16 + (lane & 15)];
  }
  float* red = (float*)lds;
#pragma unroll
  for (int m = 0; m < 4; ++m) {
#pragma unroll
    for (int q = 0; q < 4; ++q) {
      float ps = 0.f, pd = 0.f;
#pragma unroll
      for (int n = 0; n < 4; ++n) {
        ps += acc[m][n][q] * cs[n];
        pd += acc[m][n][q] * cd[n];
      }
#pragma unroll
      for (int o = 1; o < 16; o <<= 1) {
        ps += __shfl_xor(ps, o, 16);
        pd += __shfl_xor(pd, o, 16);
      }
      if ((lane & 15) == 0) {
        int rl = m * 16 + (lane >> 4) * 4 + q;
        red[((wr * 2 + wc) * 64 + rl) * 2 + 0] = ps;
        red[((wr * 2 + wc) * 64 + rl) * 2 + 1] = pd;
      }
    }
  }
  __syncthreads();
  if (tid < 128) {
    int wrr = tid >> 6, rl = tid & 63;
    float vs = red[((wrr * 2 + 0) * 64 + rl) * 2] + red[((wrr * 2 + 1) * 64 + rl) * 2];
    float vd = red[((wrr * 2 + 0) * 64 + rl) * 2 + 1] + red[((wrr * 2 + 1) * 64 + rl) * 2 + 1];
    int row = row0 + wrr * 64 + rl;
    if (row < N) { as_o[row * 4 + by] = vs; ad_o[row * 4 + by] = vd; }
  }
}

// ---------------- fused softmax-stats + aggregate (LDS-staged scores) -------
// SPLIT: emit bf16 hi/lo for MFMA GEMM (layer 1).
// H3: fuse layer-3 GEMM + alpha3 epilogue (layer 2): h3[n] = out2[n]@W3,
//     as/ad = h3 * a3s/a3d. Fixed 64-lane xor tree + 2-wave LDS combine.

__device__ __forceinline__ float leaky(float v) { return v > 0.f ? v : NEG_SLOPE * v; }

__device__ __forceinline__ void fma4(float4& a, float s, const float4& b) {
  a.x += s * b.x; a.y += s * b.y; a.z += s * b.z; a.w += s * b.w;
}

template <bool RELU, bool SPLIT, bool H3>
__global__ void fused_aggregate_kernel(const float* __restrict__ hsrc,
                                       const float* __restrict__ as, const float* __restrict__ ad,
                                       const int* __restrict__ src_s, const int* __restrict__ off,
                                       const float* __restrict__ bias, float* __restrict__ out,
                                       unsigned short* __restrict__ oh, unsigned short* __restrict__ ol,
                                       const float* __restrict__ W3, const float* __restrict__ a3s,
                                       const float* __restrict__ a3d, float* __restrict__ h3_o,
                                       float* __restrict__ as3_o, float* __restrict__ ad3_o) {
  __shared__ float esc[4][DMAX + 8];
  __shared__ float hred[2][4];
  int n = blockIdx.x;
  int tid = threadIdx.x;
  int head = tid >> 5;
  int l32 = tid & 31;
  int c0 = tid * 4;
  int p0 = off[n], p1 = off[n + 1];
  int deg = p1 - p0;
  float4 adv4 = *(const float4*)(ad + (size_t)n * 4);
  float adv = (head == 0) ? adv4.x : (head == 1) ? adv4.y : (head == 2) ? adv4.z : adv4.w;

  float m = -1e30f, s = 0.f;
  float4 acc = make_float4(0.f, 0.f, 0.f, 0.f);

  if (deg <= DMAX) {
    for (int i = tid; i < deg; i += 128) {
      int sp = src_s[p0 + i];
      float4 a4 = *(const float4*)(as + (size_t)sp * 4);
      esc[0][i] = leaky(a4.x + adv4.x);
      esc[1][i] = leaky(a4.y + adv4.y);
      esc[2][i] = leaky(a4.z + adv4.z);
      esc[3][i] = leaky(a4.w + adv4.w);
    }
    __syncthreads();
    for (int i = l32; i < deg; i += 32) {
      float e = esc[head][i];
      if (e > m) { s *= __expf(m - e); m = e; }
      s += __expf(e - m);
    }
#pragma unroll
    for (int o = 16; o > 0; o >>= 1) {
      float mo = __shfl_down(m, o, 32);
      float so = __shfl_down(s, o, 32);
      float mn = fmaxf(m, mo);
      s = s * __expf(m - mn) + so * __expf(mo - mn);
      m = mn;
    }
    m = __shfl(m, 0, 32);
    s = __shfl(s, 0, 32);
    float inv = 1.f / (s + 1e-16f);
#pragma unroll 2
    for (int i = 0; i < deg; ++i) {
      int sp = src_s[p0 + i];
      float a = __expf(esc[head][i] - m) * inv;
      float4 hv = *(const float4*)(hsrc + (size_t)sp * F + c0);
      fma4(acc, a, hv);
    }
  } else {
    for (int p = p0 + l32; p < p1; p += 32) {
      float e = leaky(as[src_s[p] * 4 + head] + adv);
      if (e > m) { s *= __expf(m - e); m = e; }
      s += __expf(e - m);
    }
#pragma unroll
    for (int o = 16; o > 0; o >>= 1) {
      float mo = __shfl_down(m, o, 32);
      float so = __shfl_down(s, o, 32);
      float mn = fmaxf(m, mo);
      s = s * __expf(m - mn) + so * __expf(mo - mn);
      m = mn;
    }
    m = __shfl(m, 0, 32);
    s = __shfl(s, 0, 32);
    float inv = 1.f / (s + 1e-16f);
    for (int p = p0; p < p1; ++p) {
      int sp = src_s[p];
      float a = __expf(leaky(as[sp * 4 + head] + adv) - m) * inv;
      float4 hv = *(const float4*)(hsrc + (size_t)sp * F + c0);
      fma4(acc, a, hv);
    }
  }

  float4 bv = *(const float4*)(bias + c0);
  acc.x += bv.x; acc.y += bv.y; acc.z += bv.z; acc.w += bv.w;
  if (RELU) {
    acc.x = fmaxf(acc.x, 0.f); acc.y = fmaxf(acc.y, 0.f);
    acc.z = fmaxf(acc.z, 0.f); acc.w = fmaxf(acc.w, 0.f);
  }
  if (SPLIT) {
    ushort4 hv4, lv4;
    hv4.x = bf16_rne(acc.x); lv4.x = bf16_rne(acc.x - bf16f(hv4.x));
    hv4.y = bf16_rne(acc.y); lv4.y = bf16_rne(acc.y - bf16f(hv4.y));
    hv4.z = bf16_rne(acc.z); lv4.z = bf16_rne(acc.z - bf16f(hv4.z));
    hv4.w = bf16_rne(acc.w); lv4.w = bf16_rne(acc.w - bf16f(hv4.w));
    *(ushort4*)(oh + (size_t)n * F + c0) = hv4;
    *(ushort4*)(ol + (size_t)n * F + c0) = lv4;
  } else if (!H3) {
    *(float4*)(out + (size_t)n * F + c0) = acc;
  }
  if (H3) {
    // fused layer-3 GEMM: h3[n][j] = sum_c out2[n][c] * W3[c][j]
    float4 w0 = *(const float4*)(W3 + (size_t)(c0 + 0) * 4);
    float4 w1 = *(const float4*)(W3 + (size_t)(c0 + 1) * 4);
    float4 w2 = *(const float4*)(W3 + (size_t)(c0 + 2) * 4);
    float4 w3r = *(const float4*)(W3 + (size_t)(c0 + 3) * 4);
    float p[4];
    p[0] = acc.x * w0.x + acc.y * w1.x + acc.z * w2.x + acc.w * w3r.x;
    p[1] = acc.x * w0.y + acc.y * w1.y + acc.z * w2.y + acc.w * w3r.y;
    p[2] = acc.x * w0.z + acc.y * w1.z + acc.z * w2.z + acc.w * w3r.z;
    p[3] = acc.x * w0.w + acc.y * w1.w + acc.z * w2.w + acc.w * w3r.w;
#pragma unroll
    for (int j = 0; j < 4; ++j)
#pragma unroll
      for (int o = 1; o < 64; o <<= 1) p[j] += __shfl_xor(p[j], o, 64);
    int wv = tid >> 6;
    if ((tid & 63) == 0) {
      hred[wv][0] = p[0]; hred[wv][1] = p[1];
      hred[wv][2] = p[2]; hred[wv][3] = p[3];
    }
    __syncthreads();
    if (tid == 0) {
      float4 h;
      h.x = hred[0][0] + hred[1][0];
      h.y = hred[0][1] + hred[1][1];
      h.z = hred[0][2] + hred[1][2];
      h.w = hred[0][3] + hred[1][3];
      *(float4*)(h3_o + (size_t)n * 4) = h;
      float4 so, dd;
      so.x = h.x * a3s[0]; so.y = h.y * a3s[1]; so.z = h.z * a3s[2]; so.w = h.w * a3s[3];
      dd.x = h.x * a3d[0]; dd.y = h.y * a3d[1]; dd.z = h.z * a3d[2]; dd.w = h.w * a3d[3];
      *(float4*)(as3_o + (size_t)n * 4) = so;
      *(float4*)(ad3_o + (size_t)n * 4) = dd;
    }
  }
}

// layer3: one thread per (node, head); two serial passes (small L2-hot data)
__global__ void fused_aggregate3_kernel(const float* __restrict__ h3,
                                        const float* __restrict__ as, const float* __restrict__ ad,
                                        const int* __restrict__ src_s, const int* __restrict__ off,
                                        const float* __restrict__ b3, float* __restrict__ out, int N) {
  int t = blockIdx.x * blockDim.x + threadIdx.x;
  if (t >= N * 4) return;
  int n = t >> 2, head = t & 3;
  int p0 = off[n], p1 = off[n + 1];
  float adv = ad[t];
  float m = -1e30f, s = 0.f;
  for (int p = p0; p < p1; ++p) {
    float e = leaky(as[src_s[p] * 4 + head] + adv);
    if (e > m) { s *= __expf(m - e); m = e; }
    s += __expf(e - m);
  }
  float inv = 1.f / (s + 1e-16f);
  float acc = 0.f;
  for (int p = p0; p < p1; ++p) {
    int sp = src_s[p];
    float a = __expf(leaky(as[sp * 4 + head] + adv) - m) * inv;
    acc += a * h3[(size_t)sp * 4 + head];
  }
  acc += __shfl_down(acc, 1);
  acc += __shfl_down(acc, 2);
  if (head == 0) out[n] = acc * 0.25f + b3[0];
}

// ---------------- host orchestration ----------------

extern "C" void kernel_launch(void* const* d_in, const int* in_sizes, int n_in,
                              void* d_out, int out_size, void* d_ws, size_t ws_size,
                              hipStream_t stream) {
  const float* x   = (const float*)d_in[0];
  const int*   ei  = (const int*)d_in[1];
  const float* W1  = (const float*)d_in[2];
  const float* a1s = (const float*)d_in[3];
  const float* a1d = (const float*)d_in[4];
  const float* b1  = (const float*)d_in[5];
  const float* W2  = (const float*)d_in[6];
  const float* a2s = (const float*)d_in[7];
  const float* a2d = (const float*)d_in[8];
  const float* b2  = (const float*)d_in[9];
  const float* W3  = (const float*)d_in[10];
  const float* a3s = (const float*)d_in[11];
  const float* a3d = (const float*)d_in[12];
  const float* b3  = (const float*)d_in[13];

  const int N = in_sizes[0] / F_IN;
  const int E = in_sizes[1] / 2;
  const int Et = E + N;
  const int Npad = (N + 127) & ~127;
  const int nb = (N + 1023) >> 10;

  char* base = (char*)d_ws;
  size_t off = 0;
  auto alloc = [&](size_t bytes) {
    void* p = base + off;
    off = (off + bytes + 255) & ~(size_t)255;
    return p;
  };
  float* A      = (float*)alloc((size_t)N * F * sizeof(float));
  float* U      = (float*)alloc((size_t)Npad * F * sizeof(float));
  unsigned short* Xhi = (unsigned short*)U;
  unsigned short* Xlo = Xhi + (size_t)Npad * F;
  int*   src_s  = (int*)alloc((size_t)Et * sizeof(int));
  int*   counts = (int*)alloc((size_t)N * sizeof(int));
  int*   offs   = (int*)alloc((size_t)(N + 1) * sizeof(int));
  int*   cursor = (int*)alloc((size_t)N * sizeof(int));
  int*   bsums  = (int*)alloc((size_t)1025 * sizeof(int));
  int*   boffs  = (int*)alloc((size_t)1026 * sizeof(int));
  float* as     = (float*)alloc((size_t)N * 4 * sizeof(float));
  float* ad     = (float*)alloc((size_t)N * 4 * sizeof(float));
  float* as3    = (float*)alloc((size_t)N * 4 * sizeof(float));
  float* ad3    = (float*)alloc((size_t)N * 4 * sizeof(float));
  float* h3     = (float*)alloc((size_t)N * 4 * sizeof(float));
  unsigned short* Wth = (unsigned short*)alloc((size_t)512 * 512 * sizeof(unsigned short));
  unsigned short* Wtl = (unsigned short*)alloc((size_t)512 * 512 * sizeof(unsigned short));

  // ---- CSR build + W2 split ----
  hipMemsetAsync(counts, 0, (size_t)N * sizeof(int), stream);
  {
    int gg = (Et + 255) / 256;
    hipLaunchKernelGGL(hist_kernel, dim3(gg), dim3(256), 0, stream, ei, counts, N, E);
    hipLaunchKernelGGL(blockscan_kernel, dim3(nb), dim3(1024), 0, stream, counts, offs, bsums, N);
    hipLaunchKernelGGL(sumscan_kernel, dim3(1), dim3(1024), 0, stream, bsums, boffs, nb);
    hipLaunchKernelGGL(scanadd_kernel, dim3((N + 256) / 256), dim3(256), 0, stream, offs, boffs, cursor, N, nb);
    hipLaunchKernelGGL(scatter_kernel, dim3(gg), dim3(256), 0, stream, ei, cursor, src_s, N, E);
    hipLaunchKernelGGL(segsort_kernel, dim3((N + 255) / 256), dim3(256), 0, stream, src_s, offs, N);
    hipLaunchKernelGGL(wsplit_kernel, dim3(64), dim3(256), 0, stream, W2, Wth, Wtl);
  }

  int nhGrid = (N * 4 + 255) / 256;

  // ---- layer 1 ----
  hipLaunchKernelGGL(gemm30_kernel, dim3((N + 15) / 16), dim3(256), 0, stream,
                     x, W1, a1s, a1d, A, as, ad, N);
  hipLaunchKernelGGL((fused_aggregate_kernel<true, true, false>), dim3(N), dim3(128), 0, stream,
                     A, as, ad, src_s, offs, b1, (float*)nullptr, Xhi, Xlo,
                     (const float*)nullptr, (const float*)nullptr, (const float*)nullptr,
                     (float*)nullptr, (float*)nullptr, (float*)nullptr);

  // ---- layer 2 (+ fused layer-3 GEMM & alpha3) ----
  hipLaunchKernelGGL(gemm512_mfma, dim3((N + 127) / 128, 4), dim3(256), 0, stream,
                     Xhi, Xlo, Wth, Wtl, a2s, a2d, A, as, ad, N);
  hipLaunchKernelGGL((fused_aggregate_kernel<true, false, true>), dim3(N), dim3(128), 0, stream,
                     A, as, ad, src_s, offs, b2, (float*)nullptr,
                     (unsigned short*)nullptr, (unsigned short*)nullptr,
                     W3, a3s, a3d, h3, as3, ad3);

  // ---- layer 3 ----
  hipLaunchKernelGGL(fused_aggregate3_kernel, dim3(nhGrid), dim3(256), 0, stream,
                     h3, as3, ad3, src_s, offs, b3, (float*)d_out, N);
}

// Round 15
// 828.682 us; speedup vs baseline: 7.9110x; 1.0502x over previous
//
#include <hip/hip_runtime.h>

#define NEG_SLOPE 0.2f

constexpr int F = 512;    // heads * channels
constexpr int F_IN = 30;
constexpr int DMAX = 512; // LDS-staged max degree (fallback path beyond)

typedef short bfrag __attribute__((ext_vector_type(8)));   // 8 bf16 = 4 VGPR
typedef float f32x4 __attribute__((ext_vector_type(4)));

__device__ __forceinline__ unsigned short bf16_rne(float v) {
  unsigned u = __float_as_uint(v);
  u += 0x7FFF + ((u >> 16) & 1);
  return (unsigned short)(u >> 16);
}
__device__ __forceinline__ float bf16f(unsigned short h) {
  return __uint_as_float(((unsigned)h) << 16);
}

// ---------------- CSR build ----------------

__global__ void hist_kernel(const int* __restrict__ ei, int* __restrict__ counts,
                            int N, int E) {
  int e = blockIdx.x * blockDim.x + threadIdx.x;
  int Et = E + N;
  if (e >= Et) return;
  int d = (e < E) ? ei[E + e] : (e - E);
  atomicAdd(&counts[d], 1);
}

// hierarchical scan: per-block scan -> scan of block sums -> add
__global__ void blockscan_kernel(const int* __restrict__ counts, int* __restrict__ offsets,
                                 int* __restrict__ bsums, int n) {
  __shared__ int wsum[16];
  int tid = threadIdx.x;
  int lane = tid & 63, wid = tid >> 6;
  int i = blockIdx.x * 1024 + tid;
  int v = (i < n) ? counts[i] : 0;
  int x = v;
#pragma unroll
  for (int d = 1; d < 64; d <<= 1) {
    int t2 = __shfl_up(x, d);
    if (lane >= d) x += t2;
  }
  if (lane == 63) wsum[wid] = x;
  __syncthreads();
  if (wid == 0) {
    int ws = (lane < 16) ? wsum[lane] : 0;
#pragma unroll
    for (int d = 1; d < 16; d <<= 1) {
      int t2 = __shfl_up(ws, d);
      if (lane >= d) ws += t2;
    }
    if (lane < 16) wsum[lane] = ws;
  }
  __syncthreads();
  int excl = ((wid > 0) ? wsum[wid - 1] : 0) + x - v;
  if (i < n) offsets[i] = excl;
  if (tid == 0) bsums[blockIdx.x] = wsum[15];
}

__global__ void sumscan_kernel(const int* __restrict__ bsums, int* __restrict__ boffs, int nb) {
  __shared__ int wsum[16];
  int tid = threadIdx.x;
  int lane = tid & 63, wid = tid >> 6;
  int v = (tid < nb) ? bsums[tid] : 0;
  int x = v;
#pragma unroll
  for (int d = 1; d < 64; d <<= 1) {
    int t2 = __shfl_up(x, d);
    if (lane >= d) x += t2;
  }
  if (lane == 63) wsum[wid] = x;
  __syncthreads();
  if (wid == 0) {
    int ws = (lane < 16) ? wsum[lane] : 0;
#pragma unroll
    for (int d = 1; d < 16; d <<= 1) {
      int t2 = __shfl_up(ws, d);
      if (lane >= d) ws += t2;
    }
    if (lane < 16) wsum[lane] = ws;
  }
  __syncthreads();
  int excl = ((wid > 0) ? wsum[wid - 1] : 0) + x - v;
  if (tid <= nb) boffs[tid] = (tid < nb) ? excl : wsum[15];
  if (tid == 0 && nb == 1024) boffs[1024] = wsum[15];
}

__global__ void scanadd_kernel(int* __restrict__ offsets, const int* __restrict__ boffs,
                               int* __restrict__ cursor, int n, int nb) {
  int i = blockIdx.x * blockDim.x + threadIdx.x;
  if (i < n) {
    int o = offsets[i] + boffs[i >> 10];
    offsets[i] = o;
    cursor[i] = o;
  } else if (i == n) {
    offsets[n] = boffs[nb];
  }
}

__global__ void scatter_kernel(const int* __restrict__ ei, int* __restrict__ cursor,
                               int* __restrict__ src_s, int N, int E) {
  int e = blockIdx.x * blockDim.x + threadIdx.x;
  int Et = E + N;
  if (e >= Et) return;
  int s, d;
  if (e < E) { s = ei[e]; d = ei[E + e]; } else { s = e - E; d = e - E; }
  int p = atomicAdd(&cursor[d], 1);
  src_s[p] = s;
}

// Canonicalize within-segment order for determinism across graph replays.
// LDS-staged insertion sort (padded rows: stride 65 -> conflict-free);
// deg>64 falls back to in-place global sort (never hit for Poisson(16)).
__global__ void segsort_kernel(int* __restrict__ src_s, const int* __restrict__ off, int N) {
  __shared__ int buf[128][65];
  int n = blockIdx.x * 128 + threadIdx.x;
  if (n >= N) return;
  int p0 = off[n], p1 = off[n + 1];
  int deg = p1 - p0;
  if (deg <= 64) {
    int* b = buf[threadIdx.x];
    for (int i = 0; i < deg; ++i) b[i] = src_s[p0 + i];
    for (int i = 1; i < deg; ++i) {
      int key = b[i];
      int j = i - 1;
      while (j >= 0 && b[j] > key) { b[j + 1] = b[j]; --j; }
      b[j + 1] = key;
    }
    for (int i = 0; i < deg; ++i) src_s[p0 + i] = b[i];
  } else {
    for (int i = p0 + 1; i < p1; ++i) {
      int key = src_s[i];
      int j = i - 1;
      while (j >= p0 && src_s[j] > key) { src_s[j + 1] = src_s[j]; --j; }
      src_s[j + 1] = key;
    }
  }
}

// ---------------- GEMM (layer1, K=30) + fused alpha epilogue ----------------

__global__ void gemm30_kernel(const float* __restrict__ X, const float* __restrict__ W,
                              const float* __restrict__ a_s, const float* __restrict__ a_d,
                              float* __restrict__ out,
                              float* __restrict__ as_o, float* __restrict__ ad_o, int N) {
  __shared__ float xs[16][F_IN];
  int row0 = blockIdx.x * 16;
  int tid = threadIdx.x;
  for (int i = tid; i < 16 * F_IN; i += 256) {
    int r = i / F_IN, k = i - r * F_IN;
    int row = row0 + r;
    xs[r][k] = (row < N) ? X[(size_t)row * F_IN + k] : 0.f;
  }
  __syncthreads();
  int cg = tid & 127;
  int rg = tid >> 7;
  int c0 = cg * 4;
  float4 acc[8];
#pragma unroll
  for (int r = 0; r < 8; ++r) acc[r] = make_float4(0.f, 0.f, 0.f, 0.f);
#pragma unroll 2
  for (int k = 0; k < F_IN; ++k) {
    float4 w = *(const float4*)(W + (size_t)k * F + c0);
#pragma unroll
    for (int r = 0; r < 8; ++r) {
      float xv = xs[rg * 8 + r][k];
      acc[r].x += xv * w.x; acc[r].y += xv * w.y;
      acc[r].z += xv * w.z; acc[r].w += xv * w.w;
    }
  }
#pragma unroll
  for (int r = 0; r < 8; ++r) {
    int row = row0 + rg * 8 + r;
    if (row < N) *(float4*)(out + (size_t)row * F + c0) = acc[r];
  }
  int hd = cg >> 5;
  float4 s4 = *(const float4*)(a_s + c0);
  float4 d4 = *(const float4*)(a_d + c0);
#pragma unroll
  for (int r = 0; r < 8; ++r) {
    float ps = acc[r].x * s4.x + acc[r].y * s4.y + acc[r].z * s4.z + acc[r].w * s4.w;
    float pd = acc[r].x * d4.x + acc[r].y * d4.y + acc[r].z * d4.z + acc[r].w * d4.w;
#pragma unroll
    for (int o = 1; o < 32; o <<= 1) {
      ps += __shfl_xor(ps, o, 32);
      pd += __shfl_xor(pd, o, 32);
    }
    if ((tid & 31) == 0) {
      int row = row0 + rg * 8 + r;
      if (row < N) { as_o[row * 4 + hd] = ps; ad_o[row * 4 + hd] = pd; }
    }
  }
}

// ---------------- W2 split + transpose ----------------

__global__ void wsplit_kernel(const float* __restrict__ W,
                              unsigned short* __restrict__ Wth,
                              unsigned short* __restrict__ Wtl) {
  __shared__ float t[64][65];
  int bx = blockIdx.x & 7, by = blockIdx.x >> 3;
  int tid = threadIdx.x;
#pragma unroll
  for (int i = 0; i < 16; ++i) {
    int idx = tid + i * 256;
    int r = idx >> 6, c = idx & 63;
    t[r][c] = W[(size_t)(by * 64 + r) * 512 + bx * 64 + c];
  }
  __syncthreads();
#pragma unroll
  for (int i = 0; i < 16; ++i) {
    int idx = tid + i * 256;
    int r = idx >> 6, c = idx & 63;
    float v = t[c][r];
    unsigned short hi = bf16_rne(v);
    unsigned short lo = bf16_rne(v - bf16f(hi));
    size_t o = (size_t)(bx * 64 + r) * 512 + by * 64 + c;
    Wth[o] = hi; Wtl[o] = lo;
  }
}

// ---------------- GEMM (layer2, K=512) via MFMA + fused alpha epilogue ------

__global__ void gemm512_mfma(const unsigned short* __restrict__ Xhi,
                             const unsigned short* __restrict__ Xlo,
                             const unsigned short* __restrict__ Wth,
                             const unsigned short* __restrict__ Wtl,
                             const float* __restrict__ a_s, const float* __restrict__ a_d,
                             float* __restrict__ out,
                             float* __restrict__ as_o, float* __restrict__ ad_o, int N) {
  __shared__ int4 lds4[2048];               // 32 KB
  char* lds = (char*)lds4;
  const int tid = threadIdx.x;
  const int wid = tid >> 6;
  const int lane = tid & 63;
  const int row0 = blockIdx.x * 128;
  const int by = blockIdx.y;
  const int col0 = by * 128;
  const int wr = wid >> 1, wc = wid & 1;

  const unsigned short* sb = (wid == 0) ? Xhi : (wid == 1) ? Xlo : (wid == 2) ? Wth : Wtl;
  const int tile0 = (wid < 2) ? row0 : col0;
  const int chunk = (lane & 3) ^ ((lane >> 3) & 3);
  const unsigned short* lanesrc = sb + (size_t)(tile0 + (lane >> 2)) * 512 + chunk * 8;
  char* ldst = lds + wid * 8192;

  const int g = lane >> 4;
  int aoff[4], boff[4];
#pragma unroll
  for (int m = 0; m < 4; ++m) {
    int r = wr * 64 + m * 16 + (lane & 15);
    aoff[m] = r * 64 + ((g ^ ((r >> 1) & 3)) << 4);
    int c = wc * 64 + m * 16 + (lane & 15);
    boff[m] = c * 64 + ((g ^ ((c >> 1) & 3)) << 4);
  }

  f32x4 acc[4][4];
#pragma unroll
  for (int m = 0; m < 4; ++m)
#pragma unroll
    for (int n = 0; n < 4; ++n) acc[m][n] = f32x4{0.f, 0.f, 0.f, 0.f};

  for (int kc = 0; kc < 16; ++kc) {
#pragma unroll
    for (int i = 0; i < 8; ++i) {
      __builtin_amdgcn_global_load_lds(
          (const __attribute__((address_space(1))) void*)(lanesrc + i * 8192 + kc * 32),
          (__attribute__((address_space(3))) void*)(ldst + i * 1024), 16, 0, 0);
    }
    __syncthreads();
    bfrag ah[4], al[4], bh[4], bl[4];
#pragma unroll
    for (int m = 0; m < 4; ++m) {
      ah[m] = *(const bfrag*)(lds + aoff[m]);
      al[m] = *(const bfrag*)(lds + 8192 + aoff[m]);
      bh[m] = *(const bfrag*)(lds + 16384 + boff[m]);
      bl[m] = *(const bfrag*)(lds + 24576 + boff[m]);
    }
#pragma unroll
    for (int m = 0; m < 4; ++m)
#pragma unroll
      for (int n = 0; n < 4; ++n) {
        acc[m][n] = __builtin_amdgcn_mfma_f32_16x16x32_bf16(al[m], bh[n], acc[m][n], 0, 0, 0);
        acc[m][n] = __builtin_amdgcn_mfma_f32_16x16x32_bf16(ah[m], bl[n], acc[m][n], 0, 0, 0);
        acc[m][n] = __builtin_amdgcn_mfma_f32_16x16x32_bf16(ah[m], bh[n], acc[m][n], 0, 0, 0);
      }
    __syncthreads();
  }

  const int crow = (lane >> 4) * 4, ccol = lane & 15;
#pragma unroll
  for (int m = 0; m < 4; ++m) {
    int Rb = row0 + wr * 64 + m * 16 + crow;
#pragma unroll
    for (int n = 0; n < 4; ++n) {
      int C = col0 + wc * 64 + n * 16 + ccol;
#pragma unroll
      for (int q = 0; q < 4; ++q) {
        int R = Rb + q;
        if (R < N) out[(size_t)R * F + C] = acc[m][n][q];
      }
    }
  }

  // fused alpha epilogue (head == by)
  float cs[4], cd[4];
#pragma unroll
  for (int n = 0; n < 4; ++n) {
    cs[n] = a_s[col0 + wc * 64 + n * 16 + (lane & 15)];
    cd[n] = a_d[col0 + wc * 64 + n * 16 + (lane & 15)];
  }
  float* red = (float*)lds;
#pragma unroll
  for (int m = 0; m < 4; ++m) {
#pragma unroll
    for (int q = 0; q < 4; ++q) {
      float ps = 0.f, pd = 0.f;
#pragma unroll
      for (int n = 0; n < 4; ++n) {
        ps += acc[m][n][q] * cs[n];
        pd += acc[m][n][q] * cd[n];
      }
#pragma unroll
      for (int o = 1; o < 16; o <<= 1) {
        ps += __shfl_xor(ps, o, 16);
        pd += __shfl_xor(pd, o, 16);
      }
      if ((lane & 15) == 0) {
        int rl = m * 16 + (lane >> 4) * 4 + q;
        red[((wr * 2 + wc) * 64 + rl) * 2 + 0] = ps;
        red[((wr * 2 + wc) * 64 + rl) * 2 + 1] = pd;
      }
    }
  }
  __syncthreads();
  if (tid < 128) {
    int wrr = tid >> 6, rl = tid & 63;
    float vs = red[((wrr * 2 + 0) * 64 + rl) * 2] + red[((wrr * 2 + 1) * 64 + rl) * 2];
    float vd = red[((wrr * 2 + 0) * 64 + rl) * 2 + 1] + red[((wrr * 2 + 1) * 64 + rl) * 2 + 1];
    int row = row0 + wrr * 64 + rl;
    if (row < N) { as_o[row * 4 + by] = vs; ad_o[row * 4 + by] = vd; }
  }
}

// ---------------- fused softmax-stats + aggregate (LDS-staged scores) -------
// SPLIT: emit bf16 hi/lo for MFMA GEMM (layer 1).
// H3: fuse layer-3 GEMM + alpha3 epilogue (layer 2).

__device__ __forceinline__ float leaky(float v) { return v > 0.f ? v : NEG_SLOPE * v; }

__device__ __forceinline__ void fma4(float4& a, float s, const float4& b) {
  a.x += s * b.x; a.y += s * b.y; a.z += s * b.z; a.w += s * b.w;
}

template <bool RELU, bool SPLIT, bool H3>
__global__ void fused_aggregate_kernel(const float* __restrict__ hsrc,
                                       const float* __restrict__ as, const float* __restrict__ ad,
                                       const int* __restrict__ src_s, const int* __restrict__ off,
                                       const float* __restrict__ bias, float* __restrict__ out,
                                       unsigned short* __restrict__ oh, unsigned short* __restrict__ ol,
                                       const float* __restrict__ W3, const float* __restrict__ a3s,
                                       const float* __restrict__ a3d, float* __restrict__ h3_o,
                                       float* __restrict__ as3_o, float* __restrict__ ad3_o) {
  __shared__ float esc[4][DMAX + 8];
  __shared__ float hred[2][4];
  int n = blockIdx.x;
  int tid = threadIdx.x;
  int head = tid >> 5;
  int l32 = tid & 31;
  int c0 = tid * 4;
  int p0 = off[n], p1 = off[n + 1];
  int deg = p1 - p0;
  float4 adv4 = *(const float4*)(ad + (size_t)n * 4);
  float adv = (head == 0) ? adv4.x : (head == 1) ? adv4.y : (head == 2) ? adv4.z : adv4.w;

  float m = -1e30f, s = 0.f;
  float4 acc = make_float4(0.f, 0.f, 0.f, 0.f);

  if (deg <= DMAX) {
    for (int i = tid; i < deg; i += 128) {
      int sp = src_s[p0 + i];
      float4 a4 = *(const float4*)(as + (size_t)sp * 4);
      esc[0][i] = leaky(a4.x + adv4.x);
      esc[1][i] = leaky(a4.y + adv4.y);
      esc[2][i] = leaky(a4.z + adv4.z);
      esc[3][i] = leaky(a4.w + adv4.w);
    }
    __syncthreads();
    for (int i = l32; i < deg; i += 32) {
      float e = esc[head][i];
      if (e > m) { s *= __expf(m - e); m = e; }
      s += __expf(e - m);
    }
#pragma unroll
    for (int o = 16; o > 0; o >>= 1) {
      float mo = __shfl_down(m, o, 32);
      float so = __shfl_down(s, o, 32);
      float mn = fmaxf(m, mo);
      s = s * __expf(m - mn) + so * __expf(mo - mn);
      m = mn;
    }
    m = __shfl(m, 0, 32);
    s = __shfl(s, 0, 32);
    float inv = 1.f / (s + 1e-16f);
#pragma unroll 2
    for (int i = 0; i < deg; ++i) {
      int sp = src_s[p0 + i];
      float a = __expf(esc[head][i] - m) * inv;
      float4 hv = *(const float4*)(hsrc + (size_t)sp * F + c0);
      fma4(acc, a, hv);
    }
  } else {
    for (int p = p0 + l32; p < p1; p += 32) {
      float e = leaky(as[src_s[p] * 4 + head] + adv);
      if (e > m) { s *= __expf(m - e); m = e; }
      s += __expf(e - m);
    }
#pragma unroll
    for (int o = 16; o > 0; o >>= 1) {
      float mo = __shfl_down(m, o, 32);
      float so = __shfl_down(s, o, 32);
      float mn = fmaxf(m, mo);
      s = s * __expf(m - mn) + so * __expf(mo - mn);
      m = mn;
    }
    m = __shfl(m, 0, 32);
    s = __shfl(s, 0, 32);
    float inv = 1.f / (s + 1e-16f);
    for (int p = p0; p < p1; ++p) {
      int sp = src_s[p];
      float a = __expf(leaky(as[sp * 4 + head] + adv) - m) * inv;
      float4 hv = *(const float4*)(hsrc + (size_t)sp * F + c0);
      fma4(acc, a, hv);
    }
  }

  float4 bv = *(const float4*)(bias + c0);
  acc.x += bv.x; acc.y += bv.y; acc.z += bv.z; acc.w += bv.w;
  if (RELU) {
    acc.x = fmaxf(acc.x, 0.f); acc.y = fmaxf(acc.y, 0.f);
    acc.z = fmaxf(acc.z, 0.f); acc.w = fmaxf(acc.w, 0.f);
  }
  if (SPLIT) {
    ushort4 hv4, lv4;
    hv4.x = bf16_rne(acc.x); lv4.x = bf16_rne(acc.x - bf16f(hv4.x));
    hv4.y = bf16_rne(acc.y); lv4.y = bf16_rne(acc.y - bf16f(hv4.y));
    hv4.z = bf16_rne(acc.z); lv4.z = bf16_rne(acc.z - bf16f(hv4.z));
    hv4.w = bf16_rne(acc.w); lv4.w = bf16_rne(acc.w - bf16f(hv4.w));
    *(ushort4*)(oh + (size_t)n * F + c0) = hv4;
    *(ushort4*)(ol + (size_t)n * F + c0) = lv4;
  } else if (!H3) {
    *(float4*)(out + (size_t)n * F + c0) = acc;
  }
  if (H3) {
    float4 w0 = *(const float4*)(W3 + (size_t)(c0 + 0) * 4);
    float4 w1 = *(const float4*)(W3 + (size_t)(c0 + 1) * 4);
    float4 w2 = *(const float4*)(W3 + (size_t)(c0 + 2) * 4);
    float4 w3r = *(const float4*)(W3 + (size_t)(c0 + 3) * 4);
    float p[4];
    p[0] = acc.x * w0.x + acc.y * w1.x + acc.z * w2.x + acc.w * w3r.x;
    p[1] = acc.x * w0.y + acc.y * w1.y + acc.z * w2.y + acc.w * w3r.y;
    p[2] = acc.x * w0.z + acc.y * w1.z + acc.z * w2.z + acc.w * w3r.z;
    p[3] = acc.x * w0.w + acc.y * w1.w + acc.z * w2.w + acc.w * w3r.w;
#pragma unroll
    for (int j = 0; j < 4; ++j)
#pragma unroll
      for (int o = 1; o < 64; o <<= 1) p[j] += __shfl_xor(p[j], o, 64);
    int wv = tid >> 6;
    if ((tid & 63) == 0) {
      hred[wv][0] = p[0]; hred[wv][1] = p[1];
      hred[wv][2] = p[2]; hred[wv][3] = p[3];
    }
    __syncthreads();
    if (tid == 0) {
      float4 h;
      h.x = hred[0][0] + hred[1][0];
      h.y = hred[0][1] + hred[1][1];
      h.z = hred[0][2] + hred[1][2];
      h.w = hred[0][3] + hred[1][3];
      *(float4*)(h3_o + (size_t)n * 4) = h;
      float4 so, dd;
      so.x = h.x * a3s[0]; so.y = h.y * a3s[1]; so.z = h.z * a3s[2]; so.w = h.w * a3s[3];
      dd.x = h.x * a3d[0]; dd.y = h.y * a3d[1]; dd.z = h.z * a3d[2]; dd.w = h.w * a3d[3];
      *(float4*)(as3_o + (size_t)n * 4) = so;
      *(float4*)(ad3_o + (size_t)n * 4) = dd;
    }
  }
}

// layer3: one thread per (node, head); two serial passes (small L2-hot data)
__global__ void fused_aggregate3_kernel(const float* __restrict__ h3,
                                        const float* __restrict__ as, const float* __restrict__ ad,
                                        const int* __restrict__ src_s, const int* __restrict__ off,
                                        const float* __restrict__ b3, float* __restrict__ out, int N) {
  int t = blockIdx.x * blockDim.x + threadIdx.x;
  if (t >= N * 4) return;
  int n = t >> 2, head = t & 3;
  int p0 = off[n], p1 = off[n + 1];
  float adv = ad[t];
  float m = -1e30f, s = 0.f;
  for (int p = p0; p < p1; ++p) {
    float e = leaky(as[src_s[p] * 4 + head] + adv);
    if (e > m) { s *= __expf(m - e); m = e; }
    s += __expf(e - m);
  }
  float inv = 1.f / (s + 1e-16f);
  float acc = 0.f;
  for (int p = p0; p < p1; ++p) {
    int sp = src_s[p];
    float a = __expf(leaky(as[sp * 4 + head] + adv) - m) * inv;
    acc += a * h3[(size_t)sp * 4 + head];
  }
  acc += __shfl_down(acc, 1);
  acc += __shfl_down(acc, 2);
  if (head == 0) out[n] = acc * 0.25f + b3[0];
}

// ---------------- host orchestration ----------------

extern "C" void kernel_launch(void* const* d_in, const int* in_sizes, int n_in,
                              void* d_out, int out_size, void* d_ws, size_t ws_size,
                              hipStream_t stream) {
  const float* x   = (const float*)d_in[0];
  const int*   ei  = (const int*)d_in[1];
  const float* W1  = (const float*)d_in[2];
  const float* a1s = (const float*)d_in[3];
  const float* a1d = (const float*)d_in[4];
  const float* b1  = (const float*)d_in[5];
  const float* W2  = (const float*)d_in[6];
  const float* a2s = (const float*)d_in[7];
  const float* a2d = (const float*)d_in[8];
  const float* b2  = (const float*)d_in[9];
  const float* W3  = (const float*)d_in[10];
  const float* a3s = (const float*)d_in[11];
  const float* a3d = (const float*)d_in[12];
  const float* b3  = (const float*)d_in[13];

  const int N = in_sizes[0] / F_IN;
  const int E = in_sizes[1] / 2;
  const int Et = E + N;
  const int Npad = (N + 127) & ~127;
  const int nb = (N + 1023) >> 10;

  char* base = (char*)d_ws;
  size_t off = 0;
  auto alloc = [&](size_t bytes) {
    void* p = base + off;
    off = (off + bytes + 255) & ~(size_t)255;
    return p;
  };
  float* A      = (float*)alloc((size_t)N * F * sizeof(float));
  float* U      = (float*)alloc((size_t)Npad * F * sizeof(float));
  unsigned short* Xhi = (unsigned short*)U;
  unsigned short* Xlo = Xhi + (size_t)Npad * F;
  int*   src_s  = (int*)alloc((size_t)Et * sizeof(int));
  int*   counts = (int*)alloc((size_t)N * sizeof(int));
  int*   offs   = (int*)alloc((size_t)(N + 1) * sizeof(int));
  int*   cursor = (int*)alloc((size_t)N * sizeof(int));
  int*   bsums  = (int*)alloc((size_t)1025 * sizeof(int));
  int*   boffs  = (int*)alloc((size_t)1026 * sizeof(int));
  float* as     = (float*)alloc((size_t)N * 4 * sizeof(float));
  float* ad     = (float*)alloc((size_t)N * 4 * sizeof(float));
  float* as3    = (float*)alloc((size_t)N * 4 * sizeof(float));
  float* ad3    = (float*)alloc((size_t)N * 4 * sizeof(float));
  float* h3     = (float*)alloc((size_t)N * 4 * sizeof(float));
  unsigned short* Wth = (unsigned short*)alloc((size_t)512 * 512 * sizeof(unsigned short));
  unsigned short* Wtl = (unsigned short*)alloc((size_t)512 * 512 * sizeof(unsigned short));

  // ---- CSR build + W2 split ----
  hipMemsetAsync(counts, 0, (size_t)N * sizeof(int), stream);
  {
    int gg = (Et + 255) / 256;
    hipLaunchKernelGGL(hist_kernel, dim3(gg), dim3(256), 0, stream, ei, counts, N, E);
    hipLaunchKernelGGL(blockscan_kernel, dim3(nb), dim3(1024), 0, stream, counts, offs, bsums, N);
    hipLaunchKernelGGL(sumscan_kernel, dim3(1), dim3(1024), 0, stream, bsums, boffs, nb);
    hipLaunchKernelGGL(scanadd_kernel, dim3((N + 256) / 256), dim3(256), 0, stream, offs, boffs, cursor, N, nb);
    hipLaunchKernelGGL(scatter_kernel, dim3(gg), dim3(256), 0, stream, ei, cursor, src_s, N, E);
    hipLaunchKernelGGL(segsort_kernel, dim3((N + 127) / 128), dim3(128), 0, stream, src_s, offs, N);
    hipLaunchKernelGGL(wsplit_kernel, dim3(64), dim3(256), 0, stream, W2, Wth, Wtl);
  }

  int nhGrid = (N * 4 + 255) / 256;

  // ---- layer 1 ----
  hipLaunchKernelGGL(gemm30_kernel, dim3((N + 15) / 16), dim3(256), 0, stream,
                     x, W1, a1s, a1d, A, as, ad, N);
  hipLaunchKernelGGL((fused_aggregate_kernel<true, true, false>), dim3(N), dim3(128), 0, stream,
                     A, as, ad, src_s, offs, b1, (float*)nullptr, Xhi, Xlo,
                     (const float*)nullptr, (const float*)nullptr, (const float*)nullptr,
                     (float*)nullptr, (float*)nullptr, (float*)nullptr);

  // ---- layer 2 (+ fused layer-3 GEMM & alpha3) ----
  hipLaunchKernelGGL(gemm512_mfma, dim3((N + 127) / 128, 4), dim3(256), 0, stream,
                     Xhi, Xlo, Wth, Wtl, a2s, a2d, A, as, ad, N);
  hipLaunchKernelGGL((fused_aggregate_kernel<true, false, true>), dim3(N), dim3(128), 0, stream,
                     A, as, ad, src_s, offs, b2, (float*)nullptr,
                     (unsigned short*)nullptr, (unsigned short*)nullptr,
                     W3, a3s, a3d, h3, as3, ad3);

  // ---- layer 3 ----
  hipLaunchKernelGGL(fused_aggregate3_kernel, dim3(nhGrid), dim3(256), 0, stream,
                     h3, as3, ad3, src_s, offs, b3, (float*)d_out, N);
}

// Round 16
// 814.321 us; speedup vs baseline: 8.0505x; 1.0176x over previous
//
#include <hip/hip_runtime.h>

#define NEG_SLOPE 0.2f

constexpr int F = 512;    // heads * channels
constexpr int F_IN = 30;
constexpr int DMAX = 512; // LDS-staged max degree (fallback path beyond)

typedef short bfrag __attribute__((ext_vector_type(8)));   // 8 bf16 = 4 VGPR
typedef float f32x4 __attribute__((ext_vector_type(4)));

__device__ __forceinline__ unsigned short bf16_rne(float v) {
  unsigned u = __float_as_uint(v);
  u += 0x7FFF + ((u >> 16) & 1);
  return (unsigned short)(u >> 16);
}
__device__ __forceinline__ float bf16f(unsigned short h) {
  return __uint_as_float(((unsigned)h) << 16);
}

// ---------------- CSR build ----------------

// hierarchical scan: per-block scan -> scan of block sums -> add
__global__ void blockscan_kernel(const int* __restrict__ counts, int* __restrict__ offsets,
                                 int* __restrict__ bsums, int n) {
  __shared__ int wsum[16];
  int tid = threadIdx.x;
  int lane = tid & 63, wid = tid >> 6;
  int i = blockIdx.x * 1024 + tid;
  int v = (i < n) ? counts[i] : 0;
  int x = v;
#pragma unroll
  for (int d = 1; d < 64; d <<= 1) {
    int t2 = __shfl_up(x, d);
    if (lane >= d) x += t2;
  }
  if (lane == 63) wsum[wid] = x;
  __syncthreads();
  if (wid == 0) {
    int ws = (lane < 16) ? wsum[lane] : 0;
#pragma unroll
    for (int d = 1; d < 16; d <<= 1) {
      int t2 = __shfl_up(ws, d);
      if (lane >= d) ws += t2;
    }
    if (lane < 16) wsum[lane] = ws;
  }
  __syncthreads();
  int excl = ((wid > 0) ? wsum[wid - 1] : 0) + x - v;
  if (i < n) offsets[i] = excl;
  if (tid == 0) bsums[blockIdx.x] = wsum[15];
}

__global__ void sumscan_kernel(const int* __restrict__ bsums, int* __restrict__ boffs, int nb) {
  __shared__ int wsum[16];
  int tid = threadIdx.x;
  int lane = tid & 63, wid = tid >> 6;
  int v = (tid < nb) ? bsums[tid] : 0;
  int x = v;
#pragma unroll
  for (int d = 1; d < 64; d <<= 1) {
    int t2 = __shfl_up(x, d);
    if (lane >= d) x += t2;
  }
  if (lane == 63) wsum[wid] = x;
  __syncthreads();
  if (wid == 0) {
    int ws = (lane < 16) ? wsum[lane] : 0;
#pragma unroll
    for (int d = 1; d < 16; d <<= 1) {
      int t2 = __shfl_up(ws, d);
      if (lane >= d) ws += t2;
    }
    if (lane < 16) wsum[lane] = ws;
  }
  __syncthreads();
  int excl = ((wid > 0) ? wsum[wid - 1] : 0) + x - v;
  if (tid <= nb) boffs[tid] = (tid < nb) ? excl : wsum[15];
  if (tid == 0 && nb == 1024) boffs[1024] = wsum[15];
}

__global__ void scanadd_kernel(int* __restrict__ offsets, const int* __restrict__ boffs,
                               int* __restrict__ cursor, int n, int nb) {
  int i = blockIdx.x * blockDim.x + threadIdx.x;
  if (i < n) {
    int o = offsets[i] + boffs[i >> 10];
    offsets[i] = o;
    cursor[i] = o;
  } else if (i == n) {
    offsets[n] = boffs[nb];
  }
}

// scatter + wsplit fused (independent work, grid-partitioned)
__global__ void scatter_wsplit_kernel(const int* __restrict__ ei, int* __restrict__ cursor,
                                      int* __restrict__ src_s, int N, int E, int scatGrid,
                                      const float* __restrict__ W,
                                      unsigned short* __restrict__ Wth,
                                      unsigned short* __restrict__ Wtl) {
  __shared__ float t[64][65];
  if (blockIdx.x < scatGrid) {
    int e = blockIdx.x * 256 + threadIdx.x;
    int Et = E + N;
    if (e >= Et) return;
    int s, d;
    if (e < E) { s = ei[e]; d = ei[E + e]; } else { s = e - E; d = e - E; }
    int p = atomicAdd(&cursor[d], 1);
    src_s[p] = s;
    return;
  }
  int b = blockIdx.x - scatGrid;
  int bx = b & 7, by = b >> 3;
  int tid = threadIdx.x;
#pragma unroll
  for (int i = 0; i < 16; ++i) {
    int idx = tid + i * 256;
    int r = idx >> 6, c = idx & 63;
    t[r][c] = W[(size_t)(by * 64 + r) * 512 + bx * 64 + c];
  }
  __syncthreads();
#pragma unroll
  for (int i = 0; i < 16; ++i) {
    int idx = tid + i * 256;
    int r = idx >> 6, c = idx & 63;
    float v = t[c][r];
    unsigned short hi = bf16_rne(v);
    unsigned short lo = bf16_rne(v - bf16f(hi));
    size_t o = (size_t)(bx * 64 + r) * 512 + by * 64 + c;
    Wth[o] = hi; Wtl[o] = lo;
  }
}

// Canonicalize within-segment order for determinism across graph replays.
// LDS-staged insertion sort; deg>64 falls back to global (never hit here).
__global__ void segsort_kernel(int* __restrict__ src_s, const int* __restrict__ off, int N) {
  __shared__ int buf[128][65];
  int n = blockIdx.x * 128 + threadIdx.x;
  if (n >= N) return;
  int p0 = off[n], p1 = off[n + 1];
  int deg = p1 - p0;
  if (deg <= 64) {
    int* b = buf[threadIdx.x];
    for (int i = 0; i < deg; ++i) b[i] = src_s[p0 + i];
    for (int i = 1; i < deg; ++i) {
      int key = b[i];
      int j = i - 1;
      while (j >= 0 && b[j] > key) { b[j + 1] = b[j]; --j; }
      b[j + 1] = key;
    }
    for (int i = 0; i < deg; ++i) src_s[p0 + i] = b[i];
  } else {
    for (int i = p0 + 1; i < p1; ++i) {
      int key = src_s[i];
      int j = i - 1;
      while (j >= p0 && src_s[j] > key) { src_s[j + 1] = src_s[j]; --j; }
      src_s[j + 1] = key;
    }
  }
}

// ---------------- GEMM (layer1, K=30) + fused alpha epilogue + hist ---------

__global__ void gemm30_hist_kernel(const float* __restrict__ X, const float* __restrict__ W,
                                   const float* __restrict__ a_s, const float* __restrict__ a_d,
                                   float* __restrict__ out,
                                   float* __restrict__ as_o, float* __restrict__ ad_o, int N,
                                   const int* __restrict__ ei, int* __restrict__ counts,
                                   int E, int gemmGrid) {
  __shared__ float xs[16][F_IN];
  int tid = threadIdx.x;
  if (blockIdx.x >= gemmGrid) {
    int e = (blockIdx.x - gemmGrid) * 256 + tid;
    int Et = E + N;
    if (e < Et) {
      int d = (e < E) ? ei[E + e] : (e - E);
      atomicAdd(&counts[d], 1);
    }
    return;
  }
  int row0 = blockIdx.x * 16;
  for (int i = tid; i < 16 * F_IN; i += 256) {
    int r = i / F_IN, k = i - r * F_IN;
    int row = row0 + r;
    xs[r][k] = (row < N) ? X[(size_t)row * F_IN + k] : 0.f;
  }
  __syncthreads();
  int cg = tid & 127;
  int rg = tid >> 7;
  int c0 = cg * 4;
  float4 acc[8];
#pragma unroll
  for (int r = 0; r < 8; ++r) acc[r] = make_float4(0.f, 0.f, 0.f, 0.f);
#pragma unroll 2
  for (int k = 0; k < F_IN; ++k) {
    float4 w = *(const float4*)(W + (size_t)k * F + c0);
#pragma unroll
    for (int r = 0; r < 8; ++r) {
      float xv = xs[rg * 8 + r][k];
      acc[r].x += xv * w.x; acc[r].y += xv * w.y;
      acc[r].z += xv * w.z; acc[r].w += xv * w.w;
    }
  }
#pragma unroll
  for (int r = 0; r < 8; ++r) {
    int row = row0 + rg * 8 + r;
    if (row < N) *(float4*)(out + (size_t)row * F + c0) = acc[r];
  }
  int hd = cg >> 5;
  float4 s4 = *(const float4*)(a_s + c0);
  float4 d4 = *(const float4*)(a_d + c0);
#pragma unroll
  for (int r = 0; r < 8; ++r) {
    float ps = acc[r].x * s4.x + acc[r].y * s4.y + acc[r].z * s4.z + acc[r].w * s4.w;
    float pd = acc[r].x * d4.x + acc[r].y * d4.y + acc[r].z * d4.z + acc[r].w * d4.w;
#pragma unroll
    for (int o = 1; o < 32; o <<= 1) {
      ps += __shfl_xor(ps, o, 32);
      pd += __shfl_xor(pd, o, 32);
    }
    if ((tid & 31) == 0) {
      int row = row0 + rg * 8 + r;
      if (row < N) { as_o[row * 4 + hd] = ps; ad_o[row * 4 + hd] = pd; }
    }
  }
}

// ---------------- GEMM (layer2, K=512) via MFMA + fused alpha epilogue ------

__global__ void gemm512_mfma(const unsigned short* __restrict__ Xhi,
                             const unsigned short* __restrict__ Xlo,
                             const unsigned short* __restrict__ Wth,
                             const unsigned short* __restrict__ Wtl,
                             const float* __restrict__ a_s, const float* __restrict__ a_d,
                             float* __restrict__ out,
                             float* __restrict__ as_o, float* __restrict__ ad_o, int N) {
  __shared__ int4 lds4[2048];               // 32 KB
  char* lds = (char*)lds4;
  const int tid = threadIdx.x;
  const int wid = tid >> 6;
  const int lane = tid & 63;
  const int row0 = blockIdx.x * 128;
  const int by = blockIdx.y;
  const int col0 = by * 128;
  const int wr = wid >> 1, wc = wid & 1;

  const unsigned short* sb = (wid == 0) ? Xhi : (wid == 1) ? Xlo : (wid == 2) ? Wth : Wtl;
  const int tile0 = (wid < 2) ? row0 : col0;
  const int chunk = (lane & 3) ^ ((lane >> 3) & 3);
  const unsigned short* lanesrc = sb + (size_t)(tile0 + (lane >> 2)) * 512 + chunk * 8;
  char* ldst = lds + wid * 8192;

  const int g = lane >> 4;
  int aoff[4], boff[4];
#pragma unroll
  for (int m = 0; m < 4; ++m) {
    int r = wr * 64 + m * 16 + (lane & 15);
    aoff[m] = r * 64 + ((g ^ ((r >> 1) & 3)) << 4);
    int c = wc * 64 + m * 16 + (lane & 15);
    boff[m] = c * 64 + ((g ^ ((c >> 1) & 3)) << 4);
  }

  f32x4 acc[4][4];
#pragma unroll
  for (int m = 0; m < 4; ++m)
#pragma unroll
    for (int n = 0; n < 4; ++n) acc[m][n] = f32x4{0.f, 0.f, 0.f, 0.f};

  for (int kc = 0; kc < 16; ++kc) {
#pragma unroll
    for (int i = 0; i < 8; ++i) {
      __builtin_amdgcn_global_load_lds(
          (const __attribute__((address_space(1))) void*)(lanesrc + i * 8192 + kc * 32),
          (__attribute__((address_space(3))) void*)(ldst + i * 1024), 16, 0, 0);
    }
    __syncthreads();
    bfrag ah[4], al[4], bh[4], bl[4];
#pragma unroll
    for (int m = 0; m < 4; ++m) {
      ah[m] = *(const bfrag*)(lds + aoff[m]);
      al[m] = *(const bfrag*)(lds + 8192 + aoff[m]);
      bh[m] = *(const bfrag*)(lds + 16384 + boff[m]);
      bl[m] = *(const bfrag*)(lds + 24576 + boff[m]);
    }
#pragma unroll
    for (int m = 0; m < 4; ++m)
#pragma unroll
      for (int n = 0; n < 4; ++n) {
        acc[m][n] = __builtin_amdgcn_mfma_f32_16x16x32_bf16(al[m], bh[n], acc[m][n], 0, 0, 0);
        acc[m][n] = __builtin_amdgcn_mfma_f32_16x16x32_bf16(ah[m], bl[n], acc[m][n], 0, 0, 0);
        acc[m][n] = __builtin_amdgcn_mfma_f32_16x16x32_bf16(ah[m], bh[n], acc[m][n], 0, 0, 0);
      }
    __syncthreads();
  }

  const int crow = (lane >> 4) * 4, ccol = lane & 15;
#pragma unroll
  for (int m = 0; m < 4; ++m) {
    int Rb = row0 + wr * 64 + m * 16 + crow;
#pragma unroll
    for (int n = 0; n < 4; ++n) {
      int C = col0 + wc * 64 + n * 16 + ccol;
#pragma unroll
      for (int q = 0; q < 4; ++q) {
        int R = Rb + q;
        if (R < N) out[(size_t)R * F + C] = acc[m][n][q];
      }
    }
  }

  // fused alpha epilogue (head == by)
  float cs[4], cd[4];
#pragma unroll
  for (int n = 0; n < 4; ++n) {
    cs[n] = a_s[col0 + wc * 64 + n * 16 + (lane & 15)];
    cd[n] = a_d[col0 + wc * 64 + n * 16 + (lane & 15)];
  }
  float* red = (float*)lds;
#pragma unroll
  for (int m = 0; m < 4; ++m) {
#pragma unroll
    for (int q = 0; q < 4; ++q) {
      float ps = 0.f, pd = 0.f;
#pragma unroll
      for (int n = 0; n < 4; ++n) {
        ps += acc[m][n][q] * cs[n];
        pd += acc[m][n][q] * cd[n];
      }
#pragma unroll
      for (int o = 1; o < 16; o <<= 1) {
        ps += __shfl_xor(ps, o, 16);
        pd += __shfl_xor(pd, o, 16);
      }
      if ((lane & 15) == 0) {
        int rl = m * 16 + (lane >> 4) * 4 + q;
        red[((wr * 2 + wc) * 64 + rl) * 2 + 0] = ps;
        red[((wr * 2 + wc) * 64 + rl) * 2 + 1] = pd;
      }
    }
  }
  __syncthreads();
  if (tid < 128) {
    int wrr = tid >> 6, rl = tid & 63;
    float vs = red[((wrr * 2 + 0) * 64 + rl) * 2] + red[((wrr * 2 + 1) * 64 + rl) * 2];
    float vd = red[((wrr * 2 + 0) * 64 + rl) * 2 + 1] + red[((wrr * 2 + 1) * 64 + rl) * 2 + 1];
    int row = row0 + wrr * 64 + rl;
    if (row < N) { as_o[row * 4 + by] = vs; ad_o[row * 4 + by] = vd; }
  }
}

// ---------------- fused softmax-stats + aggregate (LDS-staged scores) -------

__device__ __forceinline__ float leaky(float v) { return v > 0.f ? v : NEG_SLOPE * v; }

__device__ __forceinline__ void fma4(float4& a, float s, const float4& b) {
  a.x += s * b.x; a.y += s * b.y; a.z += s * b.z; a.w += s * b.w;
}

template <bool RELU, bool SPLIT, bool H3>
__global__ void fused_aggregate_kernel(const float* __restrict__ hsrc,
                                       const float* __restrict__ as, const float* __restrict__ ad,
                                       const int* __restrict__ src_s, const int* __restrict__ off,
                                       const float* __restrict__ bias, float* __restrict__ out,
                                       unsigned short* __restrict__ oh, unsigned short* __restrict__ ol,
                                       const float* __restrict__ W3, const float* __restrict__ a3s,
                                       const float* __restrict__ a3d, float* __restrict__ h3_o,
                                       float* __restrict__ as3_o, float* __restrict__ ad3_o) {
  __shared__ float esc[4][DMAX + 8];
  __shared__ float hred[2][4];
  int n = blockIdx.x;
  int tid = threadIdx.x;
  int head = tid >> 5;
  int l32 = tid & 31;
  int c0 = tid * 4;
  int p0 = off[n], p1 = off[n + 1];
  int deg = p1 - p0;
  float4 adv4 = *(const float4*)(ad + (size_t)n * 4);
  float adv = (head == 0) ? adv4.x : (head == 1) ? adv4.y : (head == 2) ? adv4.z : adv4.w;

  float m = -1e30f, s = 0.f;
  float4 acc = make_float4(0.f, 0.f, 0.f, 0.f);

  if (deg <= DMAX) {
    for (int i = tid; i < deg; i += 128) {
      int sp = src_s[p0 + i];
      float4 a4 = *(const float4*)(as + (size_t)sp * 4);
      esc[0][i] = leaky(a4.x + adv4.x);
      esc[1][i] = leaky(a4.y + adv4.y);
      esc[2][i] = leaky(a4.z + adv4.z);
      esc[3][i] = leaky(a4.w + adv4.w);
    }
    __syncthreads();
    for (int i = l32; i < deg; i += 32) {
      float e = esc[head][i];
      if (e > m) { s *= __expf(m - e); m = e; }
      s += __expf(e - m);
    }
#pragma unroll
    for (int o = 16; o > 0; o >>= 1) {
      float mo = __shfl_down(m, o, 32);
      float so = __shfl_down(s, o, 32);
      float mn = fmaxf(m, mo);
      s = s * __expf(m - mn) + so * __expf(mo - mn);
      m = mn;
    }
    m = __shfl(m, 0, 32);
    s = __shfl(s, 0, 32);
    float inv = 1.f / (s + 1e-16f);
#pragma unroll 2
    for (int i = 0; i < deg; ++i) {
      int sp = src_s[p0 + i];
      float a = __expf(esc[head][i] - m) * inv;
      float4 hv = *(const float4*)(hsrc + (size_t)sp * F + c0);
      fma4(acc, a, hv);
    }
  } else {
    for (int p = p0 + l32; p < p1; p += 32) {
      float e = leaky(as[src_s[p] * 4 + head] + adv);
      if (e > m) { s *= __expf(m - e); m = e; }
      s += __expf(e - m);
    }
#pragma unroll
    for (int o = 16; o > 0; o >>= 1) {
      float mo = __shfl_down(m, o, 32);
      float so = __shfl_down(s, o, 32);
      float mn = fmaxf(m, mo);
      s = s * __expf(m - mn) + so * __expf(mo - mn);
      m = mn;
    }
    m = __shfl(m, 0, 32);
    s = __shfl(s, 0, 32);
    float inv = 1.f / (s + 1e-16f);
    for (int p = p0; p < p1; ++p) {
      int sp = src_s[p];
      float a = __expf(leaky(as[sp * 4 + head] + adv) - m) * inv;
      float4 hv = *(const float4*)(hsrc + (size_t)sp * F + c0);
      fma4(acc, a, hv);
    }
  }

  float4 bv = *(const float4*)(bias + c0);
  acc.x += bv.x; acc.y += bv.y; acc.z += bv.z; acc.w += bv.w;
  if (RELU) {
    acc.x = fmaxf(acc.x, 0.f); acc.y = fmaxf(acc.y, 0.f);
    acc.z = fmaxf(acc.z, 0.f); acc.w = fmaxf(acc.w, 0.f);
  }
  if (SPLIT) {
    ushort4 hv4, lv4;
    hv4.x = bf16_rne(acc.x); lv4.x = bf16_rne(acc.x - bf16f(hv4.x));
    hv4.y = bf16_rne(acc.y); lv4.y = bf16_rne(acc.y - bf16f(hv4.y));
    hv4.z = bf16_rne(acc.z); lv4.z = bf16_rne(acc.z - bf16f(hv4.z));
    hv4.w = bf16_rne(acc.w); lv4.w = bf16_rne(acc.w - bf16f(hv4.w));
    *(ushort4*)(oh + (size_t)n * F + c0) = hv4;
    *(ushort4*)(ol + (size_t)n * F + c0) = lv4;
  } else if (!H3) {
    *(float4*)(out + (size_t)n * F + c0) = acc;
  }
  if (H3) {
    float4 w0 = *(const float4*)(W3 + (size_t)(c0 + 0) * 4);
    float4 w1 = *(const float4*)(W3 + (size_t)(c0 + 1) * 4);
    float4 w2 = *(const float4*)(W3 + (size_t)(c0 + 2) * 4);
    float4 w3r = *(const float4*)(W3 + (size_t)(c0 + 3) * 4);
    float p[4];
    p[0] = acc.x * w0.x + acc.y * w1.x + acc.z * w2.x + acc.w * w3r.x;
    p[1] = acc.x * w0.y + acc.y * w1.y + acc.z * w2.y + acc.w * w3r.y;
    p[2] = acc.x * w0.z + acc.y * w1.z + acc.z * w2.z + acc.w * w3r.z;
    p[3] = acc.x * w0.w + acc.y * w1.w + acc.z * w2.w + acc.w * w3r.w;
#pragma unroll
    for (int j = 0; j < 4; ++j)
#pragma unroll
      for (int o = 1; o < 64; o <<= 1) p[j] += __shfl_xor(p[j], o, 64);
    int wv = tid >> 6;
    if ((tid & 63) == 0) {
      hred[wv][0] = p[0]; hred[wv][1] = p[1];
      hred[wv][2] = p[2]; hred[wv][3] = p[3];
    }
    __syncthreads();
    if (tid == 0) {
      float4 h;
      h.x = hred[0][0] + hred[1][0];
      h.y = hred[0][1] + hred[1][1];
      h.z = hred[0][2] + hred[1][2];
      h.w = hred[0][3] + hred[1][3];
      *(float4*)(h3_o + (size_t)n * 4) = h;
      float4 so, dd;
      so.x = h.x * a3s[0]; so.y = h.y * a3s[1]; so.z = h.z * a3s[2]; so.w = h.w * a3s[3];
      dd.x = h.x * a3d[0]; dd.y = h.y * a3d[1]; dd.z = h.z * a3d[2]; dd.w = h.w * a3d[3];
      *(float4*)(as3_o + (size_t)n * 4) = so;
      *(float4*)(ad3_o + (size_t)n * 4) = dd;
    }
  }
}

// layer3 aggregate: one WAVE per node (4 heads x 16 lanes), strided gathers,
// fixed shfl trees -> deterministic; ~4x the memory-level parallelism of the
// old 1-thread-per-(node,head) version.
__global__ void fused_aggregate3_kernel(const float* __restrict__ h3,
                                        const float* __restrict__ as, const float* __restrict__ ad,
                                        const int* __restrict__ src_s, const int* __restrict__ off,
                                        const float* __restrict__ b3, float* __restrict__ out, int N) {
  int tid = threadIdx.x;
  int n = blockIdx.x * 4 + (tid >> 6);
  if (n >= N) return;
  int l64 = tid & 63;
  int head = l64 >> 4;
  int l16 = l64 & 15;
  int p0 = off[n], p1 = off[n + 1];
  float adv = ad[n * 4 + head];
  // stats: strided-16 online (m,s) + fixed tree
  float m = -1e30f, s = 0.f;
  for (int p = p0 + l16; p < p1; p += 16) {
    float e = leaky(as[src_s[p] * 4 + head] + adv);
    if (e > m) { s *= __expf(m - e); m = e; }
    s += __expf(e - m);
  }
#pragma unroll
  for (int o = 8; o > 0; o >>= 1) {
    float mo = __shfl_down(m, o, 16);
    float so = __shfl_down(s, o, 16);
    float mn = fmaxf(m, mo);
    s = s * __expf(m - mn) + so * __expf(mo - mn);
    m = mn;
  }
  m = __shfl(m, 0, 16);
  s = __shfl(s, 0, 16);
  float inv = 1.f / (s + 1e-16f);
  // weighted sum: strided-16 + fixed tree
  float acc = 0.f;
  for (int p = p0 + l16; p < p1; p += 16) {
    int sp = src_s[p];
    float a = __expf(leaky(as[sp * 4 + head] + adv) - m) * inv;
    acc += a * h3[(size_t)sp * 4 + head];
  }
#pragma unroll
  for (int o = 8; o > 0; o >>= 1) acc += __shfl_down(acc, o, 16);
  // combine the 4 heads (lanes 0,16,32,48 hold per-head sums)
  float v0 = __shfl(acc, 0, 64);
  float v1 = __shfl(acc, 16, 64);
  float v2 = __shfl(acc, 32, 64);
  float v3 = __shfl(acc, 48, 64);
  if (l64 == 0) out[n] = ((v0 + v1) + (v2 + v3)) * 0.25f + b3[0];
}

// ---------------- host orchestration ----------------

extern "C" void kernel_launch(void* const* d_in, const int* in_sizes, int n_in,
                              void* d_out, int out_size, void* d_ws, size_t ws_size,
                              hipStream_t stream) {
  const float* x   = (const float*)d_in[0];
  const int*   ei  = (const int*)d_in[1];
  const float* W1  = (const float*)d_in[2];
  const float* a1s = (const float*)d_in[3];
  const float* a1d = (const float*)d_in[4];
  const float* b1  = (const float*)d_in[5];
  const float* W2  = (const float*)d_in[6];
  const float* a2s = (const float*)d_in[7];
  const float* a2d = (const float*)d_in[8];
  const float* b2  = (const float*)d_in[9];
  const float* W3  = (const float*)d_in[10];
  const float* a3s = (const float*)d_in[11];
  const float* a3d = (const float*)d_in[12];
  const float* b3  = (const float*)d_in[13];

  const int N = in_sizes[0] / F_IN;
  const int E = in_sizes[1] / 2;
  const int Et = E + N;
  const int Npad = (N + 127) & ~127;
  const int nb = (N + 1023) >> 10;

  char* base = (char*)d_ws;
  size_t off = 0;
  auto alloc = [&](size_t bytes) {
    void* p = base + off;
    off = (off + bytes + 255) & ~(size_t)255;
    return p;
  };
  float* A      = (float*)alloc((size_t)N * F * sizeof(float));
  float* U      = (float*)alloc((size_t)Npad * F * sizeof(float));
  unsigned short* Xhi = (unsigned short*)U;
  unsigned short* Xlo = Xhi + (size_t)Npad * F;
  int*   src_s  = (int*)alloc((size_t)Et * sizeof(int));
  int*   counts = (int*)alloc((size_t)N * sizeof(int));
  int*   offs   = (int*)alloc((size_t)(N + 1) * sizeof(int));
  int*   cursor = (int*)alloc((size_t)N * sizeof(int));
  int*   bsums  = (int*)alloc((size_t)1025 * sizeof(int));
  int*   boffs  = (int*)alloc((size_t)1026 * sizeof(int));
  float* as     = (float*)alloc((size_t)N * 4 * sizeof(float));
  float* ad     = (float*)alloc((size_t)N * 4 * sizeof(float));
  float* as3    = (float*)alloc((size_t)N * 4 * sizeof(float));
  float* ad3    = (float*)alloc((size_t)N * 4 * sizeof(float));
  float* h3     = (float*)alloc((size_t)N * 4 * sizeof(float));
  unsigned short* Wth = (unsigned short*)alloc((size_t)512 * 512 * sizeof(unsigned short));
  unsigned short* Wtl = (unsigned short*)alloc((size_t)512 * 512 * sizeof(unsigned short));

  const int gemmGrid = (N + 15) / 16;
  const int histGrid = (Et + 255) / 256;
  const int scatGrid = histGrid;

  // ---- phase 1: gemm30+alpha1 and hist (fused, independent) ----
  hipMemsetAsync(counts, 0, (size_t)N * sizeof(int), stream);
  hipLaunchKernelGGL(gemm30_hist_kernel, dim3(gemmGrid + histGrid), dim3(256), 0, stream,
                     x, W1, a1s, a1d, A, as, ad, N, ei, counts, E, gemmGrid);
  // ---- CSR: scan -> scatter+wsplit -> segsort ----
  hipLaunchKernelGGL(blockscan_kernel, dim3(nb), dim3(1024), 0, stream, counts, offs, bsums, N);
  hipLaunchKernelGGL(sumscan_kernel, dim3(1), dim3(1024), 0, stream, bsums, boffs, nb);
  hipLaunchKernelGGL(scanadd_kernel, dim3((N + 256) / 256), dim3(256), 0, stream, offs, boffs, cursor, N, nb);
  hipLaunchKernelGGL(scatter_wsplit_kernel, dim3(scatGrid + 64), dim3(256), 0, stream,
                     ei, cursor, src_s, N, E, scatGrid, W2, Wth, Wtl);
  hipLaunchKernelGGL(segsort_kernel, dim3((N + 127) / 128), dim3(128), 0, stream, src_s, offs, N);

  // ---- layer 1 aggregate (emits bf16 hi/lo) ----
  hipLaunchKernelGGL((fused_aggregate_kernel<true, true, false>), dim3(N), dim3(128), 0, stream,
                     A, as, ad, src_s, offs, b1, (float*)nullptr, Xhi, Xlo,
                     (const float*)nullptr, (const float*)nullptr, (const float*)nullptr,
                     (float*)nullptr, (float*)nullptr, (float*)nullptr);

  // ---- layer 2 (+ fused layer-3 GEMM & alpha3) ----
  hipLaunchKernelGGL(gemm512_mfma, dim3((N + 127) / 128, 4), dim3(256), 0, stream,
                     Xhi, Xlo, Wth, Wtl, a2s, a2d, A, as, ad, N);
  hipLaunchKernelGGL((fused_aggregate_kernel<true, false, true>), dim3(N), dim3(128), 0, stream,
                     A, as, ad, src_s, offs, b2, (float*)nullptr,
                     (unsigned short*)nullptr, (unsigned short*)nullptr,
                     W3, a3s, a3d, h3, as3, ad3);

  // ---- layer 3 ----
  hipLaunchKernelGGL(fused_aggregate3_kernel, dim3((N + 3) / 4), dim3(256), 0, stream,
                     h3, as3, ad3, src_s, offs, b3, (float*)d_out, N);
}